// Round 2
// baseline (11614.825 us; speedup 1.0000x reference)
//
#include <hip/hip_runtime.h>
#include <cmath>

#define L_TOK 576
#define DIMM  512
#define DINN  1024
#define NHH   16
#define HDD   64
#define NSTT  32
#define CONVD 1088
#define DPROJJ 2128
#define BATCHH 32
#define ROWS  (BATCHH * L_TOK)   // 18432

typedef unsigned int uint;

__device__ __forceinline__ float b2f(unsigned short u) {
    union { uint i; float f; } v; v.i = ((uint)u) << 16; return v.f;
}
__device__ __forceinline__ unsigned short f2b(float x) {
    union { float f; uint i; } v; v.f = x;
    uint r = (v.i + 0x7FFFu + ((v.i >> 16) & 1u)) >> 16;
    return (unsigned short)r;
}

// ---------------- RoPE tables ----------------
__global__ void rope_init(float* __restrict__ COS, float* __restrict__ SIN) {
    int i = blockIdx.x * 256 + threadIdx.x;   // L_TOK*8 = 4608
    if (i >= L_TOK * 8) return;
    int l = i >> 3, j = i & 7;
    double inv = pow(10000.0, -(double)(2 * j) / 16.0);
    double a = (double)l * inv;
    COS[i] = (float)cos(a);
    SIN[i] = (float)sin(a);
}

// ---------------- Patch embed: im2col GEMM 18432x768 @ 768x512 ----------------
__global__ __launch_bounds__(256) void patch_kernel(
        const float* __restrict__ img, const float* __restrict__ pw,
        const float* __restrict__ pb, const float* __restrict__ pos,
        float* __restrict__ X) {
    __shared__ float As[8][128];
    __shared__ float Bs[8][128];
    const int tid = threadIdx.x;
    const int m0 = blockIdx.y * 128, n0 = blockIdx.x * 128;
    const int tm = tid >> 4, tn = tid & 15;
    const int ar = tid >> 1, ak = (tid & 1) * 4;

    int m = m0 + ar;
    int b = m / L_TOK, l = m % L_TOK;
    int oy = l / 24, ox = l % 24;
    const float* base = img + (size_t)b * 3 * 384 * 384 + (size_t)oy * 16 * 384 + ox * 16;

    const int nr = tid >> 1, nk = (tid & 1) * 4;
    const float* Bp = pw + (size_t)(n0 + nr) * 768 + nk;

    float acc[8][8];
#pragma unroll
    for (int i = 0; i < 8; ++i)
#pragma unroll
        for (int j = 0; j < 8; ++j) acc[i][j] = 0.f;

    for (int k0 = 0; k0 < 768; k0 += 8) {
        int kg = k0 + ak;
        int c = kg >> 8, rem = kg & 255, iy = rem >> 4, ix = rem & 15;
        float4 av = *(const float4*)(base + (size_t)c * 147456 + iy * 384 + ix);
        float4 bv = *(const float4*)(Bp + k0);
        __syncthreads();
        As[ak + 0][ar] = av.x; As[ak + 1][ar] = av.y; As[ak + 2][ar] = av.z; As[ak + 3][ar] = av.w;
        Bs[nk + 0][nr] = bv.x; Bs[nk + 1][nr] = bv.y; Bs[nk + 2][nr] = bv.z; Bs[nk + 3][nr] = bv.w;
        __syncthreads();
#pragma unroll
        for (int k = 0; k < 8; ++k) {
            float am[8], bm[8];
            *(float4*)&am[0] = *(float4*)&As[k][tm * 4];
            *(float4*)&am[4] = *(float4*)&As[k][64 + tm * 4];
            *(float4*)&bm[0] = *(float4*)&Bs[k][tn * 4];
            *(float4*)&bm[4] = *(float4*)&Bs[k][64 + tn * 4];
#pragma unroll
            for (int i = 0; i < 8; ++i)
#pragma unroll
                for (int j = 0; j < 8; ++j) acc[i][j] = fmaf(am[i], bm[j], acc[i][j]);
        }
    }
#pragma unroll
    for (int ih = 0; ih < 2; ++ih)
#pragma unroll
        for (int i = 0; i < 4; ++i) {
            int mm = m0 + ih * 64 + tm * 4 + i;
            int ll = mm % L_TOK;
#pragma unroll
            for (int jh = 0; jh < 2; ++jh) {
                int n = n0 + jh * 64 + tn * 4;
                float4 v = make_float4(acc[ih * 4 + i][jh * 4 + 0], acc[ih * 4 + i][jh * 4 + 1],
                                       acc[ih * 4 + i][jh * 4 + 2], acc[ih * 4 + i][jh * 4 + 3]);
                v.x += pb[n + 0] + pos[(size_t)ll * DIMM + n + 0];
                v.y += pb[n + 1] + pos[(size_t)ll * DIMM + n + 1];
                v.z += pb[n + 2] + pos[(size_t)ll * DIMM + n + 2];
                v.w += pb[n + 3] + pos[(size_t)ll * DIMM + n + 3];
                *(float4*)(X + (size_t)mm * DIMM + n) = v;
            }
        }
}

// ---------------- per-row mean/rstd of X (rows of 512) ----------------
__global__ __launch_bounds__(256) void rowstat_kernel(
        const float* __restrict__ X, float* __restrict__ RS) {
    int row = blockIdx.x * 4 + (threadIdx.x >> 6);
    int lane = threadIdx.x & 63;
    const float* xr = X + (size_t)row * DIMM;
    float4 u0 = *(const float4*)(xr + lane * 8);
    float4 u1 = *(const float4*)(xr + lane * 8 + 4);
    float v[8] = {u0.x, u0.y, u0.z, u0.w, u1.x, u1.y, u1.z, u1.w};
    float s = 0.f;
#pragma unroll
    for (int j = 0; j < 8; ++j) s += v[j];
#pragma unroll
    for (int o = 32; o > 0; o >>= 1) s += __shfl_xor(s, o);
    float m = s * (1.f / DIMM);
    float q = 0.f;
#pragma unroll
    for (int j = 0; j < 8; ++j) { float d = v[j] - m; q += d * d; }
#pragma unroll
    for (int o = 32; o > 0; o >>= 1) q += __shfl_xor(q, o);
    float rstd = rsqrtf(q * (1.f / DIMM) + 1e-6f);
    if (lane == 0) {
        RS[row * 2 + 0] = m;
        RS[row * 2 + 1] = rstd;
    }
}

// ---------------- in_proj GEMM with fused LN on A: [18432x512] @ [512x2128] ----------------
// Output split: cols [0,1024) -> Z (bf16), [1024,2112) -> XBC (bf16), [2112,2128) -> DTRAW (f32)
__global__ __launch_bounds__(256) void gemm_inproj(
        const float* __restrict__ X, const float* __restrict__ RS,
        const float* __restrict__ lnw, const float* __restrict__ lnb,
        const float* __restrict__ B,
        unsigned short* __restrict__ Z, unsigned short* __restrict__ XBC,
        float* __restrict__ DTRAW) {
    const int M = ROWS, N = DPROJJ, K = DIMM;
    __shared__ float As[8][128];
    __shared__ float Bs[8][128];
    const int tid = threadIdx.x;
    const int m0 = blockIdx.y * 128, n0 = blockIdx.x * 128;
    const int tm = tid >> 4, tn = tid & 15;
    const int ar = tid >> 1, ak = (tid & 1) * 4;
    const int bk = tid >> 5, bn = (tid & 31) * 4;

    float acc[8][8];
#pragma unroll
    for (int i = 0; i < 8; ++i)
#pragma unroll
        for (int j = 0; j < 8; ++j) acc[i][j] = 0.f;

    const int arow = m0 + ar;
    const float* Ap = X + (size_t)arow * K + ak;
    const float rm = RS[arow * 2 + 0];
    const float rr = RS[arow * 2 + 1];
    const float* Bp = B + (size_t)bk * N + n0 + bn;
    const bool bok = (n0 + bn) < N;

    for (int k0 = 0; k0 < K; k0 += 8) {
        float4 av = *(const float4*)(Ap + k0);
        float4 wv = *(const float4*)(lnw + k0 + ak);
        float4 lv = *(const float4*)(lnb + k0 + ak);
        float4 bv = bok ? *(const float4*)(Bp + (size_t)k0 * N) : make_float4(0.f, 0.f, 0.f, 0.f);
        av.x = (av.x - rm) * rr * wv.x + lv.x;
        av.y = (av.y - rm) * rr * wv.y + lv.y;
        av.z = (av.z - rm) * rr * wv.z + lv.z;
        av.w = (av.w - rm) * rr * wv.w + lv.w;
        __syncthreads();
        As[ak + 0][ar] = av.x; As[ak + 1][ar] = av.y; As[ak + 2][ar] = av.z; As[ak + 3][ar] = av.w;
        *(float4*)&Bs[bk][bn] = bv;
        __syncthreads();
#pragma unroll
        for (int k = 0; k < 8; ++k) {
            float am[8], bm[8];
            *(float4*)&am[0] = *(float4*)&As[k][tm * 4];
            *(float4*)&am[4] = *(float4*)&As[k][64 + tm * 4];
            *(float4*)&bm[0] = *(float4*)&Bs[k][tn * 4];
            *(float4*)&bm[4] = *(float4*)&Bs[k][64 + tn * 4];
#pragma unroll
            for (int i = 0; i < 8; ++i)
#pragma unroll
                for (int j = 0; j < 8; ++j) acc[i][j] = fmaf(am[i], bm[j], acc[i][j]);
        }
    }
#pragma unroll
    for (int ih = 0; ih < 2; ++ih)
#pragma unroll
        for (int i = 0; i < 4; ++i) {
            int mrow = m0 + ih * 64 + tm * 4 + i;
#pragma unroll
            for (int jh = 0; jh < 2; ++jh) {
                int n = n0 + jh * 64 + tn * 4;
                if (n >= N) continue;
                float v0 = acc[ih * 4 + i][jh * 4 + 0];
                float v1 = acc[ih * 4 + i][jh * 4 + 1];
                float v2 = acc[ih * 4 + i][jh * 4 + 2];
                float v3 = acc[ih * 4 + i][jh * 4 + 3];
                if (n < DINN) {
                    ushort4 u;
                    u.x = f2b(v0); u.y = f2b(v1); u.z = f2b(v2); u.w = f2b(v3);
                    *(ushort4*)(Z + (size_t)mrow * DINN + n) = u;
                } else if (n < DINN + CONVD) {
                    ushort4 u;
                    u.x = f2b(v0); u.y = f2b(v1); u.z = f2b(v2); u.w = f2b(v3);
                    *(ushort4*)(XBC + (size_t)mrow * CONVD + (n - DINN)) = u;
                } else {
                    *(float4*)(DTRAW + (size_t)mrow * NHH + (n - DINN - CONVD)) =
                        make_float4(v0, v1, v2, v3);
                }
            }
        }
}

// ---------------- out_proj GEMM: X += Ybf16[18432x1024] @ Wo[1024x512] ----------------
__global__ __launch_bounds__(256) void gemm_outproj(
        const unsigned short* __restrict__ A, const float* __restrict__ B,
        float* __restrict__ C) {
    const int N = DIMM, K = DINN;
    __shared__ float As[8][128];
    __shared__ float Bs[8][128];
    const int tid = threadIdx.x;
    const int m0 = blockIdx.y * 128, n0 = blockIdx.x * 128;
    const int tm = tid >> 4, tn = tid & 15;
    const int ar = tid >> 1, ak = (tid & 1) * 4;
    const int bk = tid >> 5, bn = (tid & 31) * 4;

    float acc[8][8];
#pragma unroll
    for (int i = 0; i < 8; ++i)
#pragma unroll
        for (int j = 0; j < 8; ++j) acc[i][j] = 0.f;

    const unsigned short* Ap = A + (size_t)(m0 + ar) * K + ak;
    const float* Bp = B + (size_t)bk * N + n0 + bn;

    for (int k0 = 0; k0 < K; k0 += 8) {
        ushort4 au = *(const ushort4*)(Ap + k0);
        float4 bv = *(const float4*)(Bp + (size_t)k0 * N);
        __syncthreads();
        As[ak + 0][ar] = b2f(au.x); As[ak + 1][ar] = b2f(au.y);
        As[ak + 2][ar] = b2f(au.z); As[ak + 3][ar] = b2f(au.w);
        *(float4*)&Bs[bk][bn] = bv;
        __syncthreads();
#pragma unroll
        for (int k = 0; k < 8; ++k) {
            float am[8], bm[8];
            *(float4*)&am[0] = *(float4*)&As[k][tm * 4];
            *(float4*)&am[4] = *(float4*)&As[k][64 + tm * 4];
            *(float4*)&bm[0] = *(float4*)&Bs[k][tn * 4];
            *(float4*)&bm[4] = *(float4*)&Bs[k][64 + tn * 4];
#pragma unroll
            for (int i = 0; i < 8; ++i)
#pragma unroll
                for (int j = 0; j < 8; ++j) acc[i][j] = fmaf(am[i], bm[j], acc[i][j]);
        }
    }
#pragma unroll
    for (int ih = 0; ih < 2; ++ih)
#pragma unroll
        for (int i = 0; i < 4; ++i) {
            int mrow = m0 + ih * 64 + tm * 4 + i;
#pragma unroll
            for (int jh = 0; jh < 2; ++jh) {
                int n = n0 + jh * 64 + tn * 4;
                float* p = C + (size_t)mrow * N + n;
                float4 o = *(const float4*)p;
                o.x += acc[ih * 4 + i][jh * 4 + 0];
                o.y += acc[ih * 4 + i][jh * 4 + 1];
                o.z += acc[ih * 4 + i][jh * 4 + 2];
                o.w += acc[ih * 4 + i][jh * 4 + 3];
                *(float4*)p = o;
            }
        }
}

// ---------------- Causal depthwise conv + silu + rope split (XBC bf16 in) ----------------
__global__ __launch_bounds__(256) void conv_kernel(
        const unsigned short* __restrict__ XBC, const float* __restrict__ cw,
        const float* __restrict__ cb,
        const float* __restrict__ Bb, const float* __restrict__ Cb,
        const float* __restrict__ COS, const float* __restrict__ SIN,
        unsigned short* __restrict__ XS, float* __restrict__ BM, float* __restrict__ CM) {
    int c = blockIdx.y * 256 + threadIdx.x;
    if (c >= CONVD) return;
    int bl = blockIdx.x;
    int l = bl % L_TOK;
    float w0 = cw[c * 4 + 0], w1 = cw[c * 4 + 1], w2 = cw[c * 4 + 2], w3 = cw[c * 4 + 3];
    const unsigned short* col = XBC + (size_t)bl * CONVD + c;
    float acc = w3 * b2f(col[0]);
    if (l >= 1) acc += w2 * b2f(col[-(ptrdiff_t)CONVD]);
    if (l >= 2) acc += w1 * b2f(col[-(ptrdiff_t)(2 * CONVD)]);
    if (l >= 3) acc += w0 * b2f(col[-(ptrdiff_t)(3 * CONVD)]);
    float v = acc + cb[c];
    v = v / (1.f + expf(-v));   // silu
    if (c < DINN) {
        XS[(size_t)bl * DINN + c] = f2b(v);
    } else {
        int j = c - DINN;         // 0..63 within first wave of blockIdx.y==4
        int jj = j & 31;
        float bias = (j < 32) ? Bb[jj] : Cb[jj];
        float v2 = v + bias;
        float partner = __shfl_xor(v2, 8);
        float outv;
        if (jj < 16) {
            int i = jj & 7;
            float cs = COS[l * 8 + i], sn = SIN[l * 8 + i];
            outv = (jj < 8) ? (v2 * cs - partner * sn) : (partner * sn + v2 * cs);
        } else {
            outv = v2;
        }
        if (j < 32) BM[(size_t)bl * NSTT + jj] = outv;
        else        CM[(size_t)bl * NSTT + jj] = outv;
    }
}

// ---------------- dt = softplus(raw + bias), dec = exp(-exp(Alog)*dt) ----------------
__global__ void dtdec_kernel(const float* __restrict__ DTRAW, const float* __restrict__ dtb,
                             const float* __restrict__ Alog,
                             float* __restrict__ DT, float* __restrict__ DEC) {
    int idx = blockIdx.x * 256 + threadIdx.x;
    if (idx >= ROWS * NHH) return;
    int h = idx & 15;
    float v = DTRAW[idx] + dtb[h];
    float dt = fmaxf(v, 0.f) + log1pf(expf(-fabsf(v)));
    DT[idx] = dt;
    DEC[idx] = expf(-expf(Alog[h]) * dt);
}

// ---------------- SSM scan: one wave per (b,h), state[32] in VGPRs, in-place XS->Y ----------------
__global__ __launch_bounds__(64) void scan_kernel(
        unsigned short* __restrict__ XSY,
        const float* __restrict__ DT, const float* __restrict__ DEC,
        const float* __restrict__ BM, const float* __restrict__ CM,
        const float* __restrict__ Dsk) {
    int bh = blockIdx.x;
    int b = bh >> 4, h = bh & 15;
    int p = threadIdx.x;
    float s[32];
#pragma unroll
    for (int n = 0; n < 32; ++n) s[n] = 0.f;
    float dsk = Dsk[h];
    size_t xbase = (size_t)b * L_TOK * DINN + h * HDD + p;
    size_t dbase = (size_t)b * L_TOK * NHH + h;
    size_t bcbase = (size_t)b * L_TOK * NSTT + (p & 31);
    for (int t = 0; t < L_TOK; ++t) {
        float a = DEC[dbase + (size_t)t * NHH];
        float d = DT[dbase + (size_t)t * NHH];
        float xv = b2f(XSY[xbase + (size_t)t * DINN]);
        float Bv = BM[bcbase + (size_t)t * NSTT];
        float Cv = CM[bcbase + (size_t)t * NSTT];
        float dx = d * xv;
        float y = 0.f;
#pragma unroll
        for (int n = 0; n < 32; ++n) {
            float Bn = __shfl(Bv, n);
            float Cn = __shfl(Cv, n);
            s[n] = fmaf(a, s[n], dx * Bn);
            y = fmaf(s[n], Cn, y);
        }
        XSY[xbase + (size_t)t * DINN] = f2b(y + dsk * xv);
    }
}

// ---------------- gate with silu(z) + RMSNorm(1024) * gn_w, in-place on Y (bf16) ----------------
__global__ __launch_bounds__(256) void rmsgate_kernel(
        unsigned short* __restrict__ Y, const unsigned short* __restrict__ Z,
        const float* __restrict__ gw) {
    int row = blockIdx.x * 4 + (threadIdx.x >> 6);
    int lane = threadIdx.x & 63;
    unsigned short* yr = Y + (size_t)row * DINN + lane * 16;
    const unsigned short* zr = Z + (size_t)row * DINN + lane * 16;
    float g[16];
    float q = 0.f;
#pragma unroll
    for (int i = 0; i < 16; ++i) {
        float yv = b2f(yr[i]);
        float zv = b2f(zr[i]);
        float gz = zv / (1.f + expf(-zv));
        g[i] = yv * gz;
        q += g[i] * g[i];
    }
#pragma unroll
    for (int o = 32; o > 0; o >>= 1) q += __shfl_xor(q, o);
    float sc = rsqrtf(q * (1.f / DINN) + 1e-6f);
#pragma unroll
    for (int i = 0; i < 16; ++i) {
        float wv = gw[lane * 16 + i];
        yr[i] = f2b(g[i] * sc * wv);
    }
}

// ---------------- final fused LN + mean over L ----------------
__global__ void lnmean_kernel(const float* __restrict__ X, const float* __restrict__ RS,
                              const float* __restrict__ nw, const float* __restrict__ nb,
                              float* __restrict__ MEAN) {
    int b = blockIdx.x >> 1;
    int d = (blockIdx.x & 1) * 256 + threadIdx.x;
    float w = nw[d], bb = nb[d];
    const float* p = X + (size_t)b * L_TOK * DIMM + d;
    const float* rs = RS + (size_t)b * L_TOK * 2;
    float s = 0.f;
    for (int l = 0; l < L_TOK; ++l) {
        float m = rs[l * 2 + 0], r = rs[l * 2 + 1];
        s += (p[(size_t)l * DIMM] - m) * r * w + bb;
    }
    MEAN[b * DIMM + d] = s * (1.f / L_TOK);
}

// ---------------- head: 32x512 @ 512x2 ----------------
__global__ void head_kernel(const float* __restrict__ MEAN, const float* __restrict__ hw,
                            const float* __restrict__ hb, float* __restrict__ out) {
    int t = threadIdx.x;
    if (t >= 64) return;
    int b = t >> 1, c = t & 1;
    float s = 0.f;
    for (int k = 0; k < DIMM; ++k) s += MEAN[b * DIMM + k] * hw[k * 2 + c];
    out[b * 2 + c] = s + hb[c];
}

extern "C" void kernel_launch(void* const* d_in, const int* in_sizes, int n_in,
                              void* d_out, int out_size, void* d_ws, size_t ws_size,
                              hipStream_t stream) {
    const float* x_img   = (const float*)d_in[0];
    const float* patch_w = (const float*)d_in[1];
    const float* patch_b = (const float*)d_in[2];
    const float* pos     = (const float*)d_in[3];
    const float* ln_w    = (const float*)d_in[4];
    const float* ln_b    = (const float*)d_in[5];
    const float* Wp      = (const float*)d_in[6];
    const float* cw      = (const float*)d_in[7];
    const float* cb      = (const float*)d_in[8];
    const float* dtb     = (const float*)d_in[9];
    const float* Alog    = (const float*)d_in[10];
    const float* Dsk     = (const float*)d_in[11];
    const float* Bb      = (const float*)d_in[12];
    const float* Cb      = (const float*)d_in[13];
    const float* gnw     = (const float*)d_in[14];
    const float* Wo      = (const float*)d_in[15];
    const float* nw      = (const float*)d_in[16];
    const float* nb      = (const float*)d_in[17];
    const float* hw      = (const float*)d_in[18];
    const float* hb      = (const float*)d_in[19];
    float* out = (float*)d_out;

    // ---- workspace carve (bytes, 256B-aligned chunks) ----
    char* base = (char*)d_ws;
    size_t off = 0;
    auto alloc = [&](size_t bytes) -> char* {
        char* p = base + off;
        off += (bytes + 255) & ~(size_t)255;
        return p;
    };
    float*          X     = (float*)alloc((size_t)ROWS * DIMM * 4);     // 37.75 MB
    unsigned short* XBC   = (unsigned short*)alloc((size_t)ROWS * CONVD * 2); // 40.1 MB
    unsigned short* Z     = (unsigned short*)alloc((size_t)ROWS * DINN * 2);  // 37.75 MB
    unsigned short* XSY   = (unsigned short*)alloc((size_t)ROWS * DINN * 2);  // 37.75 MB
    float*          DTRAW = (float*)alloc((size_t)ROWS * NHH * 4);
    float*          DT    = (float*)alloc((size_t)ROWS * NHH * 4);
    float*          DEC   = (float*)alloc((size_t)ROWS * NHH * 4);
    float*          BMp   = (float*)alloc((size_t)ROWS * NSTT * 4);
    float*          CMp   = (float*)alloc((size_t)ROWS * NSTT * 4);
    float*          RS    = (float*)alloc((size_t)ROWS * 2 * 4);
    float*          COS   = (float*)alloc((size_t)L_TOK * 8 * 4);
    float*          SIN   = (float*)alloc((size_t)L_TOK * 8 * 4);
    float*          MEAN  = (float*)alloc((size_t)BATCHH * DIMM * 4);
    if (off > ws_size) return;  // workspace too small: clean failure, no OOB

    rope_init<<<18, 256, 0, stream>>>(COS, SIN);
    patch_kernel<<<dim3(4, 144), 256, 0, stream>>>(x_img, patch_w, patch_b, pos, X);

    for (int i = 0; i < 8; ++i) {
        rowstat_kernel<<<ROWS / 4, 256, 0, stream>>>(X, RS);
        gemm_inproj<<<dim3(17, 144), 256, 0, stream>>>(
            X, RS, ln_w + i * DIMM, ln_b + i * DIMM,
            Wp + (size_t)i * DIMM * DPROJJ, Z, XBC, DTRAW);
        conv_kernel<<<dim3(ROWS, 5), 256, 0, stream>>>(
            XBC, cw + (size_t)i * CONVD * 4, cb + (size_t)i * CONVD,
            Bb + i * NSTT, Cb + i * NSTT, COS, SIN, XSY, BMp, CMp);
        dtdec_kernel<<<(ROWS * NHH + 255) / 256, 256, 0, stream>>>(
            DTRAW, dtb + i * NHH, Alog + i * NHH, DT, DEC);
        scan_kernel<<<BATCHH * NHH, 64, 0, stream>>>(XSY, DT, DEC, BMp, CMp, Dsk + i * NHH);
        rmsgate_kernel<<<ROWS / 4, 256, 0, stream>>>(XSY, Z, gnw + (size_t)i * DINN);
        gemm_outproj<<<dim3(4, 144), 256, 0, stream>>>(XSY, Wo + (size_t)i * DINN * DIMM, X);
    }

    rowstat_kernel<<<ROWS / 4, 256, 0, stream>>>(X, RS);
    lnmean_kernel<<<64, 256, 0, stream>>>(X, RS, nw, nb, MEAN);
    head_kernel<<<1, 64, 0, stream>>>(MEAN, hw, hb, out);
}

// Round 3
// 6663.524 us; speedup vs baseline: 1.7430x; 1.7430x over previous
//
#include <hip/hip_runtime.h>
#include <cmath>

#define L_TOK 576
#define DIMM  512
#define DINN  1024
#define NHH   16
#define HDD   64
#define NSTT  32
#define CONVD 1088
#define DPROJJ 2128
#define BATCHH 32
#define ROWS  (BATCHH * L_TOK)   // 18432
#define NPAD  2176               // 2128 padded to 17*128

typedef unsigned int uint;
typedef __attribute__((ext_vector_type(8))) short bf16x8;
typedef __attribute__((ext_vector_type(4))) float f32x4;

__device__ __forceinline__ float b2f(unsigned short u) {
    union { uint i; float f; } v; v.i = ((uint)u) << 16; return v.f;
}
__device__ __forceinline__ unsigned short f2b(float x) {
    union { float f; uint i; } v; v.f = x;
    uint r = (v.i + 0x7FFFu + ((v.i >> 16) & 1u)) >> 16;
    return (unsigned short)r;
}

__device__ __forceinline__ void gload16(const unsigned short* g, unsigned short* lds) {
    __builtin_amdgcn_global_load_lds(
        (const __attribute__((address_space(1))) unsigned int*)g,
        (__attribute__((address_space(3))) unsigned int*)lds, 16, 0, 0);
}

// ---------------- RoPE tables ----------------
__global__ void rope_init(float* __restrict__ COS, float* __restrict__ SIN) {
    int i = blockIdx.x * 256 + threadIdx.x;   // L_TOK*8 = 4608
    if (i >= L_TOK * 8) return;
    int l = i >> 3, j = i & 7;
    double inv = pow(10000.0, -(double)(2 * j) / 16.0);
    double a = (double)l * inv;
    COS[i] = (float)cos(a);
    SIN[i] = (float)sin(a);
}

// ---------------- transpose + pad + bf16 convert: src[l][R][C] f32 -> dst[l][Cp][R] bf16 ----------------
__global__ __launch_bounds__(256) void transpose_pad(
        const float* __restrict__ src, unsigned short* __restrict__ dst,
        int R, int C, int Cp) {
    __shared__ float tile[32][33];
    int lz = blockIdx.z;
    const float* S = src + (size_t)lz * R * C;
    unsigned short* D = dst + (size_t)lz * Cp * R;
    int c0 = blockIdx.x * 32, r0 = blockIdx.y * 32;
    int tx = threadIdx.x & 31, ty = threadIdx.x >> 5;   // 32 x 8
#pragma unroll
    for (int i = 0; i < 32; i += 8) {
        int c = c0 + tx;
        tile[ty + i][tx] = (c < C) ? S[(size_t)(r0 + ty + i) * C + c] : 0.f;
    }
    __syncthreads();
#pragma unroll
    for (int i = 0; i < 32; i += 8) {
        int cc = c0 + ty + i;     // dst row (= src col, padded)
        int rr = r0 + tx;         // dst col (= src row)
        if (cc < Cp) D[(size_t)cc * R + rr] = f2b(tile[tx][ty + i]);
    }
}

// ---------------- Patch embed: im2col GEMM 18432x768 @ 768x512 (fp32) ----------------
__global__ __launch_bounds__(256) void patch_kernel(
        const float* __restrict__ img, const float* __restrict__ pw,
        const float* __restrict__ pb, const float* __restrict__ pos,
        float* __restrict__ X) {
    __shared__ float As[8][128];
    __shared__ float Bs[8][128];
    const int tid = threadIdx.x;
    const int m0 = blockIdx.y * 128, n0 = blockIdx.x * 128;
    const int tm = tid >> 4, tn = tid & 15;
    const int ar = tid >> 1, ak = (tid & 1) * 4;

    int m = m0 + ar;
    int b = m / L_TOK, l = m % L_TOK;
    int oy = l / 24, ox = l % 24;
    const float* base = img + (size_t)b * 3 * 384 * 384 + (size_t)oy * 16 * 384 + ox * 16;

    const int nr = tid >> 1, nk = (tid & 1) * 4;
    const float* Bp = pw + (size_t)(n0 + nr) * 768 + nk;

    float acc[8][8];
#pragma unroll
    for (int i = 0; i < 8; ++i)
#pragma unroll
        for (int j = 0; j < 8; ++j) acc[i][j] = 0.f;

    for (int k0 = 0; k0 < 768; k0 += 8) {
        int kg = k0 + ak;
        int c = kg >> 8, rem = kg & 255, iy = rem >> 4, ix = rem & 15;
        float4 av = *(const float4*)(base + (size_t)c * 147456 + iy * 384 + ix);
        float4 bv = *(const float4*)(Bp + k0);
        __syncthreads();
        As[ak + 0][ar] = av.x; As[ak + 1][ar] = av.y; As[ak + 2][ar] = av.z; As[ak + 3][ar] = av.w;
        Bs[nk + 0][nr] = bv.x; Bs[nk + 1][nr] = bv.y; Bs[nk + 2][nr] = bv.z; Bs[nk + 3][nr] = bv.w;
        __syncthreads();
#pragma unroll
        for (int k = 0; k < 8; ++k) {
            float am[8], bm[8];
            *(float4*)&am[0] = *(float4*)&As[k][tm * 4];
            *(float4*)&am[4] = *(float4*)&As[k][64 + tm * 4];
            *(float4*)&bm[0] = *(float4*)&Bs[k][tn * 4];
            *(float4*)&bm[4] = *(float4*)&Bs[k][64 + tn * 4];
#pragma unroll
            for (int i = 0; i < 8; ++i)
#pragma unroll
                for (int j = 0; j < 8; ++j) acc[i][j] = fmaf(am[i], bm[j], acc[i][j]);
        }
    }
#pragma unroll
    for (int ih = 0; ih < 2; ++ih)
#pragma unroll
        for (int i = 0; i < 4; ++i) {
            int mm = m0 + ih * 64 + tm * 4 + i;
            int ll = mm % L_TOK;
#pragma unroll
            for (int jh = 0; jh < 2; ++jh) {
                int n = n0 + jh * 64 + tn * 4;
                float4 v = make_float4(acc[ih * 4 + i][jh * 4 + 0], acc[ih * 4 + i][jh * 4 + 1],
                                       acc[ih * 4 + i][jh * 4 + 2], acc[ih * 4 + i][jh * 4 + 3]);
                v.x += pb[n + 0] + pos[(size_t)ll * DIMM + n + 0];
                v.y += pb[n + 1] + pos[(size_t)ll * DIMM + n + 1];
                v.z += pb[n + 2] + pos[(size_t)ll * DIMM + n + 2];
                v.w += pb[n + 3] + pos[(size_t)ll * DIMM + n + 3];
                *(float4*)(X + (size_t)mm * DIMM + n) = v;
            }
        }
}

// ---------------- fused LN -> bf16 rows of 512 ----------------
__global__ __launch_bounds__(256) void lnbf16_kernel(
        const float* __restrict__ X, const float* __restrict__ w,
        const float* __restrict__ bi, unsigned short* __restrict__ Hb) {
    int row = blockIdx.x * 4 + (threadIdx.x >> 6);
    int lane = threadIdx.x & 63;
    const float* xr = X + (size_t)row * DIMM;
    float4 u0 = *(const float4*)(xr + lane * 8);
    float4 u1 = *(const float4*)(xr + lane * 8 + 4);
    float v[8] = {u0.x, u0.y, u0.z, u0.w, u1.x, u1.y, u1.z, u1.w};
    float s = 0.f;
#pragma unroll
    for (int j = 0; j < 8; ++j) s += v[j];
#pragma unroll
    for (int o = 32; o > 0; o >>= 1) s += __shfl_xor(s, o);
    float m = s * (1.f / DIMM);
    float q = 0.f;
#pragma unroll
    for (int j = 0; j < 8; ++j) { float d = v[j] - m; q += d * d; }
#pragma unroll
    for (int o = 32; o > 0; o >>= 1) q += __shfl_xor(q, o);
    float rstd = rsqrtf(q * (1.f / DIMM) + 1e-6f);
    float4 w0 = *(const float4*)(w + lane * 8);
    float4 w1 = *(const float4*)(w + lane * 8 + 4);
    float4 b0 = *(const float4*)(bi + lane * 8);
    float4 b1 = *(const float4*)(bi + lane * 8 + 4);
    float wv[8] = {w0.x, w0.y, w0.z, w0.w, w1.x, w1.y, w1.z, w1.w};
    float bv[8] = {b0.x, b0.y, b0.z, b0.w, b1.x, b1.y, b1.z, b1.w};
    ushort4 s0, s1;
    s0.x = f2b((v[0] - m) * rstd * wv[0] + bv[0]);
    s0.y = f2b((v[1] - m) * rstd * wv[1] + bv[1]);
    s0.z = f2b((v[2] - m) * rstd * wv[2] + bv[2]);
    s0.w = f2b((v[3] - m) * rstd * wv[3] + bv[3]);
    s1.x = f2b((v[4] - m) * rstd * wv[4] + bv[4]);
    s1.y = f2b((v[5] - m) * rstd * wv[5] + bv[5]);
    s1.z = f2b((v[6] - m) * rstd * wv[6] + bv[6]);
    s1.w = f2b((v[7] - m) * rstd * wv[7] + bv[7]);
    unsigned short* orow = Hb + (size_t)row * DIMM + lane * 8;
    *(ushort4*)(orow) = s0;
    *(ushort4*)(orow + 4) = s1;
}

// ---------------- per-row mean/rstd of X (final LN) ----------------
__global__ __launch_bounds__(256) void rowstat_kernel(
        const float* __restrict__ X, float* __restrict__ RS) {
    int row = blockIdx.x * 4 + (threadIdx.x >> 6);
    int lane = threadIdx.x & 63;
    const float* xr = X + (size_t)row * DIMM;
    float4 u0 = *(const float4*)(xr + lane * 8);
    float4 u1 = *(const float4*)(xr + lane * 8 + 4);
    float v[8] = {u0.x, u0.y, u0.z, u0.w, u1.x, u1.y, u1.z, u1.w};
    float s = 0.f;
#pragma unroll
    for (int j = 0; j < 8; ++j) s += v[j];
#pragma unroll
    for (int o = 32; o > 0; o >>= 1) s += __shfl_xor(s, o);
    float m = s * (1.f / DIMM);
    float q = 0.f;
#pragma unroll
    for (int j = 0; j < 8; ++j) { float d = v[j] - m; q += d * d; }
#pragma unroll
    for (int o = 32; o > 0; o >>= 1) q += __shfl_xor(q, o);
    float rstd = rsqrtf(q * (1.f / DIMM) + 1e-6f);
    if (lane == 0) {
        RS[row * 2 + 0] = m;
        RS[row * 2 + 1] = rstd;
    }
}

// ---------------- MFMA GEMM: in_proj  Hb[18432x512]bf16 @ WpT[2176x512]^T ----------------
// tile 128x128, BK=64, 4 waves (2x2), 16x16x32 bf16 MFMA, st-swizzled LDS
__global__ __launch_bounds__(256) void gemm_in_mfma(
        const unsigned short* __restrict__ A,   // [ROWS][512]
        const unsigned short* __restrict__ Bt,  // [NPAD][512]
        unsigned short* __restrict__ Z, unsigned short* __restrict__ XBC,
        float* __restrict__ DTRAW) {
    __shared__ unsigned short As[128 * 64];
    __shared__ unsigned short Bs[128 * 64];
    const int tid = threadIdx.x;
    const int l = tid & 63, w = tid >> 6;
    const int wr = w >> 1, wc = w & 1;
    const int m0 = blockIdx.y * 128, n0 = blockIdx.x * 128;
    f32x4 acc[4][4];
#pragma unroll
    for (int i = 0; i < 4; ++i)
#pragma unroll
        for (int j = 0; j < 4; ++j) acc[i][j] = (f32x4)(0.f);

    int rA[4], rB[4];
#pragma unroll
    for (int f = 0; f < 4; ++f) {
        rA[f] = wr * 64 + f * 16 + (l & 15);
        rB[f] = wc * 64 + f * 16 + (l & 15);
    }
    const char* AsB = (const char*)As;
    const char* BsB = (const char*)Bs;

    for (int k0 = 0; k0 < 512; k0 += 64) {
        __syncthreads();
#pragma unroll
        for (int i = 0; i < 4; ++i) {
            int lin = i * 256 + tid;
            int r = lin >> 3, slot = lin & 7;
            int sc = (slot ^ (r & 7)) * 8;
            gload16(A  + (size_t)(m0 + r) * 512 + k0 + sc, As + lin * 8);
            gload16(Bt + (size_t)(n0 + r) * 512 + k0 + sc, Bs + lin * 8);
        }
        __syncthreads();
#pragma unroll
        for (int kk = 0; kk < 2; ++kk) {
            bf16x8 af[4], bfr[4];
            int c16 = kk * 4 + (l >> 4);
#pragma unroll
            for (int f = 0; f < 4; ++f) {
                int row = rA[f];
                af[f] = *(const bf16x8*)(AsB + row * 128 + ((c16 ^ (row & 7)) << 4));
            }
#pragma unroll
            for (int f = 0; f < 4; ++f) {
                int row = rB[f];
                bfr[f] = *(const bf16x8*)(BsB + row * 128 + ((c16 ^ (row & 7)) << 4));
            }
#pragma unroll
            for (int mf = 0; mf < 4; ++mf)
#pragma unroll
                for (int nf = 0; nf < 4; ++nf)
                    acc[mf][nf] = __builtin_amdgcn_mfma_f32_16x16x32_bf16(
                        af[mf], bfr[nf], acc[mf][nf], 0, 0, 0);
        }
    }
#pragma unroll
    for (int mf = 0; mf < 4; ++mf)
#pragma unroll
        for (int nf = 0; nf < 4; ++nf) {
            int col = n0 + wc * 64 + nf * 16 + (l & 15);
#pragma unroll
            for (int reg = 0; reg < 4; ++reg) {
                int row = m0 + wr * 64 + mf * 16 + (l >> 4) * 4 + reg;
                float v = acc[mf][nf][reg];
                if (col < DINN)             Z[(size_t)row * DINN + col] = f2b(v);
                else if (col < DINN + CONVD) XBC[(size_t)row * CONVD + (col - DINN)] = f2b(v);
                else if (col < DPROJJ)       DTRAW[(size_t)row * NHH + (col - DINN - CONVD)] = v;
            }
        }
}

// ---------------- MFMA GEMM: out_proj  XSY[18432x1024]bf16 @ WoT[512x1024]^T, X += ----------------
__global__ __launch_bounds__(256) void gemm_out_mfma(
        const unsigned short* __restrict__ A,   // [ROWS][1024]
        const unsigned short* __restrict__ Bt,  // [512][1024]
        float* __restrict__ X) {
    __shared__ unsigned short As[128 * 64];
    __shared__ unsigned short Bs[128 * 64];
    const int tid = threadIdx.x;
    const int l = tid & 63, w = tid >> 6;
    const int wr = w >> 1, wc = w & 1;
    const int m0 = blockIdx.y * 128, n0 = blockIdx.x * 128;
    f32x4 acc[4][4];
#pragma unroll
    for (int i = 0; i < 4; ++i)
#pragma unroll
        for (int j = 0; j < 4; ++j) acc[i][j] = (f32x4)(0.f);

    int rA[4], rB[4];
#pragma unroll
    for (int f = 0; f < 4; ++f) {
        rA[f] = wr * 64 + f * 16 + (l & 15);
        rB[f] = wc * 64 + f * 16 + (l & 15);
    }
    const char* AsB = (const char*)As;
    const char* BsB = (const char*)Bs;

    for (int k0 = 0; k0 < 1024; k0 += 64) {
        __syncthreads();
#pragma unroll
        for (int i = 0; i < 4; ++i) {
            int lin = i * 256 + tid;
            int r = lin >> 3, slot = lin & 7;
            int sc = (slot ^ (r & 7)) * 8;
            gload16(A  + (size_t)(m0 + r) * 1024 + k0 + sc, As + lin * 8);
            gload16(Bt + (size_t)(n0 + r) * 1024 + k0 + sc, Bs + lin * 8);
        }
        __syncthreads();
#pragma unroll
        for (int kk = 0; kk < 2; ++kk) {
            bf16x8 af[4], bfr[4];
            int c16 = kk * 4 + (l >> 4);
#pragma unroll
            for (int f = 0; f < 4; ++f) {
                int row = rA[f];
                af[f] = *(const bf16x8*)(AsB + row * 128 + ((c16 ^ (row & 7)) << 4));
            }
#pragma unroll
            for (int f = 0; f < 4; ++f) {
                int row = rB[f];
                bfr[f] = *(const bf16x8*)(BsB + row * 128 + ((c16 ^ (row & 7)) << 4));
            }
#pragma unroll
            for (int mf = 0; mf < 4; ++mf)
#pragma unroll
                for (int nf = 0; nf < 4; ++nf)
                    acc[mf][nf] = __builtin_amdgcn_mfma_f32_16x16x32_bf16(
                        af[mf], bfr[nf], acc[mf][nf], 0, 0, 0);
        }
    }
#pragma unroll
    for (int mf = 0; mf < 4; ++mf)
#pragma unroll
        for (int nf = 0; nf < 4; ++nf) {
            int col = n0 + wc * 64 + nf * 16 + (l & 15);
#pragma unroll
            for (int reg = 0; reg < 4; ++reg) {
                int row = m0 + wr * 64 + mf * 16 + (l >> 4) * 4 + reg;
                float* p = X + (size_t)row * DIMM + col;
                *p += acc[mf][nf][reg];
            }
        }
}

// ---------------- Causal depthwise conv + silu + rope split (XBC bf16 in) ----------------
__global__ __launch_bounds__(256) void conv_kernel(
        const unsigned short* __restrict__ XBC, const float* __restrict__ cw,
        const float* __restrict__ cb,
        const float* __restrict__ Bb, const float* __restrict__ Cb,
        const float* __restrict__ COS, const float* __restrict__ SIN,
        unsigned short* __restrict__ XS, float* __restrict__ BM, float* __restrict__ CM) {
    int c = blockIdx.y * 256 + threadIdx.x;
    if (c >= CONVD) return;
    int bl = blockIdx.x;
    int l = bl % L_TOK;
    float w0 = cw[c * 4 + 0], w1 = cw[c * 4 + 1], w2 = cw[c * 4 + 2], w3 = cw[c * 4 + 3];
    const unsigned short* col = XBC + (size_t)bl * CONVD + c;
    float acc = w3 * b2f(col[0]);
    if (l >= 1) acc += w2 * b2f(col[-(ptrdiff_t)CONVD]);
    if (l >= 2) acc += w1 * b2f(col[-(ptrdiff_t)(2 * CONVD)]);
    if (l >= 3) acc += w0 * b2f(col[-(ptrdiff_t)(3 * CONVD)]);
    float v = acc + cb[c];
    v = v / (1.f + expf(-v));   // silu
    if (c < DINN) {
        XS[(size_t)bl * DINN + c] = f2b(v);
    } else {
        int j = c - DINN;         // 0..63, single wave
        int jj = j & 31;
        float bias = (j < 32) ? Bb[jj] : Cb[jj];
        float v2 = v + bias;
        float partner = __shfl_xor(v2, 8);
        float outv;
        if (jj < 16) {
            int i = jj & 7;
            float cs = COS[l * 8 + i], sn = SIN[l * 8 + i];
            outv = (jj < 8) ? (v2 * cs - partner * sn) : (partner * sn + v2 * cs);
        } else {
            outv = v2;
        }
        if (j < 32) BM[(size_t)bl * NSTT + jj] = outv;
        else        CM[(size_t)bl * NSTT + jj] = outv;
    }
}

// ---------------- dt = softplus(raw + bias), dec = exp(-exp(Alog)*dt) ----------------
__global__ void dtdec_kernel(const float* __restrict__ DTRAW, const float* __restrict__ dtb,
                             const float* __restrict__ Alog,
                             float* __restrict__ DT, float* __restrict__ DEC) {
    int idx = blockIdx.x * 256 + threadIdx.x;
    if (idx >= ROWS * NHH) return;
    int h = idx & 15;
    float v = DTRAW[idx] + dtb[h];
    float dt = fmaxf(v, 0.f) + log1pf(expf(-fabsf(v)));
    DT[idx] = dt;
    DEC[idx] = expf(-expf(Alog[h]) * dt);
}

// ---------------- SSM scan: one wave per (b,h), state[32] in VGPRs, in-place XS->Y ----------------
__global__ __launch_bounds__(64) void scan_kernel(
        unsigned short* __restrict__ XSY,
        const float* __restrict__ DT, const float* __restrict__ DEC,
        const float* __restrict__ BM, const float* __restrict__ CM,
        const float* __restrict__ Dsk) {
    int bh = blockIdx.x;
    int b = bh >> 4, h = bh & 15;
    int p = threadIdx.x;
    float s[32];
#pragma unroll
    for (int n = 0; n < 32; ++n) s[n] = 0.f;
    float dsk = Dsk[h];
    size_t xbase = (size_t)b * L_TOK * DINN + h * HDD + p;
    size_t dbase = (size_t)b * L_TOK * NHH + h;
    size_t bcbase = (size_t)b * L_TOK * NSTT + (p & 31);
    for (int t = 0; t < L_TOK; ++t) {
        float a = DEC[dbase + (size_t)t * NHH];
        float d = DT[dbase + (size_t)t * NHH];
        float xv = b2f(XSY[xbase + (size_t)t * DINN]);
        float Bv = BM[bcbase + (size_t)t * NSTT];
        float Cv = CM[bcbase + (size_t)t * NSTT];
        float dx = d * xv;
        float y = 0.f;
#pragma unroll
        for (int n = 0; n < 32; ++n) {
            float Bn = __shfl(Bv, n);
            float Cn = __shfl(Cv, n);
            s[n] = fmaf(a, s[n], dx * Bn);
            y = fmaf(s[n], Cn, y);
        }
        XSY[xbase + (size_t)t * DINN] = f2b(y + dsk * xv);
    }
}

// ---------------- gate with silu(z) + RMSNorm(1024) * gn_w, in-place on Y (bf16) ----------------
__global__ __launch_bounds__(256) void rmsgate_kernel(
        unsigned short* __restrict__ Y, const unsigned short* __restrict__ Z,
        const float* __restrict__ gw) {
    int row = blockIdx.x * 4 + (threadIdx.x >> 6);
    int lane = threadIdx.x & 63;
    unsigned short* yr = Y + (size_t)row * DINN + lane * 16;
    const unsigned short* zr = Z + (size_t)row * DINN + lane * 16;
    float g[16];
    float q = 0.f;
#pragma unroll
    for (int i = 0; i < 16; ++i) {
        float yv = b2f(yr[i]);
        float zv = b2f(zr[i]);
        float gz = zv / (1.f + expf(-zv));
        g[i] = yv * gz;
        q += g[i] * g[i];
    }
#pragma unroll
    for (int o = 32; o > 0; o >>= 1) q += __shfl_xor(q, o);
    float sc = rsqrtf(q * (1.f / DINN) + 1e-6f);
#pragma unroll
    for (int i = 0; i < 16; ++i) {
        float wv = gw[lane * 16 + i];
        yr[i] = f2b(g[i] * sc * wv);
    }
}

// ---------------- final fused LN + mean over L ----------------
__global__ void lnmean_kernel(const float* __restrict__ X, const float* __restrict__ RS,
                              const float* __restrict__ nw, const float* __restrict__ nb,
                              float* __restrict__ MEAN) {
    int b = blockIdx.x >> 1;
    int d = (blockIdx.x & 1) * 256 + threadIdx.x;
    float w = nw[d], bb = nb[d];
    const float* p = X + (size_t)b * L_TOK * DIMM + d;
    const float* rs = RS + (size_t)b * L_TOK * 2;
    float s = 0.f;
    for (int l = 0; l < L_TOK; ++l) {
        float m = rs[l * 2 + 0], r = rs[l * 2 + 1];
        s += (p[(size_t)l * DIMM] - m) * r * w + bb;
    }
    MEAN[b * DIMM + d] = s * (1.f / L_TOK);
}

// ---------------- head: 32x512 @ 512x2 ----------------
__global__ void head_kernel(const float* __restrict__ MEAN, const float* __restrict__ hw,
                            const float* __restrict__ hb, float* __restrict__ out) {
    int t = threadIdx.x;
    if (t >= 64) return;
    int b = t >> 1, c = t & 1;
    float s = 0.f;
    for (int k = 0; k < DIMM; ++k) s += MEAN[b * DIMM + k] * hw[k * 2 + c];
    out[b * 2 + c] = s + hb[c];
}

extern "C" void kernel_launch(void* const* d_in, const int* in_sizes, int n_in,
                              void* d_out, int out_size, void* d_ws, size_t ws_size,
                              hipStream_t stream) {
    const float* x_img   = (const float*)d_in[0];
    const float* patch_w = (const float*)d_in[1];
    const float* patch_b = (const float*)d_in[2];
    const float* pos     = (const float*)d_in[3];
    const float* ln_w    = (const float*)d_in[4];
    const float* ln_b    = (const float*)d_in[5];
    const float* Wp      = (const float*)d_in[6];
    const float* cw      = (const float*)d_in[7];
    const float* cb      = (const float*)d_in[8];
    const float* dtb     = (const float*)d_in[9];
    const float* Alog    = (const float*)d_in[10];
    const float* Dsk     = (const float*)d_in[11];
    const float* Bb      = (const float*)d_in[12];
    const float* Cb      = (const float*)d_in[13];
    const float* gnw     = (const float*)d_in[14];
    const float* Wo      = (const float*)d_in[15];
    const float* nw      = (const float*)d_in[16];
    const float* nb      = (const float*)d_in[17];
    const float* hw      = (const float*)d_in[18];
    const float* hb      = (const float*)d_in[19];
    float* out = (float*)d_out;

    // ---- workspace carve ----
    char* base = (char*)d_ws;
    size_t off = 0;
    auto alloc = [&](size_t bytes) -> char* {
        char* p = base + off;
        off += (bytes + 255) & ~(size_t)255;
        return p;
    };
    float*          X     = (float*)alloc((size_t)ROWS * DIMM * 4);           // 37.7 MB
    unsigned short* XBC   = (unsigned short*)alloc((size_t)ROWS * CONVD * 2); // 40.1 MB
    unsigned short* Z     = (unsigned short*)alloc((size_t)ROWS * DINN * 2);  // 37.7 MB
    unsigned short* XSY   = (unsigned short*)alloc((size_t)ROWS * DINN * 2);  // 37.7 MB
    unsigned short* Hb    = (unsigned short*)alloc((size_t)ROWS * DIMM * 2);  // 18.9 MB
    unsigned short* WpT   = (unsigned short*)alloc((size_t)8 * NPAD * DIMM * 2); // 17.8 MB
    unsigned short* WoT   = (unsigned short*)alloc((size_t)8 * DIMM * DINN * 2); //  8.4 MB
    float*          DTRAW = (float*)alloc((size_t)ROWS * NHH * 4);
    float*          DT    = (float*)alloc((size_t)ROWS * NHH * 4);
    float*          DEC   = (float*)alloc((size_t)ROWS * NHH * 4);
    float*          BMp   = (float*)alloc((size_t)ROWS * NSTT * 4);
    float*          CMp   = (float*)alloc((size_t)ROWS * NSTT * 4);
    float*          RS    = (float*)alloc((size_t)ROWS * 2 * 4);
    float*          COS   = (float*)alloc((size_t)L_TOK * 8 * 4);
    float*          SIN   = (float*)alloc((size_t)L_TOK * 8 * 4);
    float*          MEAN  = (float*)alloc((size_t)BATCHH * DIMM * 4);
    if (off > ws_size) return;  // workspace too small: clean failure, no OOB

    rope_init<<<18, 256, 0, stream>>>(COS, SIN);
    // Wp [8][512][2128] -> WpT [8][2176][512]
    transpose_pad<<<dim3(NPAD / 32, DIMM / 32, 8), 256, 0, stream>>>(Wp, WpT, DIMM, DPROJJ, NPAD);
    // Wo [8][1024][512] -> WoT [8][512][1024]
    transpose_pad<<<dim3(DIMM / 32, DINN / 32, 8), 256, 0, stream>>>(Wo, WoT, DINN, DIMM, DIMM);
    patch_kernel<<<dim3(4, 144), 256, 0, stream>>>(x_img, patch_w, patch_b, pos, X);

    for (int i = 0; i < 8; ++i) {
        lnbf16_kernel<<<ROWS / 4, 256, 0, stream>>>(X, ln_w + i * DIMM, ln_b + i * DIMM, Hb);
        gemm_in_mfma<<<dim3(NPAD / 128, ROWS / 128), 256, 0, stream>>>(
            Hb, WpT + (size_t)i * NPAD * DIMM, Z, XBC, DTRAW);
        conv_kernel<<<dim3(ROWS, 5), 256, 0, stream>>>(
            XBC, cw + (size_t)i * CONVD * 4, cb + (size_t)i * CONVD,
            Bb + i * NSTT, Cb + i * NSTT, COS, SIN, XSY, BMp, CMp);
        dtdec_kernel<<<(ROWS * NHH + 255) / 256, 256, 0, stream>>>(
            DTRAW, dtb + i * NHH, Alog + i * NHH, DT, DEC);
        scan_kernel<<<BATCHH * NHH, 64, 0, stream>>>(XSY, DT, DEC, BMp, CMp, Dsk + i * NHH);
        rmsgate_kernel<<<ROWS / 4, 256, 0, stream>>>(XSY, Z, gnw + (size_t)i * DINN);
        gemm_out_mfma<<<dim3(DIMM / 128, ROWS / 128), 256, 0, stream>>>(
            XSY, WoT + (size_t)i * DIMM * DINN, X);
    }

    rowstat_kernel<<<ROWS / 4, 256, 0, stream>>>(X, RS);
    lnmean_kernel<<<64, 256, 0, stream>>>(X, RS, nw, nb, MEAN);
    head_kernel<<<1, 64, 0, stream>>>(MEAN, hw, hb, out);
}

// Round 4
// 4398.207 us; speedup vs baseline: 2.6408x; 1.5151x over previous
//
#include <hip/hip_runtime.h>
#include <cmath>

#define L_TOK 576
#define DIMM  512
#define DINN  1024
#define NHH   16
#define HDD   64
#define NSTT  32
#define CONVD 1088
#define DPROJJ 2128
#define BATCHH 32
#define ROWS  (BATCHH * L_TOK)   // 18432
#define NPAD  2176               // 2128 padded to 17*128
#define NCH   9                  // 576 / 64 chunks

typedef unsigned int uint;
typedef __attribute__((ext_vector_type(8))) short bf16x8;
typedef __attribute__((ext_vector_type(4))) float f32x4;

__device__ __forceinline__ float b2f(unsigned short u) {
    union { uint i; float f; } v; v.i = ((uint)u) << 16; return v.f;
}
__device__ __forceinline__ unsigned short f2b(float x) {
    union { float f; uint i; } v; v.f = x;
    uint r = (v.i + 0x7FFFu + ((v.i >> 16) & 1u)) >> 16;
    return (unsigned short)r;
}

__device__ __forceinline__ void gload16(const unsigned short* g, unsigned short* lds) {
    __builtin_amdgcn_global_load_lds(
        (const __attribute__((address_space(1))) unsigned int*)g,
        (__attribute__((address_space(3))) unsigned int*)lds, 16, 0, 0);
}

// ---------------- RoPE tables ----------------
__global__ void rope_init(float* __restrict__ COS, float* __restrict__ SIN) {
    int i = blockIdx.x * 256 + threadIdx.x;   // L_TOK*8 = 4608
    if (i >= L_TOK * 8) return;
    int l = i >> 3, j = i & 7;
    double inv = pow(10000.0, -(double)(2 * j) / 16.0);
    double a = (double)l * inv;
    COS[i] = (float)cos(a);
    SIN[i] = (float)sin(a);
}

// ---------------- transpose + pad + bf16 convert: src[l][R][C] f32 -> dst[l][Cp][R] bf16 ----------------
__global__ __launch_bounds__(256) void transpose_pad(
        const float* __restrict__ src, unsigned short* __restrict__ dst,
        int R, int C, int Cp) {
    __shared__ float tile[32][33];
    int lz = blockIdx.z;
    const float* S = src + (size_t)lz * R * C;
    unsigned short* D = dst + (size_t)lz * Cp * R;
    int c0 = blockIdx.x * 32, r0 = blockIdx.y * 32;
    int tx = threadIdx.x & 31, ty = threadIdx.x >> 5;   // 32 x 8
#pragma unroll
    for (int i = 0; i < 32; i += 8) {
        int c = c0 + tx;
        tile[ty + i][tx] = (c < C) ? S[(size_t)(r0 + ty + i) * C + c] : 0.f;
    }
    __syncthreads();
#pragma unroll
    for (int i = 0; i < 32; i += 8) {
        int cc = c0 + ty + i;     // dst row (= src col, padded)
        int rr = r0 + tx;         // dst col (= src row)
        if (cc < Cp) D[(size_t)cc * R + rr] = f2b(tile[tx][ty + i]);
    }
}

// ---------------- Patch embed: im2col GEMM 18432x768 @ 768x512 (fp32) ----------------
__global__ __launch_bounds__(256) void patch_kernel(
        const float* __restrict__ img, const float* __restrict__ pw,
        const float* __restrict__ pb, const float* __restrict__ pos,
        float* __restrict__ X) {
    __shared__ float As[8][128];
    __shared__ float Bs[8][128];
    const int tid = threadIdx.x;
    const int m0 = blockIdx.y * 128, n0 = blockIdx.x * 128;
    const int tm = tid >> 4, tn = tid & 15;
    const int ar = tid >> 1, ak = (tid & 1) * 4;

    int m = m0 + ar;
    int b = m / L_TOK, l = m % L_TOK;
    int oy = l / 24, ox = l % 24;
    const float* base = img + (size_t)b * 3 * 384 * 384 + (size_t)oy * 16 * 384 + ox * 16;

    const int nr = tid >> 1, nk = (tid & 1) * 4;
    const float* Bp = pw + (size_t)(n0 + nr) * 768 + nk;

    float acc[8][8];
#pragma unroll
    for (int i = 0; i < 8; ++i)
#pragma unroll
        for (int j = 0; j < 8; ++j) acc[i][j] = 0.f;

    for (int k0 = 0; k0 < 768; k0 += 8) {
        int kg = k0 + ak;
        int c = kg >> 8, rem = kg & 255, iy = rem >> 4, ix = rem & 15;
        float4 av = *(const float4*)(base + (size_t)c * 147456 + iy * 384 + ix);
        float4 bv = *(const float4*)(Bp + k0);
        __syncthreads();
        As[ak + 0][ar] = av.x; As[ak + 1][ar] = av.y; As[ak + 2][ar] = av.z; As[ak + 3][ar] = av.w;
        Bs[nk + 0][nr] = bv.x; Bs[nk + 1][nr] = bv.y; Bs[nk + 2][nr] = bv.z; Bs[nk + 3][nr] = bv.w;
        __syncthreads();
#pragma unroll
        for (int k = 0; k < 8; ++k) {
            float am[8], bm[8];
            *(float4*)&am[0] = *(float4*)&As[k][tm * 4];
            *(float4*)&am[4] = *(float4*)&As[k][64 + tm * 4];
            *(float4*)&bm[0] = *(float4*)&Bs[k][tn * 4];
            *(float4*)&bm[4] = *(float4*)&Bs[k][64 + tn * 4];
#pragma unroll
            for (int i = 0; i < 8; ++i)
#pragma unroll
                for (int j = 0; j < 8; ++j) acc[i][j] = fmaf(am[i], bm[j], acc[i][j]);
        }
    }
#pragma unroll
    for (int ih = 0; ih < 2; ++ih)
#pragma unroll
        for (int i = 0; i < 4; ++i) {
            int mm = m0 + ih * 64 + tm * 4 + i;
            int ll = mm % L_TOK;
#pragma unroll
            for (int jh = 0; jh < 2; ++jh) {
                int n = n0 + jh * 64 + tn * 4;
                float4 v = make_float4(acc[ih * 4 + i][jh * 4 + 0], acc[ih * 4 + i][jh * 4 + 1],
                                       acc[ih * 4 + i][jh * 4 + 2], acc[ih * 4 + i][jh * 4 + 3]);
                v.x += pb[n + 0] + pos[(size_t)ll * DIMM + n + 0];
                v.y += pb[n + 1] + pos[(size_t)ll * DIMM + n + 1];
                v.z += pb[n + 2] + pos[(size_t)ll * DIMM + n + 2];
                v.w += pb[n + 3] + pos[(size_t)ll * DIMM + n + 3];
                *(float4*)(X + (size_t)mm * DIMM + n) = v;
            }
        }
}

// ---------------- fused LN -> bf16 rows of 512 ----------------
__global__ __launch_bounds__(256) void lnbf16_kernel(
        const float* __restrict__ X, const float* __restrict__ w,
        const float* __restrict__ bi, unsigned short* __restrict__ Hb) {
    int row = blockIdx.x * 4 + (threadIdx.x >> 6);
    int lane = threadIdx.x & 63;
    const float* xr = X + (size_t)row * DIMM;
    float4 u0 = *(const float4*)(xr + lane * 8);
    float4 u1 = *(const float4*)(xr + lane * 8 + 4);
    float v[8] = {u0.x, u0.y, u0.z, u0.w, u1.x, u1.y, u1.z, u1.w};
    float s = 0.f;
#pragma unroll
    for (int j = 0; j < 8; ++j) s += v[j];
#pragma unroll
    for (int o = 32; o > 0; o >>= 1) s += __shfl_xor(s, o);
    float m = s * (1.f / DIMM);
    float q = 0.f;
#pragma unroll
    for (int j = 0; j < 8; ++j) { float d = v[j] - m; q += d * d; }
#pragma unroll
    for (int o = 32; o > 0; o >>= 1) q += __shfl_xor(q, o);
    float rstd = rsqrtf(q * (1.f / DIMM) + 1e-6f);
    float4 w0 = *(const float4*)(w + lane * 8);
    float4 w1 = *(const float4*)(w + lane * 8 + 4);
    float4 b0 = *(const float4*)(bi + lane * 8);
    float4 b1 = *(const float4*)(bi + lane * 8 + 4);
    float wv[8] = {w0.x, w0.y, w0.z, w0.w, w1.x, w1.y, w1.z, w1.w};
    float bv[8] = {b0.x, b0.y, b0.z, b0.w, b1.x, b1.y, b1.z, b1.w};
    ushort4 s0, s1;
    s0.x = f2b((v[0] - m) * rstd * wv[0] + bv[0]);
    s0.y = f2b((v[1] - m) * rstd * wv[1] + bv[1]);
    s0.z = f2b((v[2] - m) * rstd * wv[2] + bv[2]);
    s0.w = f2b((v[3] - m) * rstd * wv[3] + bv[3]);
    s1.x = f2b((v[4] - m) * rstd * wv[4] + bv[4]);
    s1.y = f2b((v[5] - m) * rstd * wv[5] + bv[5]);
    s1.z = f2b((v[6] - m) * rstd * wv[6] + bv[6]);
    s1.w = f2b((v[7] - m) * rstd * wv[7] + bv[7]);
    unsigned short* orow = Hb + (size_t)row * DIMM + lane * 8;
    *(ushort4*)(orow) = s0;
    *(ushort4*)(orow + 4) = s1;
}

// ---------------- per-row mean/rstd of X (final LN) ----------------
__global__ __launch_bounds__(256) void rowstat_kernel(
        const float* __restrict__ X, float* __restrict__ RS) {
    int row = blockIdx.x * 4 + (threadIdx.x >> 6);
    int lane = threadIdx.x & 63;
    const float* xr = X + (size_t)row * DIMM;
    float4 u0 = *(const float4*)(xr + lane * 8);
    float4 u1 = *(const float4*)(xr + lane * 8 + 4);
    float v[8] = {u0.x, u0.y, u0.z, u0.w, u1.x, u1.y, u1.z, u1.w};
    float s = 0.f;
#pragma unroll
    for (int j = 0; j < 8; ++j) s += v[j];
#pragma unroll
    for (int o = 32; o > 0; o >>= 1) s += __shfl_xor(s, o);
    float m = s * (1.f / DIMM);
    float q = 0.f;
#pragma unroll
    for (int j = 0; j < 8; ++j) { float d = v[j] - m; q += d * d; }
#pragma unroll
    for (int o = 32; o > 0; o >>= 1) q += __shfl_xor(q, o);
    float rstd = rsqrtf(q * (1.f / DIMM) + 1e-6f);
    if (lane == 0) {
        RS[row * 2 + 0] = m;
        RS[row * 2 + 1] = rstd;
    }
}

// ---------------- MFMA GEMM: in_proj  Hb[18432x512]bf16 @ WpT[2176x512]^T ----------------
__global__ __launch_bounds__(256) void gemm_in_mfma(
        const unsigned short* __restrict__ A,   // [ROWS][512]
        const unsigned short* __restrict__ Bt,  // [NPAD][512]
        unsigned short* __restrict__ Z, unsigned short* __restrict__ XBC,
        float* __restrict__ DTRAW) {
    __shared__ unsigned short As[128 * 64];
    __shared__ unsigned short Bs[128 * 64];
    const int tid = threadIdx.x;
    const int l = tid & 63, w = tid >> 6;
    const int wr = w >> 1, wc = w & 1;
    const int m0 = blockIdx.y * 128, n0 = blockIdx.x * 128;
    f32x4 acc[4][4];
#pragma unroll
    for (int i = 0; i < 4; ++i)
#pragma unroll
        for (int j = 0; j < 4; ++j) acc[i][j] = (f32x4)(0.f);

    int rA[4], rB[4];
#pragma unroll
    for (int f = 0; f < 4; ++f) {
        rA[f] = wr * 64 + f * 16 + (l & 15);
        rB[f] = wc * 64 + f * 16 + (l & 15);
    }
    const char* AsB = (const char*)As;
    const char* BsB = (const char*)Bs;

    for (int k0 = 0; k0 < 512; k0 += 64) {
        __syncthreads();
#pragma unroll
        for (int i = 0; i < 4; ++i) {
            int lin = i * 256 + tid;
            int r = lin >> 3, slot = lin & 7;
            int sc = (slot ^ (r & 7)) * 8;
            gload16(A  + (size_t)(m0 + r) * 512 + k0 + sc, As + lin * 8);
            gload16(Bt + (size_t)(n0 + r) * 512 + k0 + sc, Bs + lin * 8);
        }
        __syncthreads();
#pragma unroll
        for (int kk = 0; kk < 2; ++kk) {
            bf16x8 af[4], bfr[4];
            int c16 = kk * 4 + (l >> 4);
#pragma unroll
            for (int f = 0; f < 4; ++f) {
                int row = rA[f];
                af[f] = *(const bf16x8*)(AsB + row * 128 + ((c16 ^ (row & 7)) << 4));
            }
#pragma unroll
            for (int f = 0; f < 4; ++f) {
                int row = rB[f];
                bfr[f] = *(const bf16x8*)(BsB + row * 128 + ((c16 ^ (row & 7)) << 4));
            }
#pragma unroll
            for (int mf = 0; mf < 4; ++mf)
#pragma unroll
                for (int nf = 0; nf < 4; ++nf)
                    acc[mf][nf] = __builtin_amdgcn_mfma_f32_16x16x32_bf16(
                        af[mf], bfr[nf], acc[mf][nf], 0, 0, 0);
        }
    }
#pragma unroll
    for (int mf = 0; mf < 4; ++mf)
#pragma unroll
        for (int nf = 0; nf < 4; ++nf) {
            int col = n0 + wc * 64 + nf * 16 + (l & 15);
#pragma unroll
            for (int reg = 0; reg < 4; ++reg) {
                int row = m0 + wr * 64 + mf * 16 + (l >> 4) * 4 + reg;
                float v = acc[mf][nf][reg];
                if (col < DINN)             Z[(size_t)row * DINN + col] = f2b(v);
                else if (col < DINN + CONVD) XBC[(size_t)row * CONVD + (col - DINN)] = f2b(v);
                else if (col < DPROJJ)       DTRAW[(size_t)row * NHH + (col - DINN - CONVD)] = v;
            }
        }
}

// ---------------- MFMA GEMM: out_proj  XSY[18432x1024]bf16 @ WoT[512x1024]^T, X += ----------------
__global__ __launch_bounds__(256) void gemm_out_mfma(
        const unsigned short* __restrict__ A,   // [ROWS][1024]
        const unsigned short* __restrict__ Bt,  // [512][1024]
        float* __restrict__ X) {
    __shared__ unsigned short As[128 * 64];
    __shared__ unsigned short Bs[128 * 64];
    const int tid = threadIdx.x;
    const int l = tid & 63, w = tid >> 6;
    const int wr = w >> 1, wc = w & 1;
    const int m0 = blockIdx.y * 128, n0 = blockIdx.x * 128;
    f32x4 acc[4][4];
#pragma unroll
    for (int i = 0; i < 4; ++i)
#pragma unroll
        for (int j = 0; j < 4; ++j) acc[i][j] = (f32x4)(0.f);

    int rA[4], rB[4];
#pragma unroll
    for (int f = 0; f < 4; ++f) {
        rA[f] = wr * 64 + f * 16 + (l & 15);
        rB[f] = wc * 64 + f * 16 + (l & 15);
    }
    const char* AsB = (const char*)As;
    const char* BsB = (const char*)Bs;

    for (int k0 = 0; k0 < 1024; k0 += 64) {
        __syncthreads();
#pragma unroll
        for (int i = 0; i < 4; ++i) {
            int lin = i * 256 + tid;
            int r = lin >> 3, slot = lin & 7;
            int sc = (slot ^ (r & 7)) * 8;
            gload16(A  + (size_t)(m0 + r) * 1024 + k0 + sc, As + lin * 8);
            gload16(Bt + (size_t)(n0 + r) * 1024 + k0 + sc, Bs + lin * 8);
        }
        __syncthreads();
#pragma unroll
        for (int kk = 0; kk < 2; ++kk) {
            bf16x8 af[4], bfr[4];
            int c16 = kk * 4 + (l >> 4);
#pragma unroll
            for (int f = 0; f < 4; ++f) {
                int row = rA[f];
                af[f] = *(const bf16x8*)(AsB + row * 128 + ((c16 ^ (row & 7)) << 4));
            }
#pragma unroll
            for (int f = 0; f < 4; ++f) {
                int row = rB[f];
                bfr[f] = *(const bf16x8*)(BsB + row * 128 + ((c16 ^ (row & 7)) << 4));
            }
#pragma unroll
            for (int mf = 0; mf < 4; ++mf)
#pragma unroll
                for (int nf = 0; nf < 4; ++nf)
                    acc[mf][nf] = __builtin_amdgcn_mfma_f32_16x16x32_bf16(
                        af[mf], bfr[nf], acc[mf][nf], 0, 0, 0);
        }
    }
#pragma unroll
    for (int mf = 0; mf < 4; ++mf)
#pragma unroll
        for (int nf = 0; nf < 4; ++nf) {
            int col = n0 + wc * 64 + nf * 16 + (l & 15);
#pragma unroll
            for (int reg = 0; reg < 4; ++reg) {
                int row = m0 + wr * 64 + mf * 16 + (l >> 4) * 4 + reg;
                float* p = X + (size_t)row * DIMM + col;
                *p += acc[mf][nf][reg];
            }
        }
}

// ---------------- Causal depthwise conv + silu + rope split (XBC bf16 in) ----------------
__global__ __launch_bounds__(256) void conv_kernel(
        const unsigned short* __restrict__ XBC, const float* __restrict__ cw,
        const float* __restrict__ cb,
        const float* __restrict__ Bb, const float* __restrict__ Cb,
        const float* __restrict__ COS, const float* __restrict__ SIN,
        unsigned short* __restrict__ XS, float* __restrict__ BM, float* __restrict__ CM) {
    int c = blockIdx.y * 256 + threadIdx.x;
    if (c >= CONVD) return;
    int bl = blockIdx.x;
    int l = bl % L_TOK;
    float w0 = cw[c * 4 + 0], w1 = cw[c * 4 + 1], w2 = cw[c * 4 + 2], w3 = cw[c * 4 + 3];
    const unsigned short* col = XBC + (size_t)bl * CONVD + c;
    float acc = w3 * b2f(col[0]);
    if (l >= 1) acc += w2 * b2f(col[-(ptrdiff_t)CONVD]);
    if (l >= 2) acc += w1 * b2f(col[-(ptrdiff_t)(2 * CONVD)]);
    if (l >= 3) acc += w0 * b2f(col[-(ptrdiff_t)(3 * CONVD)]);
    float v = acc + cb[c];
    v = v / (1.f + expf(-v));   // silu
    if (c < DINN) {
        XS[(size_t)bl * DINN + c] = f2b(v);
    } else {
        int j = c - DINN;         // 0..63, single wave
        int jj = j & 31;
        float bias = (j < 32) ? Bb[jj] : Cb[jj];
        float v2 = v + bias;
        float partner = __shfl_xor(v2, 8);
        float outv;
        if (jj < 16) {
            int i = jj & 7;
            float cs = COS[l * 8 + i], sn = SIN[l * 8 + i];
            outv = (jj < 8) ? (v2 * cs - partner * sn) : (partner * sn + v2 * cs);
        } else {
            outv = v2;
        }
        if (j < 32) BM[(size_t)bl * NSTT + jj] = outv;
        else        CM[(size_t)bl * NSTT + jj] = outv;
    }
}

// ---------------- dt = softplus(raw + bias), logdec = -exp(Alog)*dt ----------------
__global__ void dtdec_kernel(const float* __restrict__ DTRAW, const float* __restrict__ dtb,
                             const float* __restrict__ Alog,
                             float* __restrict__ DT, float* __restrict__ LOGDEC) {
    int idx = blockIdx.x * 256 + threadIdx.x;
    if (idx >= ROWS * NHH) return;
    int h = idx & 15;
    float v = DTRAW[idx] + dtb[h];
    float dt = fmaxf(v, 0.f) + log1pf(expf(-fabsf(v)));
    DT[idx] = dt;
    LOGDEC[idx] = -expf(Alog[h]) * dt;
}

// ---------------- chunked scan pass A: per (chunk, b, h) one wave ----------------
// y_local(t) = sum_{s<=t} exp(L_t-L_s) dt_s (C_t . B_s) x_s  (+ dsk x_t via W[t][t])
// S_c[p][n] = sum_s exp(Lend-L_s) dt_s x_s[p] B_s[n]
__global__ __launch_bounds__(64) void scanA_kernel(
        unsigned short* __restrict__ XSY,
        const float* __restrict__ DT, const float* __restrict__ LOGDEC,
        const float* __restrict__ BM, const float* __restrict__ CM,
        const float* __restrict__ Dsk,
        float* __restrict__ SC, float* __restrict__ ET, float* __restrict__ ECH) {
    int c = blockIdx.x, bh = blockIdx.y;
    int b = bh >> 4, h = bh & 15;
    int l = threadIdx.x;
    int r0 = b * L_TOK + c * 64;

    __shared__ float Csh[64][36];
    __shared__ float Wsh[64];
    __shared__ float Ush[64];
    __shared__ float Lsh[64];

    float dtl = DT[(size_t)(r0 + l) * NHH + h];
    float L   = LOGDEC[(size_t)(r0 + l) * NHH + h];
#pragma unroll
    for (int off = 1; off < 64; off <<= 1) {
        float v = __shfl_up(L, off);
        if (l >= off) L += v;
    }
    float LEND = __shfl(L, 63);
    ET[(size_t)bh * L_TOK + c * 64 + l] = __expf(L);
    if (l == 0) ECH[bh * NCH + c] = __expf(LEND);
    Lsh[l] = L;
    Ush[l] = __expf(LEND - L) * dtl;

#pragma unroll
    for (int i = 0; i < 32; ++i) {
        int idx = i * 64 + l;
        int t = idx >> 5, n = idx & 31;
        Csh[t][n] = CM[(size_t)(r0 + t) * NSTT + n];
    }
    float Breg[32];
    {
        const float* bp = BM + (size_t)(r0 + l) * NSTT;
#pragma unroll
        for (int n4 = 0; n4 < 8; ++n4) {
            float4 v = *(const float4*)(bp + n4 * 4);
            Breg[n4*4+0]=v.x; Breg[n4*4+1]=v.y; Breg[n4*4+2]=v.z; Breg[n4*4+3]=v.w;
        }
    }
    float xr[64];
    {
        const unsigned short* xp = XSY + (size_t)r0 * DINN + h * HDD + l;
#pragma unroll
        for (int s = 0; s < 64; ++s) xr[s] = b2f(xp[(size_t)s * DINN]);
    }
    float dsk = Dsk[h];
    __builtin_amdgcn_wave_barrier();

    unsigned short* yp = XSY + (size_t)r0 * DINN + h * HDD + l;
    for (int t = 0; t < 64; ++t) {
        float cb = 0.f;
#pragma unroll
        for (int n4 = 0; n4 < 8; ++n4) {
            float4 cv = *(const float4*)&Csh[t][n4 * 4];
            cb += cv.x * Breg[n4*4+0] + cv.y * Breg[n4*4+1]
                + cv.z * Breg[n4*4+2] + cv.w * Breg[n4*4+3];
        }
        float Lt = Lsh[t];
        float w = (l <= t) ? __expf(Lt - L) * dtl * cb : 0.f;
        if (l == t) w += dsk;
        __builtin_amdgcn_wave_barrier();
        Wsh[l] = w;
        __builtin_amdgcn_wave_barrier();
        float y = 0.f;
#pragma unroll
        for (int sb = 0; sb < 16; ++sb) {
            float4 wv = *(const float4*)&Wsh[sb * 4];
            y += wv.x * xr[sb*4+0] + wv.y * xr[sb*4+1]
               + wv.z * xr[sb*4+2] + wv.w * xr[sb*4+3];
        }
        yp[(size_t)t * DINN] = f2b(y);
        __builtin_amdgcn_wave_barrier();
    }

    // ---- chunk state: reuse Csh for B rows ----
#pragma unroll
    for (int n4 = 0; n4 < 8; ++n4)
        *(float4*)&Csh[l][n4 * 4] = make_float4(Breg[n4*4+0], Breg[n4*4+1],
                                                Breg[n4*4+2], Breg[n4*4+3]);
    __builtin_amdgcn_wave_barrier();
#pragma unroll
    for (int s = 0; s < 64; ++s) xr[s] *= Ush[s];
    float S[32];
#pragma unroll
    for (int n = 0; n < 32; ++n) S[n] = 0.f;
#pragma unroll
    for (int s = 0; s < 64; ++s) {
#pragma unroll
        for (int n4 = 0; n4 < 8; ++n4) {
            float4 bv = *(const float4*)&Csh[s][n4 * 4];
            S[n4*4+0] += xr[s] * bv.x;
            S[n4*4+1] += xr[s] * bv.y;
            S[n4*4+2] += xr[s] * bv.z;
            S[n4*4+3] += xr[s] * bv.w;
        }
    }
    float* sp = SC + ((size_t)(bh * NCH + c) * 64 + l) * 32;
#pragma unroll
    for (int n4 = 0; n4 < 8; ++n4)
        *(float4*)(sp + n4 * 4) = make_float4(S[n4*4+0], S[n4*4+1], S[n4*4+2], S[n4*4+3]);
}

// ---------------- pass B: sequential over 9 chunks; SC slot becomes H_start ----------------
__global__ __launch_bounds__(64) void scanB_kernel(
        float* __restrict__ SC, const float* __restrict__ ECH) {
    int bh = blockIdx.x;
    int p = threadIdx.x;
    float H[32];
#pragma unroll
    for (int n = 0; n < 32; ++n) H[n] = 0.f;
    for (int c = 0; c < NCH; ++c) {
        float e = ECH[bh * NCH + c];
        float* sp = SC + ((size_t)(bh * NCH + c) * 64 + p) * 32;
        float s[32];
#pragma unroll
        for (int n4 = 0; n4 < 8; ++n4) {
            float4 v = *(const float4*)(sp + n4 * 4);
            s[n4*4+0]=v.x; s[n4*4+1]=v.y; s[n4*4+2]=v.z; s[n4*4+3]=v.w;
        }
#pragma unroll
        for (int n4 = 0; n4 < 8; ++n4)
            *(float4*)(sp + n4 * 4) = make_float4(H[n4*4+0], H[n4*4+1], H[n4*4+2], H[n4*4+3]);
#pragma unroll
        for (int n = 0; n < 32; ++n) H[n] = e * H[n] + s[n];
    }
}

// ---------------- pass C: y += exp(L_t) C_t . H_start ----------------
__global__ __launch_bounds__(64) void scanC_kernel(
        unsigned short* __restrict__ XSY, const float* __restrict__ SC,
        const float* __restrict__ CM, const float* __restrict__ ET) {
    int c = blockIdx.x, bh = blockIdx.y;
    int b = bh >> 4, h = bh & 15;
    int l = threadIdx.x;
    int r0 = b * L_TOK + c * 64;
    __shared__ float CEsh[64][36];
#pragma unroll
    for (int i = 0; i < 32; ++i) {
        int idx = i * 64 + l;
        int t = idx >> 5, n = idx & 31;
        CEsh[t][n] = CM[(size_t)(r0 + t) * NSTT + n] * ET[(size_t)bh * L_TOK + c * 64 + t];
    }
    const float* hp = SC + ((size_t)(bh * NCH + c) * 64 + l) * 32;
    float H[32];
#pragma unroll
    for (int n4 = 0; n4 < 8; ++n4) {
        float4 v = *(const float4*)(hp + n4 * 4);
        H[n4*4+0]=v.x; H[n4*4+1]=v.y; H[n4*4+2]=v.z; H[n4*4+3]=v.w;
    }
    __builtin_amdgcn_wave_barrier();
    unsigned short* yp = XSY + (size_t)r0 * DINN + h * HDD + l;
    for (int t = 0; t < 64; ++t) {
        float acc = 0.f;
#pragma unroll
        for (int n4 = 0; n4 < 8; ++n4) {
            float4 ce = *(const float4*)&CEsh[t][n4 * 4];
            acc += ce.x * H[n4*4+0] + ce.y * H[n4*4+1]
                 + ce.z * H[n4*4+2] + ce.w * H[n4*4+3];
        }
        float y = b2f(yp[(size_t)t * DINN]) + acc;
        yp[(size_t)t * DINN] = f2b(y);
    }
}

// ---------------- gate with silu(z) + RMSNorm(1024) * gn_w, in-place on Y (bf16) ----------------
__global__ __launch_bounds__(256) void rmsgate_kernel(
        unsigned short* __restrict__ Y, const unsigned short* __restrict__ Z,
        const float* __restrict__ gw) {
    int row = blockIdx.x * 4 + (threadIdx.x >> 6);
    int lane = threadIdx.x & 63;
    unsigned short* yr = Y + (size_t)row * DINN + lane * 16;
    const unsigned short* zr = Z + (size_t)row * DINN + lane * 16;
    float g[16];
    float q = 0.f;
#pragma unroll
    for (int i = 0; i < 16; ++i) {
        float yv = b2f(yr[i]);
        float zv = b2f(zr[i]);
        float gz = zv / (1.f + expf(-zv));
        g[i] = yv * gz;
        q += g[i] * g[i];
    }
#pragma unroll
    for (int o = 32; o > 0; o >>= 1) q += __shfl_xor(q, o);
    float sc = rsqrtf(q * (1.f / DINN) + 1e-6f);
#pragma unroll
    for (int i = 0; i < 16; ++i) {
        float wv = gw[lane * 16 + i];
        yr[i] = f2b(g[i] * sc * wv);
    }
}

// ---------------- final fused LN + mean over L ----------------
__global__ void lnmean_kernel(const float* __restrict__ X, const float* __restrict__ RS,
                              const float* __restrict__ nw, const float* __restrict__ nb,
                              float* __restrict__ MEAN) {
    int b = blockIdx.x >> 1;
    int d = (blockIdx.x & 1) * 256 + threadIdx.x;
    float w = nw[d], bb = nb[d];
    const float* p = X + (size_t)b * L_TOK * DIMM + d;
    const float* rs = RS + (size_t)b * L_TOK * 2;
    float s = 0.f;
    for (int l = 0; l < L_TOK; ++l) {
        float m = rs[l * 2 + 0], r = rs[l * 2 + 1];
        s += (p[(size_t)l * DIMM] - m) * r * w + bb;
    }
    MEAN[b * DIMM + d] = s * (1.f / L_TOK);
}

// ---------------- head: 32x512 @ 512x2 ----------------
__global__ void head_kernel(const float* __restrict__ MEAN, const float* __restrict__ hw,
                            const float* __restrict__ hb, float* __restrict__ out) {
    int t = threadIdx.x;
    if (t >= 64) return;
    int b = t >> 1, c = t & 1;
    float s = 0.f;
    for (int k = 0; k < DIMM; ++k) s += MEAN[b * DIMM + k] * hw[k * 2 + c];
    out[b * 2 + c] = s + hb[c];
}

extern "C" void kernel_launch(void* const* d_in, const int* in_sizes, int n_in,
                              void* d_out, int out_size, void* d_ws, size_t ws_size,
                              hipStream_t stream) {
    const float* x_img   = (const float*)d_in[0];
    const float* patch_w = (const float*)d_in[1];
    const float* patch_b = (const float*)d_in[2];
    const float* pos     = (const float*)d_in[3];
    const float* ln_w    = (const float*)d_in[4];
    const float* ln_b    = (const float*)d_in[5];
    const float* Wp      = (const float*)d_in[6];
    const float* cw      = (const float*)d_in[7];
    const float* cb      = (const float*)d_in[8];
    const float* dtb     = (const float*)d_in[9];
    const float* Alog    = (const float*)d_in[10];
    const float* Dsk     = (const float*)d_in[11];
    const float* Bb      = (const float*)d_in[12];
    const float* Cb      = (const float*)d_in[13];
    const float* gnw     = (const float*)d_in[14];
    const float* Wo      = (const float*)d_in[15];
    const float* nw      = (const float*)d_in[16];
    const float* nb      = (const float*)d_in[17];
    const float* hw      = (const float*)d_in[18];
    const float* hb      = (const float*)d_in[19];
    float* out = (float*)d_out;

    // ---- workspace carve ----
    char* base = (char*)d_ws;
    size_t off = 0;
    auto alloc = [&](size_t bytes) -> char* {
        char* p = base + off;
        off += (bytes + 255) & ~(size_t)255;
        return p;
    };
    float*          X     = (float*)alloc((size_t)ROWS * DIMM * 4);           // 37.7 MB
    unsigned short* XBC   = (unsigned short*)alloc((size_t)ROWS * CONVD * 2); // 40.1 MB
    unsigned short* Z     = (unsigned short*)alloc((size_t)ROWS * DINN * 2);  // 37.7 MB
    unsigned short* XSY   = (unsigned short*)alloc((size_t)ROWS * DINN * 2);  // 37.7 MB
    unsigned short* Hb    = (unsigned short*)alloc((size_t)ROWS * DIMM * 2);  // 18.9 MB
    unsigned short* WpT   = (unsigned short*)alloc((size_t)8 * NPAD * DIMM * 2); // 17.8 MB
    unsigned short* WoT   = (unsigned short*)alloc((size_t)8 * DIMM * DINN * 2); //  8.4 MB
    float*          DTRAW = (float*)alloc((size_t)ROWS * NHH * 4);
    float*          DT    = (float*)alloc((size_t)ROWS * NHH * 4);
    float*          LOGD  = (float*)alloc((size_t)ROWS * NHH * 4);
    float*          BMp   = (float*)alloc((size_t)ROWS * NSTT * 4);
    float*          CMp   = (float*)alloc((size_t)ROWS * NSTT * 4);
    float*          RS    = (float*)alloc((size_t)ROWS * 2 * 4);
    float*          COS   = (float*)alloc((size_t)L_TOK * 8 * 4);
    float*          SIN   = (float*)alloc((size_t)L_TOK * 8 * 4);
    float*          MEAN  = (float*)alloc((size_t)BATCHH * DIMM * 4);
    float*          ET    = (float*)alloc((size_t)BATCHH * NHH * L_TOK * 4);  // 1.2 MB
    float*          ECH   = (float*)alloc((size_t)BATCHH * NHH * NCH * 4);    // 18 KB
    // SC (512*9*64*32 f32 = 37.7 MB) aliases XBC: XBC is dead after conv_kernel,
    // SC is fully consumed by scanC before next layer's gemm_in rewrites XBC.
    float*          SCp   = (float*)XBC;
    if (off > ws_size) return;  // workspace too small: clean failure, no OOB

    rope_init<<<18, 256, 0, stream>>>(COS, SIN);
    transpose_pad<<<dim3(NPAD / 32, DIMM / 32, 8), 256, 0, stream>>>(Wp, WpT, DIMM, DPROJJ, NPAD);
    transpose_pad<<<dim3(DIMM / 32, DINN / 32, 8), 256, 0, stream>>>(Wo, WoT, DINN, DIMM, DIMM);
    patch_kernel<<<dim3(4, 144), 256, 0, stream>>>(x_img, patch_w, patch_b, pos, X);

    for (int i = 0; i < 8; ++i) {
        lnbf16_kernel<<<ROWS / 4, 256, 0, stream>>>(X, ln_w + i * DIMM, ln_b + i * DIMM, Hb);
        gemm_in_mfma<<<dim3(NPAD / 128, ROWS / 128), 256, 0, stream>>>(
            Hb, WpT + (size_t)i * NPAD * DIMM, Z, XBC, DTRAW);
        conv_kernel<<<dim3(ROWS, 5), 256, 0, stream>>>(
            XBC, cw + (size_t)i * CONVD * 4, cb + (size_t)i * CONVD,
            Bb + i * NSTT, Cb + i * NSTT, COS, SIN, XSY, BMp, CMp);
        dtdec_kernel<<<(ROWS * NHH + 255) / 256, 256, 0, stream>>>(
            DTRAW, dtb + i * NHH, Alog + i * NHH, DT, LOGD);
        scanA_kernel<<<dim3(NCH, BATCHH * NHH), 64, 0, stream>>>(
            XSY, DT, LOGD, BMp, CMp, Dsk + i * NHH, SCp, ET, ECH);
        scanB_kernel<<<BATCHH * NHH, 64, 0, stream>>>(SCp, ECH);
        scanC_kernel<<<dim3(NCH, BATCHH * NHH), 64, 0, stream>>>(XSY, SCp, CMp, ET);
        rmsgate_kernel<<<ROWS / 4, 256, 0, stream>>>(XSY, Z, gnw + (size_t)i * DINN);
        gemm_out_mfma<<<dim3(DIMM / 128, ROWS / 128), 256, 0, stream>>>(
            XSY, WoT + (size_t)i * DIMM * DINN, X);
    }

    rowstat_kernel<<<ROWS / 4, 256, 0, stream>>>(X, RS);
    lnmean_kernel<<<64, 256, 0, stream>>>(X, RS, nw, nb, MEAN);
    head_kernel<<<1, 64, 0, stream>>>(MEAN, hw, hb, out);
}

// Round 5
// 3736.046 us; speedup vs baseline: 3.1089x; 1.1772x over previous
//
#include <hip/hip_runtime.h>
#include <cmath>

#define L_TOK 576
#define DIMM  512
#define DINN  1024
#define NHH   16
#define HDD   64
#define NSTT  32
#define CONVD 1088
#define DPROJJ 2128
#define BATCHH 32
#define ROWS  (BATCHH * L_TOK)   // 18432
#define NPAD  2176               // 2128 padded to 17*128
#define NCH   9                  // 576 / 64 chunks

typedef unsigned int uint;
typedef __attribute__((ext_vector_type(8))) short bf16x8;
typedef __attribute__((ext_vector_type(4))) float f32x4;

__device__ __forceinline__ float b2f(unsigned short u) {
    union { uint i; float f; } v; v.i = ((uint)u) << 16; return v.f;
}
__device__ __forceinline__ unsigned short f2b(float x) {
    union { float f; uint i; } v; v.f = x;
    uint r = (v.i + 0x7FFFu + ((v.i >> 16) & 1u)) >> 16;
    return (unsigned short)r;
}

__device__ __forceinline__ void gload16(const unsigned short* g, unsigned short* lds) {
    __builtin_amdgcn_global_load_lds(
        (const __attribute__((address_space(1))) unsigned int*)g,
        (__attribute__((address_space(3))) unsigned int*)lds, 16, 0, 0);
}

// ---------------- RoPE tables ----------------
__global__ void rope_init(float* __restrict__ COS, float* __restrict__ SIN) {
    int i = blockIdx.x * 256 + threadIdx.x;   // L_TOK*8 = 4608
    if (i >= L_TOK * 8) return;
    int l = i >> 3, j = i & 7;
    double inv = pow(10000.0, -(double)(2 * j) / 16.0);
    double a = (double)l * inv;
    COS[i] = (float)cos(a);
    SIN[i] = (float)sin(a);
}

// ---------------- transpose + pad + bf16 convert: src[l][R][C] f32 -> dst[l][Cp][R] bf16 ----------------
__global__ __launch_bounds__(256) void transpose_pad(
        const float* __restrict__ src, unsigned short* __restrict__ dst,
        int R, int C, int Cp) {
    __shared__ float tile[32][33];
    int lz = blockIdx.z;
    const float* S = src + (size_t)lz * R * C;
    unsigned short* D = dst + (size_t)lz * Cp * R;
    int c0 = blockIdx.x * 32, r0 = blockIdx.y * 32;
    int tx = threadIdx.x & 31, ty = threadIdx.x >> 5;   // 32 x 8
#pragma unroll
    for (int i = 0; i < 32; i += 8) {
        int c = c0 + tx;
        tile[ty + i][tx] = (c < C) ? S[(size_t)(r0 + ty + i) * C + c] : 0.f;
    }
    __syncthreads();
#pragma unroll
    for (int i = 0; i < 32; i += 8) {
        int cc = c0 + ty + i;     // dst row (= src col, padded)
        int rr = r0 + tx;         // dst col (= src row)
        if (cc < Cp) D[(size_t)cc * R + rr] = f2b(tile[tx][ty + i]);
    }
}

// ---------------- f32 -> bf16 copy (patch weights: already [512][768] K-major) ----------------
__global__ void f32tobf16_kernel(const float* __restrict__ src, unsigned short* __restrict__ dst,
                                 int n) {
    int i = blockIdx.x * 256 + threadIdx.x;
    if (i < n) dst[i] = f2b(src[i]);
}

// ---------------- im2col: img[b][c][384][384] -> A[b*576+l][768] bf16 ----------------
__global__ __launch_bounds__(192) void im2col_kernel(
        const float* __restrict__ img, unsigned short* __restrict__ A) {
    int m = blockIdx.x;
    int tid = threadIdx.x;            // 0..191, float4 at k = tid*4
    int b = m / L_TOK, l = m % L_TOK;
    int oy = l / 24, ox = l % 24;
    int k = tid * 4;
    int c = k >> 8, rem = k & 255, iy = rem >> 4, ix = rem & 15;
    const float* p = img + ((size_t)(b * 3 + c) * 384 + oy * 16 + iy) * 384 + ox * 16 + ix;
    float4 v = *(const float4*)p;
    ushort4 u;
    u.x = f2b(v.x); u.y = f2b(v.y); u.z = f2b(v.z); u.w = f2b(v.w);
    *(ushort4*)(A + (size_t)m * 768 + k) = u;
}

// ---------------- MFMA GEMM: patch  A[18432x768]bf16 @ Bt[512x768]^T + pb + pos -> X f32 ----------------
__global__ __launch_bounds__(256) void gemm_patch_mfma(
        const unsigned short* __restrict__ A, const unsigned short* __restrict__ Bt,
        const float* __restrict__ pb, const float* __restrict__ pos,
        float* __restrict__ X) {
    __shared__ unsigned short As[128 * 64];
    __shared__ unsigned short Bs[128 * 64];
    const int tid = threadIdx.x;
    const int l = tid & 63, w = tid >> 6;
    const int wr = w >> 1, wc = w & 1;
    const int m0 = blockIdx.y * 128, n0 = blockIdx.x * 128;
    f32x4 acc[4][4];
#pragma unroll
    for (int i = 0; i < 4; ++i)
#pragma unroll
        for (int j = 0; j < 4; ++j) acc[i][j] = (f32x4)(0.f);

    int rA[4], rB[4];
#pragma unroll
    for (int f = 0; f < 4; ++f) {
        rA[f] = wr * 64 + f * 16 + (l & 15);
        rB[f] = wc * 64 + f * 16 + (l & 15);
    }
    const char* AsB = (const char*)As;
    const char* BsB = (const char*)Bs;

    for (int k0 = 0; k0 < 768; k0 += 64) {
        __syncthreads();
#pragma unroll
        for (int i = 0; i < 4; ++i) {
            int lin = i * 256 + tid;
            int r = lin >> 3, slot = lin & 7;
            int sc = (slot ^ (r & 7)) * 8;
            gload16(A  + (size_t)(m0 + r) * 768 + k0 + sc, As + lin * 8);
            gload16(Bt + (size_t)(n0 + r) * 768 + k0 + sc, Bs + lin * 8);
        }
        __syncthreads();
#pragma unroll
        for (int kk = 0; kk < 2; ++kk) {
            bf16x8 af[4], bfr[4];
            int c16 = kk * 4 + (l >> 4);
#pragma unroll
            for (int f = 0; f < 4; ++f) {
                int row = rA[f];
                af[f] = *(const bf16x8*)(AsB + row * 128 + ((c16 ^ (row & 7)) << 4));
            }
#pragma unroll
            for (int f = 0; f < 4; ++f) {
                int row = rB[f];
                bfr[f] = *(const bf16x8*)(BsB + row * 128 + ((c16 ^ (row & 7)) << 4));
            }
#pragma unroll
            for (int mf = 0; mf < 4; ++mf)
#pragma unroll
                for (int nf = 0; nf < 4; ++nf)
                    acc[mf][nf] = __builtin_amdgcn_mfma_f32_16x16x32_bf16(
                        af[mf], bfr[nf], acc[mf][nf], 0, 0, 0);
        }
    }
#pragma unroll
    for (int mf = 0; mf < 4; ++mf)
#pragma unroll
        for (int nf = 0; nf < 4; ++nf) {
            int col = n0 + wc * 64 + nf * 16 + (l & 15);
            float pbv = pb[col];
#pragma unroll
            for (int reg = 0; reg < 4; ++reg) {
                int row = m0 + wr * 64 + mf * 16 + (l >> 4) * 4 + reg;
                int tokl = row % L_TOK;
                X[(size_t)row * DIMM + col] =
                    acc[mf][nf][reg] + pbv + pos[(size_t)tokl * DIMM + col];
            }
        }
}

// ---------------- fused LN -> bf16 rows of 512 ----------------
__global__ __launch_bounds__(256) void lnbf16_kernel(
        const float* __restrict__ X, const float* __restrict__ w,
        const float* __restrict__ bi, unsigned short* __restrict__ Hb) {
    int row = blockIdx.x * 4 + (threadIdx.x >> 6);
    int lane = threadIdx.x & 63;
    const float* xr = X + (size_t)row * DIMM;
    float4 u0 = *(const float4*)(xr + lane * 8);
    float4 u1 = *(const float4*)(xr + lane * 8 + 4);
    float v[8] = {u0.x, u0.y, u0.z, u0.w, u1.x, u1.y, u1.z, u1.w};
    float s = 0.f;
#pragma unroll
    for (int j = 0; j < 8; ++j) s += v[j];
#pragma unroll
    for (int o = 32; o > 0; o >>= 1) s += __shfl_xor(s, o);
    float m = s * (1.f / DIMM);
    float q = 0.f;
#pragma unroll
    for (int j = 0; j < 8; ++j) { float d = v[j] - m; q += d * d; }
#pragma unroll
    for (int o = 32; o > 0; o >>= 1) q += __shfl_xor(q, o);
    float rstd = rsqrtf(q * (1.f / DIMM) + 1e-6f);
    float4 w0 = *(const float4*)(w + lane * 8);
    float4 w1 = *(const float4*)(w + lane * 8 + 4);
    float4 b0 = *(const float4*)(bi + lane * 8);
    float4 b1 = *(const float4*)(bi + lane * 8 + 4);
    float wv[8] = {w0.x, w0.y, w0.z, w0.w, w1.x, w1.y, w1.z, w1.w};
    float bv[8] = {b0.x, b0.y, b0.z, b0.w, b1.x, b1.y, b1.z, b1.w};
    ushort4 s0, s1;
    s0.x = f2b((v[0] - m) * rstd * wv[0] + bv[0]);
    s0.y = f2b((v[1] - m) * rstd * wv[1] + bv[1]);
    s0.z = f2b((v[2] - m) * rstd * wv[2] + bv[2]);
    s0.w = f2b((v[3] - m) * rstd * wv[3] + bv[3]);
    s1.x = f2b((v[4] - m) * rstd * wv[4] + bv[4]);
    s1.y = f2b((v[5] - m) * rstd * wv[5] + bv[5]);
    s1.z = f2b((v[6] - m) * rstd * wv[6] + bv[6]);
    s1.w = f2b((v[7] - m) * rstd * wv[7] + bv[7]);
    unsigned short* orow = Hb + (size_t)row * DIMM + lane * 8;
    *(ushort4*)(orow) = s0;
    *(ushort4*)(orow + 4) = s1;
}

// ---------------- per-row mean/rstd of X (final LN) ----------------
__global__ __launch_bounds__(256) void rowstat_kernel(
        const float* __restrict__ X, float* __restrict__ RS) {
    int row = blockIdx.x * 4 + (threadIdx.x >> 6);
    int lane = threadIdx.x & 63;
    const float* xr = X + (size_t)row * DIMM;
    float4 u0 = *(const float4*)(xr + lane * 8);
    float4 u1 = *(const float4*)(xr + lane * 8 + 4);
    float v[8] = {u0.x, u0.y, u0.z, u0.w, u1.x, u1.y, u1.z, u1.w};
    float s = 0.f;
#pragma unroll
    for (int j = 0; j < 8; ++j) s += v[j];
#pragma unroll
    for (int o = 32; o > 0; o >>= 1) s += __shfl_xor(s, o);
    float m = s * (1.f / DIMM);
    float q = 0.f;
#pragma unroll
    for (int j = 0; j < 8; ++j) { float d = v[j] - m; q += d * d; }
#pragma unroll
    for (int o = 32; o > 0; o >>= 1) q += __shfl_xor(q, o);
    float rstd = rsqrtf(q * (1.f / DIMM) + 1e-6f);
    if (lane == 0) {
        RS[row * 2 + 0] = m;
        RS[row * 2 + 1] = rstd;
    }
}

// ---------------- MFMA GEMM: in_proj  Hb[18432x512]bf16 @ WpT[2176x512]^T ----------------
__global__ __launch_bounds__(256) void gemm_in_mfma(
        const unsigned short* __restrict__ A,   // [ROWS][512]
        const unsigned short* __restrict__ Bt,  // [NPAD][512]
        unsigned short* __restrict__ Z, unsigned short* __restrict__ XBC,
        float* __restrict__ DTRAW) {
    __shared__ unsigned short As[128 * 64];
    __shared__ unsigned short Bs[128 * 64];
    const int tid = threadIdx.x;
    const int l = tid & 63, w = tid >> 6;
    const int wr = w >> 1, wc = w & 1;
    const int m0 = blockIdx.y * 128, n0 = blockIdx.x * 128;
    f32x4 acc[4][4];
#pragma unroll
    for (int i = 0; i < 4; ++i)
#pragma unroll
        for (int j = 0; j < 4; ++j) acc[i][j] = (f32x4)(0.f);

    int rA[4], rB[4];
#pragma unroll
    for (int f = 0; f < 4; ++f) {
        rA[f] = wr * 64 + f * 16 + (l & 15);
        rB[f] = wc * 64 + f * 16 + (l & 15);
    }
    const char* AsB = (const char*)As;
    const char* BsB = (const char*)Bs;

    for (int k0 = 0; k0 < 512; k0 += 64) {
        __syncthreads();
#pragma unroll
        for (int i = 0; i < 4; ++i) {
            int lin = i * 256 + tid;
            int r = lin >> 3, slot = lin & 7;
            int sc = (slot ^ (r & 7)) * 8;
            gload16(A  + (size_t)(m0 + r) * 512 + k0 + sc, As + lin * 8);
            gload16(Bt + (size_t)(n0 + r) * 512 + k0 + sc, Bs + lin * 8);
        }
        __syncthreads();
#pragma unroll
        for (int kk = 0; kk < 2; ++kk) {
            bf16x8 af[4], bfr[4];
            int c16 = kk * 4 + (l >> 4);
#pragma unroll
            for (int f = 0; f < 4; ++f) {
                int row = rA[f];
                af[f] = *(const bf16x8*)(AsB + row * 128 + ((c16 ^ (row & 7)) << 4));
            }
#pragma unroll
            for (int f = 0; f < 4; ++f) {
                int row = rB[f];
                bfr[f] = *(const bf16x8*)(BsB + row * 128 + ((c16 ^ (row & 7)) << 4));
            }
#pragma unroll
            for (int mf = 0; mf < 4; ++mf)
#pragma unroll
                for (int nf = 0; nf < 4; ++nf)
                    acc[mf][nf] = __builtin_amdgcn_mfma_f32_16x16x32_bf16(
                        af[mf], bfr[nf], acc[mf][nf], 0, 0, 0);
        }
    }
#pragma unroll
    for (int mf = 0; mf < 4; ++mf)
#pragma unroll
        for (int nf = 0; nf < 4; ++nf) {
            int col = n0 + wc * 64 + nf * 16 + (l & 15);
#pragma unroll
            for (int reg = 0; reg < 4; ++reg) {
                int row = m0 + wr * 64 + mf * 16 + (l >> 4) * 4 + reg;
                float v = acc[mf][nf][reg];
                if (col < DINN)             Z[(size_t)row * DINN + col] = f2b(v);
                else if (col < DINN + CONVD) XBC[(size_t)row * CONVD + (col - DINN)] = f2b(v);
                else if (col < DPROJJ)       DTRAW[(size_t)row * NHH + (col - DINN - CONVD)] = v;
            }
        }
}

// ---------------- MFMA GEMM: out_proj  XSY[18432x1024]bf16 @ WoT[512x1024]^T, X += ----------------
__global__ __launch_bounds__(256) void gemm_out_mfma(
        const unsigned short* __restrict__ A,   // [ROWS][1024]
        const unsigned short* __restrict__ Bt,  // [512][1024]
        float* __restrict__ X) {
    __shared__ unsigned short As[128 * 64];
    __shared__ unsigned short Bs[128 * 64];
    const int tid = threadIdx.x;
    const int l = tid & 63, w = tid >> 6;
    const int wr = w >> 1, wc = w & 1;
    const int m0 = blockIdx.y * 128, n0 = blockIdx.x * 128;
    f32x4 acc[4][4];
#pragma unroll
    for (int i = 0; i < 4; ++i)
#pragma unroll
        for (int j = 0; j < 4; ++j) acc[i][j] = (f32x4)(0.f);

    int rA[4], rB[4];
#pragma unroll
    for (int f = 0; f < 4; ++f) {
        rA[f] = wr * 64 + f * 16 + (l & 15);
        rB[f] = wc * 64 + f * 16 + (l & 15);
    }
    const char* AsB = (const char*)As;
    const char* BsB = (const char*)Bs;

    for (int k0 = 0; k0 < 1024; k0 += 64) {
        __syncthreads();
#pragma unroll
        for (int i = 0; i < 4; ++i) {
            int lin = i * 256 + tid;
            int r = lin >> 3, slot = lin & 7;
            int sc = (slot ^ (r & 7)) * 8;
            gload16(A  + (size_t)(m0 + r) * 1024 + k0 + sc, As + lin * 8);
            gload16(Bt + (size_t)(n0 + r) * 1024 + k0 + sc, Bs + lin * 8);
        }
        __syncthreads();
#pragma unroll
        for (int kk = 0; kk < 2; ++kk) {
            bf16x8 af[4], bfr[4];
            int c16 = kk * 4 + (l >> 4);
#pragma unroll
            for (int f = 0; f < 4; ++f) {
                int row = rA[f];
                af[f] = *(const bf16x8*)(AsB + row * 128 + ((c16 ^ (row & 7)) << 4));
            }
#pragma unroll
            for (int f = 0; f < 4; ++f) {
                int row = rB[f];
                bfr[f] = *(const bf16x8*)(BsB + row * 128 + ((c16 ^ (row & 7)) << 4));
            }
#pragma unroll
            for (int mf = 0; mf < 4; ++mf)
#pragma unroll
                for (int nf = 0; nf < 4; ++nf)
                    acc[mf][nf] = __builtin_amdgcn_mfma_f32_16x16x32_bf16(
                        af[mf], bfr[nf], acc[mf][nf], 0, 0, 0);
        }
    }
#pragma unroll
    for (int mf = 0; mf < 4; ++mf)
#pragma unroll
        for (int nf = 0; nf < 4; ++nf) {
            int col = n0 + wc * 64 + nf * 16 + (l & 15);
#pragma unroll
            for (int reg = 0; reg < 4; ++reg) {
                int row = m0 + wr * 64 + mf * 16 + (l >> 4) * 4 + reg;
                float* p = X + (size_t)row * DIMM + col;
                *p += acc[mf][nf][reg];
            }
        }
}

// ---------------- Causal depthwise conv + silu + rope split, LDS-tiled ----------------
// grid: (BATCHH*18, 9); block 256 = 128 channels x 2 token-halves; 32 tokens/block
__global__ __launch_bounds__(256) void conv_kernel(
        const unsigned short* __restrict__ XBC, const float* __restrict__ cw,
        const float* __restrict__ cb,
        const float* __restrict__ Bb, const float* __restrict__ Cb,
        const float* __restrict__ COS, const float* __restrict__ SIN,
        unsigned short* __restrict__ XS, float* __restrict__ BM, float* __restrict__ CM) {
    __shared__ unsigned short sh[35][128];
    int tileIdx = blockIdx.x;
    int c0 = blockIdx.y * 128;
    int b = tileIdx / 18, lt = tileIdx % 18;
    int l0 = lt * 32;
    int r0 = b * L_TOK + l0;

    for (int idx = threadIdx.x; idx < 35 * 128; idx += 256) {
        int row = idx >> 7, col = idx & 127;
        int t = l0 - 3 + row;
        int c = c0 + col;
        unsigned short v = 0;
        if (t >= 0 && c < CONVD)
            v = XBC[(size_t)(b * L_TOK + t) * CONVD + c];
        sh[row][col] = v;
    }
    __syncthreads();

    int tx = threadIdx.x & 127, ty = threadIdx.x >> 7;
    int c = c0 + tx;
    if (c >= CONVD) return;
    float w0 = cw[c * 4 + 0], w1 = cw[c * 4 + 1], w2 = cw[c * 4 + 2], w3 = cw[c * 4 + 3];
    float bias = cb[c];

    if (c < DINN) {
#pragma unroll
        for (int i = 0; i < 16; ++i) {
            int t = ty * 16 + i;
            float acc = w0 * b2f(sh[t][tx]) + w1 * b2f(sh[t + 1][tx])
                      + w2 * b2f(sh[t + 2][tx]) + w3 * b2f(sh[t + 3][tx]);
            float v = acc + bias;
            v = v / (1.f + expf(-v));
            XS[(size_t)(r0 + t) * DINN + c] = f2b(v);
        }
    } else {
        int j = c - DINN;        // 0..63
        int jj = j & 31;
        bool isB = j < 32;
        float bias2 = isB ? Bb[jj] : Cb[jj];
        int i0 = jj & 7;
#pragma unroll
        for (int i = 0; i < 16; ++i) {
            int t = ty * 16 + i;
            int lglob = l0 + t;
            float acc = w0 * b2f(sh[t][tx]) + w1 * b2f(sh[t + 1][tx])
                      + w2 * b2f(sh[t + 2][tx]) + w3 * b2f(sh[t + 3][tx]);
            float v = acc + bias;
            v = v / (1.f + expf(-v));
            float v2 = v + bias2;
            float partner = __shfl_xor(v2, 8);
            float outv;
            if (jj < 16) {
                float cs = COS[lglob * 8 + i0], sn = SIN[lglob * 8 + i0];
                outv = (jj < 8) ? (v2 * cs - partner * sn) : (partner * sn + v2 * cs);
            } else {
                outv = v2;
            }
            if (isB) BM[(size_t)(r0 + t) * NSTT + jj] = outv;
            else     CM[(size_t)(r0 + t) * NSTT + jj] = outv;
        }
    }
}

// ---------------- chunked scan pass A (dt/decay computed inline) ----------------
__global__ __launch_bounds__(64) void scanA_kernel(
        unsigned short* __restrict__ XSY,
        const float* __restrict__ DTRAW, const float* __restrict__ dtb,
        const float* __restrict__ Alog,
        const float* __restrict__ BM, const float* __restrict__ CM,
        const float* __restrict__ Dsk,
        float* __restrict__ SC, float* __restrict__ ET, float* __restrict__ ECH) {
    int c = blockIdx.x, bh = blockIdx.y;
    int b = bh >> 4, h = bh & 15;
    int l = threadIdx.x;
    int r0 = b * L_TOK + c * 64;

    __shared__ float Csh[64][36];
    __shared__ float Wsh[64];
    __shared__ float Ush[64];
    __shared__ float Lsh[64];

    float raw = DTRAW[(size_t)(r0 + l) * NHH + h] + dtb[h];
    float dtl = fmaxf(raw, 0.f) + log1pf(expf(-fabsf(raw)));
    float L   = -expf(Alog[h]) * dtl;
#pragma unroll
    for (int off = 1; off < 64; off <<= 1) {
        float v = __shfl_up(L, off);
        if (l >= off) L += v;
    }
    float LEND = __shfl(L, 63);
    ET[(size_t)bh * L_TOK + c * 64 + l] = __expf(L);
    if (l == 0) ECH[bh * NCH + c] = __expf(LEND);
    Lsh[l] = L;
    Ush[l] = __expf(LEND - L) * dtl;

#pragma unroll
    for (int i = 0; i < 32; ++i) {
        int idx = i * 64 + l;
        int t = idx >> 5, n = idx & 31;
        Csh[t][n] = CM[(size_t)(r0 + t) * NSTT + n];
    }
    float Breg[32];
    {
        const float* bp = BM + (size_t)(r0 + l) * NSTT;
#pragma unroll
        for (int n4 = 0; n4 < 8; ++n4) {
            float4 v = *(const float4*)(bp + n4 * 4);
            Breg[n4*4+0]=v.x; Breg[n4*4+1]=v.y; Breg[n4*4+2]=v.z; Breg[n4*4+3]=v.w;
        }
    }
    float xr[64];
    {
        const unsigned short* xp = XSY + (size_t)r0 * DINN + h * HDD + l;
#pragma unroll
        for (int s = 0; s < 64; ++s) xr[s] = b2f(xp[(size_t)s * DINN]);
    }
    float dsk = Dsk[h];
    __builtin_amdgcn_wave_barrier();

    unsigned short* yp = XSY + (size_t)r0 * DINN + h * HDD + l;
    for (int t = 0; t < 64; ++t) {
        float cb2 = 0.f;
#pragma unroll
        for (int n4 = 0; n4 < 8; ++n4) {
            float4 cv = *(const float4*)&Csh[t][n4 * 4];
            cb2 += cv.x * Breg[n4*4+0] + cv.y * Breg[n4*4+1]
                 + cv.z * Breg[n4*4+2] + cv.w * Breg[n4*4+3];
        }
        float Lt = Lsh[t];
        float w = (l <= t) ? __expf(Lt - L) * dtl * cb2 : 0.f;
        if (l == t) w += dsk;
        __builtin_amdgcn_wave_barrier();
        Wsh[l] = w;
        __builtin_amdgcn_wave_barrier();
        float y = 0.f;
#pragma unroll
        for (int sb = 0; sb < 16; ++sb) {
            float4 wv = *(const float4*)&Wsh[sb * 4];
            y += wv.x * xr[sb*4+0] + wv.y * xr[sb*4+1]
               + wv.z * xr[sb*4+2] + wv.w * xr[sb*4+3];
        }
        yp[(size_t)t * DINN] = f2b(y);
        __builtin_amdgcn_wave_barrier();
    }

    // ---- chunk state: reuse Csh for B rows ----
#pragma unroll
    for (int n4 = 0; n4 < 8; ++n4)
        *(float4*)&Csh[l][n4 * 4] = make_float4(Breg[n4*4+0], Breg[n4*4+1],
                                                Breg[n4*4+2], Breg[n4*4+3]);
    __builtin_amdgcn_wave_barrier();
#pragma unroll
    for (int s = 0; s < 64; ++s) xr[s] *= Ush[s];
    float S[32];
#pragma unroll
    for (int n = 0; n < 32; ++n) S[n] = 0.f;
#pragma unroll
    for (int s = 0; s < 64; ++s) {
#pragma unroll
        for (int n4 = 0; n4 < 8; ++n4) {
            float4 bv = *(const float4*)&Csh[s][n4 * 4];
            S[n4*4+0] += xr[s] * bv.x;
            S[n4*4+1] += xr[s] * bv.y;
            S[n4*4+2] += xr[s] * bv.z;
            S[n4*4+3] += xr[s] * bv.w;
        }
    }
    float* sp = SC + ((size_t)(bh * NCH + c) * 64 + l) * 32;
#pragma unroll
    for (int n4 = 0; n4 < 8; ++n4)
        *(float4*)(sp + n4 * 4) = make_float4(S[n4*4+0], S[n4*4+1], S[n4*4+2], S[n4*4+3]);
}

// ---------------- pass B: sequential over 9 chunks; SC slot becomes H_start ----------------
__global__ __launch_bounds__(64) void scanB_kernel(
        float* __restrict__ SC, const float* __restrict__ ECH) {
    int bh = blockIdx.x;
    int p = threadIdx.x;
    float H[32];
#pragma unroll
    for (int n = 0; n < 32; ++n) H[n] = 0.f;
    for (int c = 0; c < NCH; ++c) {
        float e = ECH[bh * NCH + c];
        float* sp = SC + ((size_t)(bh * NCH + c) * 64 + p) * 32;
        float s[32];
#pragma unroll
        for (int n4 = 0; n4 < 8; ++n4) {
            float4 v = *(const float4*)(sp + n4 * 4);
            s[n4*4+0]=v.x; s[n4*4+1]=v.y; s[n4*4+2]=v.z; s[n4*4+3]=v.w;
        }
#pragma unroll
        for (int n4 = 0; n4 < 8; ++n4)
            *(float4*)(sp + n4 * 4) = make_float4(H[n4*4+0], H[n4*4+1], H[n4*4+2], H[n4*4+3]);
#pragma unroll
        for (int n = 0; n < 32; ++n) H[n] = e * H[n] + s[n];
    }
}

// ---------------- pass C: y += exp(L_t) C_t . H_start ----------------
__global__ __launch_bounds__(64) void scanC_kernel(
        unsigned short* __restrict__ XSY, const float* __restrict__ SC,
        const float* __restrict__ CM, const float* __restrict__ ET) {
    int c = blockIdx.x, bh = blockIdx.y;
    int b = bh >> 4, h = bh & 15;
    int l = threadIdx.x;
    int r0 = b * L_TOK + c * 64;
    __shared__ float CEsh[64][36];
#pragma unroll
    for (int i = 0; i < 32; ++i) {
        int idx = i * 64 + l;
        int t = idx >> 5, n = idx & 31;
        CEsh[t][n] = CM[(size_t)(r0 + t) * NSTT + n] * ET[(size_t)bh * L_TOK + c * 64 + t];
    }
    const float* hp = SC + ((size_t)(bh * NCH + c) * 64 + l) * 32;
    float H[32];
#pragma unroll
    for (int n4 = 0; n4 < 8; ++n4) {
        float4 v = *(const float4*)(hp + n4 * 4);
        H[n4*4+0]=v.x; H[n4*4+1]=v.y; H[n4*4+2]=v.z; H[n4*4+3]=v.w;
    }
    __builtin_amdgcn_wave_barrier();
    unsigned short* yp = XSY + (size_t)r0 * DINN + h * HDD + l;
    for (int t = 0; t < 64; ++t) {
        float acc = 0.f;
#pragma unroll
        for (int n4 = 0; n4 < 8; ++n4) {
            float4 ce = *(const float4*)&CEsh[t][n4 * 4];
            acc += ce.x * H[n4*4+0] + ce.y * H[n4*4+1]
                 + ce.z * H[n4*4+2] + ce.w * H[n4*4+3];
        }
        float y = b2f(yp[(size_t)t * DINN]) + acc;
        yp[(size_t)t * DINN] = f2b(y);
    }
}

// ---------------- gate with silu(z) + RMSNorm(1024) * gn_w, in-place on Y (bf16) ----------------
__global__ __launch_bounds__(256) void rmsgate_kernel(
        unsigned short* __restrict__ Y, const unsigned short* __restrict__ Z,
        const float* __restrict__ gw) {
    int row = blockIdx.x * 4 + (threadIdx.x >> 6);
    int lane = threadIdx.x & 63;
    unsigned short* yr = Y + (size_t)row * DINN + lane * 16;
    const unsigned short* zr = Z + (size_t)row * DINN + lane * 16;
    float g[16];
    float q = 0.f;
#pragma unroll
    for (int i = 0; i < 16; ++i) {
        float yv = b2f(yr[i]);
        float zv = b2f(zr[i]);
        float gz = zv / (1.f + expf(-zv));
        g[i] = yv * gz;
        q += g[i] * g[i];
    }
#pragma unroll
    for (int o = 32; o > 0; o >>= 1) q += __shfl_xor(q, o);
    float sc = rsqrtf(q * (1.f / DINN) + 1e-6f);
#pragma unroll
    for (int i = 0; i < 16; ++i) {
        float wv = gw[lane * 16 + i];
        yr[i] = f2b(g[i] * sc * wv);
    }
}

// ---------------- final fused LN + mean over L ----------------
__global__ void lnmean_kernel(const float* __restrict__ X, const float* __restrict__ RS,
                              const float* __restrict__ nw, const float* __restrict__ nb,
                              float* __restrict__ MEAN) {
    int b = blockIdx.x >> 1;
    int d = (blockIdx.x & 1) * 256 + threadIdx.x;
    float w = nw[d], bb = nb[d];
    const float* p = X + (size_t)b * L_TOK * DIMM + d;
    const float* rs = RS + (size_t)b * L_TOK * 2;
    float s = 0.f;
    for (int l = 0; l < L_TOK; ++l) {
        float m = rs[l * 2 + 0], r = rs[l * 2 + 1];
        s += (p[(size_t)l * DIMM] - m) * r * w + bb;
    }
    MEAN[b * DIMM + d] = s * (1.f / L_TOK);
}

// ---------------- head: 32x512 @ 512x2 ----------------
__global__ void head_kernel(const float* __restrict__ MEAN, const float* __restrict__ hw,
                            const float* __restrict__ hb, float* __restrict__ out) {
    int t = threadIdx.x;
    if (t >= 64) return;
    int b = t >> 1, c = t & 1;
    float s = 0.f;
    for (int k = 0; k < DIMM; ++k) s += MEAN[b * DIMM + k] * hw[k * 2 + c];
    out[b * 2 + c] = s + hb[c];
}

extern "C" void kernel_launch(void* const* d_in, const int* in_sizes, int n_in,
                              void* d_out, int out_size, void* d_ws, size_t ws_size,
                              hipStream_t stream) {
    const float* x_img   = (const float*)d_in[0];
    const float* patch_w = (const float*)d_in[1];
    const float* patch_b = (const float*)d_in[2];
    const float* pos     = (const float*)d_in[3];
    const float* ln_w    = (const float*)d_in[4];
    const float* ln_b    = (const float*)d_in[5];
    const float* Wp      = (const float*)d_in[6];
    const float* cw      = (const float*)d_in[7];
    const float* cb      = (const float*)d_in[8];
    const float* dtb     = (const float*)d_in[9];
    const float* Alog    = (const float*)d_in[10];
    const float* Dsk     = (const float*)d_in[11];
    const float* Bb      = (const float*)d_in[12];
    const float* Cb      = (const float*)d_in[13];
    const float* gnw     = (const float*)d_in[14];
    const float* Wo      = (const float*)d_in[15];
    const float* nw      = (const float*)d_in[16];
    const float* nb      = (const float*)d_in[17];
    const float* hw      = (const float*)d_in[18];
    const float* hb      = (const float*)d_in[19];
    float* out = (float*)d_out;

    // ---- workspace carve ----
    char* base = (char*)d_ws;
    size_t off = 0;
    auto alloc = [&](size_t bytes) -> char* {
        char* p = base + off;
        off += (bytes + 255) & ~(size_t)255;
        return p;
    };
    float*          X     = (float*)alloc((size_t)ROWS * DIMM * 4);           // 37.7 MB
    unsigned short* XBC   = (unsigned short*)alloc((size_t)ROWS * CONVD * 2); // 40.1 MB
    unsigned short* Z     = (unsigned short*)alloc((size_t)ROWS * DINN * 2);  // 37.7 MB
    unsigned short* XSY   = (unsigned short*)alloc((size_t)ROWS * DINN * 2);  // 37.7 MB
    unsigned short* Hb    = (unsigned short*)alloc((size_t)ROWS * DIMM * 2);  // 18.9 MB
    unsigned short* WpT   = (unsigned short*)alloc((size_t)8 * NPAD * DIMM * 2); // 17.8 MB
    unsigned short* WoT   = (unsigned short*)alloc((size_t)8 * DIMM * DINN * 2); //  8.4 MB
    float*          DTRAW = (float*)alloc((size_t)ROWS * NHH * 4);
    float*          BMp   = (float*)alloc((size_t)ROWS * NSTT * 4);
    float*          CMp   = (float*)alloc((size_t)ROWS * NSTT * 4);
    float*          RS    = (float*)alloc((size_t)ROWS * 2 * 4);
    float*          COS   = (float*)alloc((size_t)L_TOK * 8 * 4);
    float*          SIN   = (float*)alloc((size_t)L_TOK * 8 * 4);
    float*          MEAN  = (float*)alloc((size_t)BATCHH * DIMM * 4);
    float*          ET    = (float*)alloc((size_t)BATCHH * NHH * L_TOK * 4);  // 1.2 MB
    float*          ECH   = (float*)alloc((size_t)BATCHH * NHH * NCH * 4);    // 18 KB
    // Aliases into buffers that are dead at patch/scan time:
    //  - im2col A (18432x768 bf16 = 27 MB) aliases XBC (dead until layer-0 gemm_in)
    //  - patch weight bf16 (512x768 = 0.79 MB) aliases Z (dead until layer-0 gemm_in)
    //  - SC (512*9*64*32 f32 = 37.7 MB) aliases XBC (dead between conv and next gemm_in)
    unsigned short* AIM   = XBC;
    unsigned short* PWB   = Z;
    float*          SCp   = (float*)XBC;
    if (off > ws_size) return;  // workspace too small: clean failure, no OOB

    rope_init<<<18, 256, 0, stream>>>(COS, SIN);
    transpose_pad<<<dim3(NPAD / 32, DIMM / 32, 8), 256, 0, stream>>>(Wp, WpT, DIMM, DPROJJ, NPAD);
    transpose_pad<<<dim3(DIMM / 32, DINN / 32, 8), 256, 0, stream>>>(Wo, WoT, DINN, DIMM, DIMM);

    f32tobf16_kernel<<<(512 * 768 + 255) / 256, 256, 0, stream>>>(patch_w, PWB, 512 * 768);
    im2col_kernel<<<ROWS, 192, 0, stream>>>(x_img, AIM);
    gemm_patch_mfma<<<dim3(4, 144), 256, 0, stream>>>(AIM, PWB, patch_b, pos, X);

    for (int i = 0; i < 8; ++i) {
        lnbf16_kernel<<<ROWS / 4, 256, 0, stream>>>(X, ln_w + i * DIMM, ln_b + i * DIMM, Hb);
        gemm_in_mfma<<<dim3(NPAD / 128, ROWS / 128), 256, 0, stream>>>(
            Hb, WpT + (size_t)i * NPAD * DIMM, Z, XBC, DTRAW);
        conv_kernel<<<dim3(BATCHH * 18, 9), 256, 0, stream>>>(
            XBC, cw + (size_t)i * CONVD * 4, cb + (size_t)i * CONVD,
            Bb + i * NSTT, Cb + i * NSTT, COS, SIN, XSY, BMp, CMp);
        scanA_kernel<<<dim3(NCH, BATCHH * NHH), 64, 0, stream>>>(
            XSY, DTRAW, dtb + i * NHH, Alog + i * NHH, BMp, CMp, Dsk + i * NHH, SCp, ET, ECH);
        scanB_kernel<<<BATCHH * NHH, 64, 0, stream>>>(SCp, ECH);
        scanC_kernel<<<dim3(NCH, BATCHH * NHH), 64, 0, stream>>>(XSY, SCp, CMp, ET);
        rmsgate_kernel<<<ROWS / 4, 256, 0, stream>>>(XSY, Z, gnw + (size_t)i * DINN);
        gemm_out_mfma<<<dim3(DIMM / 128, ROWS / 128), 256, 0, stream>>>(
            XSY, WoT + (size_t)i * DIMM * DINN, X);
    }

    rowstat_kernel<<<ROWS / 4, 256, 0, stream>>>(X, RS);
    lnmean_kernel<<<64, 256, 0, stream>>>(X, RS, nw, nb, MEAN);
    head_kernel<<<1, 64, 0, stream>>>(MEAN, hw, hb, out);
}

// Round 6
// 2782.765 us; speedup vs baseline: 4.1738x; 1.3426x over previous
//
#include <hip/hip_runtime.h>
#include <cmath>

#define L_TOK 576
#define DIMM  512
#define DINN  1024
#define NHH   16
#define HDD   64
#define NSTT  32
#define CONVD 1088
#define DPROJJ 2128
#define BATCHH 32
#define ROWS  (BATCHH * L_TOK)   // 18432
#define NPAD  2176               // 2128 padded to 17*128
#define NCH   9                  // 576 / 64 chunks

typedef unsigned int uint;
typedef __attribute__((ext_vector_type(8))) short bf16x8;
typedef __attribute__((ext_vector_type(4))) float f32x4;

__device__ __forceinline__ float b2f(unsigned short u) {
    union { uint i; float f; } v; v.i = ((uint)u) << 16; return v.f;
}
__device__ __forceinline__ unsigned short f2b(float x) {
    union { float f; uint i; } v; v.f = x;
    uint r = (v.i + 0x7FFFu + ((v.i >> 16) & 1u)) >> 16;
    return (unsigned short)r;
}

__device__ __forceinline__ void gload16(const unsigned short* g, unsigned short* lds) {
    __builtin_amdgcn_global_load_lds(
        (const __attribute__((address_space(1))) unsigned int*)g,
        (__attribute__((address_space(3))) unsigned int*)lds, 16, 0, 0);
}

// byte offset for [row][col] in a 64-col bf16 row (128B), 16B-slot XOR swizzle
__device__ __forceinline__ int swz64(int row, int col) {
    return row * 128 + ((((col >> 3) ^ row) & 7) << 4) + (col & 7) * 2;
}

// ---------------- RoPE tables ----------------
__global__ void rope_init(float* __restrict__ COS, float* __restrict__ SIN) {
    int i = blockIdx.x * 256 + threadIdx.x;   // L_TOK*8 = 4608
    if (i >= L_TOK * 8) return;
    int l = i >> 3, j = i & 7;
    double inv = pow(10000.0, -(double)(2 * j) / 16.0);
    double a = (double)l * inv;
    COS[i] = (float)cos(a);
    SIN[i] = (float)sin(a);
}

// ---------------- transpose + pad + bf16 convert ----------------
__global__ __launch_bounds__(256) void transpose_pad(
        const float* __restrict__ src, unsigned short* __restrict__ dst,
        int R, int C, int Cp) {
    __shared__ float tile[32][33];
    int lz = blockIdx.z;
    const float* S = src + (size_t)lz * R * C;
    unsigned short* D = dst + (size_t)lz * Cp * R;
    int c0 = blockIdx.x * 32, r0 = blockIdx.y * 32;
    int tx = threadIdx.x & 31, ty = threadIdx.x >> 5;   // 32 x 8
#pragma unroll
    for (int i = 0; i < 32; i += 8) {
        int c = c0 + tx;
        tile[ty + i][tx] = (c < C) ? S[(size_t)(r0 + ty + i) * C + c] : 0.f;
    }
    __syncthreads();
#pragma unroll
    for (int i = 0; i < 32; i += 8) {
        int cc = c0 + ty + i;
        int rr = r0 + tx;
        if (cc < Cp) D[(size_t)cc * R + rr] = f2b(tile[tx][ty + i]);
    }
}

// ---------------- f32 -> bf16 copy ----------------
__global__ void f32tobf16_kernel(const float* __restrict__ src, unsigned short* __restrict__ dst,
                                 int n) {
    int i = blockIdx.x * 256 + threadIdx.x;
    if (i < n) dst[i] = f2b(src[i]);
}

// ---------------- im2col: img[b][c][384][384] -> A[b*576+l][768] bf16 ----------------
__global__ __launch_bounds__(192) void im2col_kernel(
        const float* __restrict__ img, unsigned short* __restrict__ A) {
    int m = blockIdx.x;
    int tid = threadIdx.x;
    int b = m / L_TOK, l = m % L_TOK;
    int oy = l / 24, ox = l % 24;
    int k = tid * 4;
    int c = k >> 8, rem = k & 255, iy = rem >> 4, ix = rem & 15;
    const float* p = img + ((size_t)(b * 3 + c) * 384 + oy * 16 + iy) * 384 + ox * 16 + ix;
    float4 v = *(const float4*)p;
    ushort4 u;
    u.x = f2b(v.x); u.y = f2b(v.y); u.z = f2b(v.z); u.w = f2b(v.w);
    *(ushort4*)(A + (size_t)m * 768 + k) = u;
}

// ---------------- MFMA GEMM: patch ----------------
__global__ __launch_bounds__(256) void gemm_patch_mfma(
        const unsigned short* __restrict__ A, const unsigned short* __restrict__ Bt,
        const float* __restrict__ pb, const float* __restrict__ pos,
        float* __restrict__ X) {
    __shared__ unsigned short As[128 * 64];
    __shared__ unsigned short Bs[128 * 64];
    const int tid = threadIdx.x;
    const int l = tid & 63, w = tid >> 6;
    const int wr = w >> 1, wc = w & 1;
    const int m0 = blockIdx.y * 128, n0 = blockIdx.x * 128;
    f32x4 acc[4][4];
#pragma unroll
    for (int i = 0; i < 4; ++i)
#pragma unroll
        for (int j = 0; j < 4; ++j) acc[i][j] = (f32x4)(0.f);

    int rA[4], rB[4];
#pragma unroll
    for (int f = 0; f < 4; ++f) {
        rA[f] = wr * 64 + f * 16 + (l & 15);
        rB[f] = wc * 64 + f * 16 + (l & 15);
    }
    const char* AsB = (const char*)As;
    const char* BsB = (const char*)Bs;

    for (int k0 = 0; k0 < 768; k0 += 64) {
        __syncthreads();
#pragma unroll
        for (int i = 0; i < 4; ++i) {
            int lin = i * 256 + tid;
            int r = lin >> 3, slot = lin & 7;
            int sc = (slot ^ (r & 7)) * 8;
            gload16(A  + (size_t)(m0 + r) * 768 + k0 + sc, As + lin * 8);
            gload16(Bt + (size_t)(n0 + r) * 768 + k0 + sc, Bs + lin * 8);
        }
        __syncthreads();
#pragma unroll
        for (int kk = 0; kk < 2; ++kk) {
            bf16x8 af[4], bfr[4];
            int c16 = kk * 4 + (l >> 4);
#pragma unroll
            for (int f = 0; f < 4; ++f) {
                int row = rA[f];
                af[f] = *(const bf16x8*)(AsB + row * 128 + ((c16 ^ (row & 7)) << 4));
            }
#pragma unroll
            for (int f = 0; f < 4; ++f) {
                int row = rB[f];
                bfr[f] = *(const bf16x8*)(BsB + row * 128 + ((c16 ^ (row & 7)) << 4));
            }
#pragma unroll
            for (int mf = 0; mf < 4; ++mf)
#pragma unroll
                for (int nf = 0; nf < 4; ++nf)
                    acc[mf][nf] = __builtin_amdgcn_mfma_f32_16x16x32_bf16(
                        af[mf], bfr[nf], acc[mf][nf], 0, 0, 0);
        }
    }
#pragma unroll
    for (int mf = 0; mf < 4; ++mf)
#pragma unroll
        for (int nf = 0; nf < 4; ++nf) {
            int col = n0 + wc * 64 + nf * 16 + (l & 15);
            float pbv = pb[col];
#pragma unroll
            for (int reg = 0; reg < 4; ++reg) {
                int row = m0 + wr * 64 + mf * 16 + (l >> 4) * 4 + reg;
                int tokl = row % L_TOK;
                X[(size_t)row * DIMM + col] =
                    acc[mf][nf][reg] + pbv + pos[(size_t)tokl * DIMM + col];
            }
        }
}

// ---------------- fused LN -> bf16 ----------------
__global__ __launch_bounds__(256) void lnbf16_kernel(
        const float* __restrict__ X, const float* __restrict__ w,
        const float* __restrict__ bi, unsigned short* __restrict__ Hb) {
    int row = blockIdx.x * 4 + (threadIdx.x >> 6);
    int lane = threadIdx.x & 63;
    const float* xr = X + (size_t)row * DIMM;
    float4 u0 = *(const float4*)(xr + lane * 8);
    float4 u1 = *(const float4*)(xr + lane * 8 + 4);
    float v[8] = {u0.x, u0.y, u0.z, u0.w, u1.x, u1.y, u1.z, u1.w};
    float s = 0.f;
#pragma unroll
    for (int j = 0; j < 8; ++j) s += v[j];
#pragma unroll
    for (int o = 32; o > 0; o >>= 1) s += __shfl_xor(s, o);
    float m = s * (1.f / DIMM);
    float q = 0.f;
#pragma unroll
    for (int j = 0; j < 8; ++j) { float d = v[j] - m; q += d * d; }
#pragma unroll
    for (int o = 32; o > 0; o >>= 1) q += __shfl_xor(q, o);
    float rstd = rsqrtf(q * (1.f / DIMM) + 1e-6f);
    float4 w0 = *(const float4*)(w + lane * 8);
    float4 w1 = *(const float4*)(w + lane * 8 + 4);
    float4 b0 = *(const float4*)(bi + lane * 8);
    float4 b1 = *(const float4*)(bi + lane * 8 + 4);
    float wv[8] = {w0.x, w0.y, w0.z, w0.w, w1.x, w1.y, w1.z, w1.w};
    float bv[8] = {b0.x, b0.y, b0.z, b0.w, b1.x, b1.y, b1.z, b1.w};
    ushort4 s0, s1;
    s0.x = f2b((v[0] - m) * rstd * wv[0] + bv[0]);
    s0.y = f2b((v[1] - m) * rstd * wv[1] + bv[1]);
    s0.z = f2b((v[2] - m) * rstd * wv[2] + bv[2]);
    s0.w = f2b((v[3] - m) * rstd * wv[3] + bv[3]);
    s1.x = f2b((v[4] - m) * rstd * wv[4] + bv[4]);
    s1.y = f2b((v[5] - m) * rstd * wv[5] + bv[5]);
    s1.z = f2b((v[6] - m) * rstd * wv[6] + bv[6]);
    s1.w = f2b((v[7] - m) * rstd * wv[7] + bv[7]);
    unsigned short* orow = Hb + (size_t)row * DIMM + lane * 8;
    *(ushort4*)(orow) = s0;
    *(ushort4*)(orow + 4) = s1;
}

// ---------------- per-row mean/rstd (final LN) ----------------
__global__ __launch_bounds__(256) void rowstat_kernel(
        const float* __restrict__ X, float* __restrict__ RS) {
    int row = blockIdx.x * 4 + (threadIdx.x >> 6);
    int lane = threadIdx.x & 63;
    const float* xr = X + (size_t)row * DIMM;
    float4 u0 = *(const float4*)(xr + lane * 8);
    float4 u1 = *(const float4*)(xr + lane * 8 + 4);
    float v[8] = {u0.x, u0.y, u0.z, u0.w, u1.x, u1.y, u1.z, u1.w};
    float s = 0.f;
#pragma unroll
    for (int j = 0; j < 8; ++j) s += v[j];
#pragma unroll
    for (int o = 32; o > 0; o >>= 1) s += __shfl_xor(s, o);
    float m = s * (1.f / DIMM);
    float q = 0.f;
#pragma unroll
    for (int j = 0; j < 8; ++j) { float d = v[j] - m; q += d * d; }
#pragma unroll
    for (int o = 32; o > 0; o >>= 1) q += __shfl_xor(q, o);
    float rstd = rsqrtf(q * (1.f / DIMM) + 1e-6f);
    if (lane == 0) {
        RS[row * 2 + 0] = m;
        RS[row * 2 + 1] = rstd;
    }
}

// ---------------- MFMA GEMM: in_proj ----------------
__global__ __launch_bounds__(256) void gemm_in_mfma(
        const unsigned short* __restrict__ A,
        const unsigned short* __restrict__ Bt,
        unsigned short* __restrict__ Z, unsigned short* __restrict__ XBC,
        float* __restrict__ DTRAW) {
    __shared__ unsigned short As[128 * 64];
    __shared__ unsigned short Bs[128 * 64];
    const int tid = threadIdx.x;
    const int l = tid & 63, w = tid >> 6;
    const int wr = w >> 1, wc = w & 1;
    const int m0 = blockIdx.y * 128, n0 = blockIdx.x * 128;
    f32x4 acc[4][4];
#pragma unroll
    for (int i = 0; i < 4; ++i)
#pragma unroll
        for (int j = 0; j < 4; ++j) acc[i][j] = (f32x4)(0.f);

    int rA[4], rB[4];
#pragma unroll
    for (int f = 0; f < 4; ++f) {
        rA[f] = wr * 64 + f * 16 + (l & 15);
        rB[f] = wc * 64 + f * 16 + (l & 15);
    }
    const char* AsB = (const char*)As;
    const char* BsB = (const char*)Bs;

    for (int k0 = 0; k0 < 512; k0 += 64) {
        __syncthreads();
#pragma unroll
        for (int i = 0; i < 4; ++i) {
            int lin = i * 256 + tid;
            int r = lin >> 3, slot = lin & 7;
            int sc = (slot ^ (r & 7)) * 8;
            gload16(A  + (size_t)(m0 + r) * 512 + k0 + sc, As + lin * 8);
            gload16(Bt + (size_t)(n0 + r) * 512 + k0 + sc, Bs + lin * 8);
        }
        __syncthreads();
#pragma unroll
        for (int kk = 0; kk < 2; ++kk) {
            bf16x8 af[4], bfr[4];
            int c16 = kk * 4 + (l >> 4);
#pragma unroll
            for (int f = 0; f < 4; ++f) {
                int row = rA[f];
                af[f] = *(const bf16x8*)(AsB + row * 128 + ((c16 ^ (row & 7)) << 4));
            }
#pragma unroll
            for (int f = 0; f < 4; ++f) {
                int row = rB[f];
                bfr[f] = *(const bf16x8*)(BsB + row * 128 + ((c16 ^ (row & 7)) << 4));
            }
#pragma unroll
            for (int mf = 0; mf < 4; ++mf)
#pragma unroll
                for (int nf = 0; nf < 4; ++nf)
                    acc[mf][nf] = __builtin_amdgcn_mfma_f32_16x16x32_bf16(
                        af[mf], bfr[nf], acc[mf][nf], 0, 0, 0);
        }
    }
#pragma unroll
    for (int mf = 0; mf < 4; ++mf)
#pragma unroll
        for (int nf = 0; nf < 4; ++nf) {
            int col = n0 + wc * 64 + nf * 16 + (l & 15);
#pragma unroll
            for (int reg = 0; reg < 4; ++reg) {
                int row = m0 + wr * 64 + mf * 16 + (l >> 4) * 4 + reg;
                float v = acc[mf][nf][reg];
                if (col < DINN)             Z[(size_t)row * DINN + col] = f2b(v);
                else if (col < DINN + CONVD) XBC[(size_t)row * CONVD + (col - DINN)] = f2b(v);
                else if (col < DPROJJ)       DTRAW[(size_t)row * NHH + (col - DINN - CONVD)] = v;
            }
        }
}

// ---------------- MFMA GEMM: out_proj, X += ----------------
__global__ __launch_bounds__(256) void gemm_out_mfma(
        const unsigned short* __restrict__ A,
        const unsigned short* __restrict__ Bt,
        float* __restrict__ X) {
    __shared__ unsigned short As[128 * 64];
    __shared__ unsigned short Bs[128 * 64];
    const int tid = threadIdx.x;
    const int l = tid & 63, w = tid >> 6;
    const int wr = w >> 1, wc = w & 1;
    const int m0 = blockIdx.y * 128, n0 = blockIdx.x * 128;
    f32x4 acc[4][4];
#pragma unroll
    for (int i = 0; i < 4; ++i)
#pragma unroll
        for (int j = 0; j < 4; ++j) acc[i][j] = (f32x4)(0.f);

    int rA[4], rB[4];
#pragma unroll
    for (int f = 0; f < 4; ++f) {
        rA[f] = wr * 64 + f * 16 + (l & 15);
        rB[f] = wc * 64 + f * 16 + (l & 15);
    }
    const char* AsB = (const char*)As;
    const char* BsB = (const char*)Bs;

    for (int k0 = 0; k0 < 1024; k0 += 64) {
        __syncthreads();
#pragma unroll
        for (int i = 0; i < 4; ++i) {
            int lin = i * 256 + tid;
            int r = lin >> 3, slot = lin & 7;
            int sc = (slot ^ (r & 7)) * 8;
            gload16(A  + (size_t)(m0 + r) * 1024 + k0 + sc, As + lin * 8);
            gload16(Bt + (size_t)(n0 + r) * 1024 + k0 + sc, Bs + lin * 8);
        }
        __syncthreads();
#pragma unroll
        for (int kk = 0; kk < 2; ++kk) {
            bf16x8 af[4], bfr[4];
            int c16 = kk * 4 + (l >> 4);
#pragma unroll
            for (int f = 0; f < 4; ++f) {
                int row = rA[f];
                af[f] = *(const bf16x8*)(AsB + row * 128 + ((c16 ^ (row & 7)) << 4));
            }
#pragma unroll
            for (int f = 0; f < 4; ++f) {
                int row = rB[f];
                bfr[f] = *(const bf16x8*)(BsB + row * 128 + ((c16 ^ (row & 7)) << 4));
            }
#pragma unroll
            for (int mf = 0; mf < 4; ++mf)
#pragma unroll
                for (int nf = 0; nf < 4; ++nf)
                    acc[mf][nf] = __builtin_amdgcn_mfma_f32_16x16x32_bf16(
                        af[mf], bfr[nf], acc[mf][nf], 0, 0, 0);
        }
    }
#pragma unroll
    for (int mf = 0; mf < 4; ++mf)
#pragma unroll
        for (int nf = 0; nf < 4; ++nf) {
            int col = n0 + wc * 64 + nf * 16 + (l & 15);
#pragma unroll
            for (int reg = 0; reg < 4; ++reg) {
                int row = m0 + wr * 64 + mf * 16 + (l >> 4) * 4 + reg;
                float* p = X + (size_t)row * DIMM + col;
                *p += acc[mf][nf][reg];
            }
        }
}

// ---------------- Causal depthwise conv + silu + rope split, LDS-tiled ----------------
__global__ __launch_bounds__(256) void conv_kernel(
        const unsigned short* __restrict__ XBC, const float* __restrict__ cw,
        const float* __restrict__ cb,
        const float* __restrict__ Bb, const float* __restrict__ Cb,
        const float* __restrict__ COS, const float* __restrict__ SIN,
        unsigned short* __restrict__ XS, float* __restrict__ BM, float* __restrict__ CM) {
    __shared__ unsigned short sh[35][128];
    int tileIdx = blockIdx.x;
    int c0 = blockIdx.y * 128;
    int b = tileIdx / 18, lt = tileIdx % 18;
    int l0 = lt * 32;
    int r0 = b * L_TOK + l0;

    for (int idx = threadIdx.x; idx < 35 * 128; idx += 256) {
        int row = idx >> 7, col = idx & 127;
        int t = l0 - 3 + row;
        int c = c0 + col;
        unsigned short v = 0;
        if (t >= 0 && c < CONVD)
            v = XBC[(size_t)(b * L_TOK + t) * CONVD + c];
        sh[row][col] = v;
    }
    __syncthreads();

    int tx = threadIdx.x & 127, ty = threadIdx.x >> 7;
    int c = c0 + tx;
    if (c >= CONVD) return;
    float w0 = cw[c * 4 + 0], w1 = cw[c * 4 + 1], w2 = cw[c * 4 + 2], w3 = cw[c * 4 + 3];
    float bias = cb[c];

    if (c < DINN) {
#pragma unroll
        for (int i = 0; i < 16; ++i) {
            int t = ty * 16 + i;
            float acc = w0 * b2f(sh[t][tx]) + w1 * b2f(sh[t + 1][tx])
                      + w2 * b2f(sh[t + 2][tx]) + w3 * b2f(sh[t + 3][tx]);
            float v = acc + bias;
            v = v / (1.f + expf(-v));
            XS[(size_t)(r0 + t) * DINN + c] = f2b(v);
        }
    } else {
        int j = c - DINN;
        int jj = j & 31;
        bool isB = j < 32;
        float bias2 = isB ? Bb[jj] : Cb[jj];
        int i0 = jj & 7;
#pragma unroll
        for (int i = 0; i < 16; ++i) {
            int t = ty * 16 + i;
            int lglob = l0 + t;
            float acc = w0 * b2f(sh[t][tx]) + w1 * b2f(sh[t + 1][tx])
                      + w2 * b2f(sh[t + 2][tx]) + w3 * b2f(sh[t + 3][tx]);
            float v = acc + bias;
            v = v / (1.f + expf(-v));
            float v2 = v + bias2;
            float partner = __shfl_xor(v2, 8);
            float outv;
            if (jj < 16) {
                float cs = COS[lglob * 8 + i0], sn = SIN[lglob * 8 + i0];
                outv = (jj < 8) ? (v2 * cs - partner * sn) : (partner * sn + v2 * cs);
            } else {
                outv = v2;
            }
            if (isB) BM[(size_t)(r0 + t) * NSTT + jj] = outv;
            else     CM[(size_t)(r0 + t) * NSTT + jj] = outv;
        }
    }
}

// ---------------- chunked scan pass A: MFMA SSD intra-chunk ----------------
// One 64-lane wave per (chunk, b, h).
// W = mask(C·B^T); y_local = W·X; S_c = (u∘X)^T·B
__global__ __launch_bounds__(64) void scanA_kernel(
        unsigned short* __restrict__ XSY,
        const float* __restrict__ DTRAW, const float* __restrict__ dtb,
        const float* __restrict__ Alog,
        const float* __restrict__ BM, const float* __restrict__ CM,
        const float* __restrict__ Dsk,
        float* __restrict__ SC, float* __restrict__ ET, float* __restrict__ ECH) {
    int c = blockIdx.x, bh = blockIdx.y;
    int b = bh >> 4, h = bh & 15;
    int l = threadIdx.x;
    int r0 = b * L_TOK + c * 64;

    __shared__ unsigned short Wl[64 * 64];   // swizzled [t][s]; reused for Y [t][p]
    __shared__ unsigned short XT[64 * 64];   // swizzled [p][s]; reused for u∘X
    __shared__ unsigned short BT[32 * 64];   // swizzled [n][s]
    __shared__ float Lsh[64];
    __shared__ float dtsh[64];

    // ---- dt, log-decay inclusive prefix ----
    float raw = DTRAW[(size_t)(r0 + l) * NHH + h] + dtb[h];
    float dtl = fmaxf(raw, 0.f) + log1pf(expf(-fabsf(raw)));
    float L = -expf(Alog[h]) * dtl;
#pragma unroll
    for (int off = 1; off < 64; off <<= 1) {
        float v = __shfl_up(L, off);
        if (l >= off) L += v;
    }
    float LEND = __shfl(L, 63);
    ET[(size_t)bh * L_TOK + c * 64 + l] = __expf(L);
    if (l == 0) ECH[bh * NCH + c] = __expf(LEND);
    Lsh[l] = L;
    dtsh[l] = dtl;
    float ul = __expf(LEND - L) * dtl;
    float dsk = Dsk[h];

    // ---- W = C · B^T  (M=t, N=s, K=32) ----
    bf16x8 cf[4], bq[4];
#pragma unroll
    for (int f = 0; f < 4; ++f) {
        const float* cp = CM + (size_t)(r0 + f * 16 + (l & 15)) * NSTT + (l >> 4) * 8;
        const float* bp = BM + (size_t)(r0 + f * 16 + (l & 15)) * NSTT + (l >> 4) * 8;
        float4 c0 = *(const float4*)cp, c1 = *(const float4*)(cp + 4);
        float4 b0 = *(const float4*)bp, b1 = *(const float4*)(bp + 4);
        bf16x8 cv, bv;
        cv[0]=(short)f2b(c0.x); cv[1]=(short)f2b(c0.y); cv[2]=(short)f2b(c0.z); cv[3]=(short)f2b(c0.w);
        cv[4]=(short)f2b(c1.x); cv[5]=(short)f2b(c1.y); cv[6]=(short)f2b(c1.z); cv[7]=(short)f2b(c1.w);
        bv[0]=(short)f2b(b0.x); bv[1]=(short)f2b(b0.y); bv[2]=(short)f2b(b0.z); bv[3]=(short)f2b(b0.w);
        bv[4]=(short)f2b(b1.x); bv[5]=(short)f2b(b1.y); bv[6]=(short)f2b(b1.z); bv[7]=(short)f2b(b1.w);
        cf[f] = cv; bq[f] = bv;
    }
    f32x4 acc[4][4];
#pragma unroll
    for (int i = 0; i < 4; ++i)
#pragma unroll
        for (int j = 0; j < 4; ++j) acc[i][j] = (f32x4)(0.f);
#pragma unroll
    for (int mf = 0; mf < 4; ++mf)
#pragma unroll
        for (int nf = 0; nf < 4; ++nf)
            acc[mf][nf] = __builtin_amdgcn_mfma_f32_16x16x32_bf16(cf[mf], bq[nf], acc[mf][nf], 0, 0, 0);

    // ---- mask/scale, bf16, swizzled store ----
    __builtin_amdgcn_wave_barrier();
#pragma unroll
    for (int nf = 0; nf < 4; ++nf) {
        int s = nf * 16 + (l & 15);
        float Ls = Lsh[s], dts = dtsh[s];
#pragma unroll
        for (int mf = 0; mf < 4; ++mf) {
#pragma unroll
            for (int reg = 0; reg < 4; ++reg) {
                int t = mf * 16 + (l >> 4) * 4 + reg;
                float Lt = Lsh[t];
                float v = acc[mf][nf][reg];
                float wv = (s <= t) ? __expf(Lt - Ls) * dts * v : 0.f;
                if (s == t) wv += dsk;
                *(unsigned short*)((char*)Wl + swz64(t, s)) = f2b(wv);
            }
        }
    }

    // ---- stage X row (this lane's token) + transpose to XT[p][s] ----
    uint xw[32];
    {
        const uint* xp = (const uint*)(XSY + (size_t)(r0 + l) * DINN + h * HDD);
#pragma unroll
        for (int i = 0; i < 8; ++i) {
            uint4 v = *(const uint4*)(xp + i * 4);
            xw[i*4+0]=v.x; xw[i*4+1]=v.y; xw[i*4+2]=v.z; xw[i*4+3]=v.w;
        }
    }
#pragma unroll
    for (int p = 0; p < 64; ++p) {
        unsigned short xv = (p & 1) ? (unsigned short)(xw[p >> 1] >> 16)
                                    : (unsigned short)(xw[p >> 1] & 0xffffu);
        *(unsigned short*)((char*)XT + swz64(p, l)) = xv;
    }
    __builtin_amdgcn_wave_barrier();

    // ---- Y = W · X  (M=t, N=p, K=64) ----
    f32x4 yacc[4][4];
#pragma unroll
    for (int i = 0; i < 4; ++i)
#pragma unroll
        for (int j = 0; j < 4; ++j) yacc[i][j] = (f32x4)(0.f);
#pragma unroll
    for (int kk = 0; kk < 2; ++kk) {
        int slot = kk * 4 + (l >> 4);
        bf16x8 wf[4], xf[4];
#pragma unroll
        for (int f = 0; f < 4; ++f) {
            int rw = f * 16 + (l & 15);
            wf[f] = *(const bf16x8*)((const char*)Wl + rw * 128 + (((slot ^ rw) & 7) << 4));
            xf[f] = *(const bf16x8*)((const char*)XT + rw * 128 + (((slot ^ rw) & 7) << 4));
        }
#pragma unroll
        for (int mf = 0; mf < 4; ++mf)
#pragma unroll
            for (int nf = 0; nf < 4; ++nf)
                yacc[mf][nf] = __builtin_amdgcn_mfma_f32_16x16x32_bf16(
                    wf[mf], xf[nf], yacc[mf][nf], 0, 0, 0);
    }

    // ---- Y -> Wl (reuse), coalesced store back to XSY ----
    __builtin_amdgcn_wave_barrier();
#pragma unroll
    for (int mf = 0; mf < 4; ++mf)
#pragma unroll
        for (int nf = 0; nf < 4; ++nf)
#pragma unroll
            for (int reg = 0; reg < 4; ++reg) {
                int t = mf * 16 + (l >> 4) * 4 + reg;
                int p = nf * 16 + (l & 15);
                *(unsigned short*)((char*)Wl + swz64(t, p)) = f2b(yacc[mf][nf][reg]);
            }
    __builtin_amdgcn_wave_barrier();
    {
        unsigned short* yp = XSY + (size_t)(r0 + l) * DINN + h * HDD;
#pragma unroll
        for (int j = 0; j < 8; ++j) {
            uint4 v = *(const uint4*)((const char*)Wl + l * 128 + (((j ^ l) & 7) << 4));
            *(uint4*)(yp + j * 8) = v;
        }
    }

    // ---- S = (u∘X)^T · B  (M=p, N=n(32), K=64): u∘X into XT region, B^T into BT ----
    __builtin_amdgcn_wave_barrier();
#pragma unroll
    for (int p = 0; p < 64; ++p) {
        unsigned short xv = (p & 1) ? (unsigned short)(xw[p >> 1] >> 16)
                                    : (unsigned short)(xw[p >> 1] & 0xffffu);
        *(unsigned short*)((char*)XT + swz64(p, l)) = f2b(b2f(xv) * ul);
    }
    {
        const float* bp = BM + (size_t)(r0 + l) * NSTT;
#pragma unroll
        for (int n = 0; n < 32; n += 4) {
            float4 v = *(const float4*)(bp + n);
            *(unsigned short*)((char*)BT + swz64(n + 0, l)) = f2b(v.x);
            *(unsigned short*)((char*)BT + swz64(n + 1, l)) = f2b(v.y);
            *(unsigned short*)((char*)BT + swz64(n + 2, l)) = f2b(v.z);
            *(unsigned short*)((char*)BT + swz64(n + 3, l)) = f2b(v.w);
        }
    }
    __builtin_amdgcn_wave_barrier();
    f32x4 sacc[4][2];
#pragma unroll
    for (int i = 0; i < 4; ++i)
#pragma unroll
        for (int j = 0; j < 2; ++j) sacc[i][j] = (f32x4)(0.f);
#pragma unroll
    for (int kk = 0; kk < 2; ++kk) {
        int slot = kk * 4 + (l >> 4);
        bf16x8 uf[4], btf[2];
#pragma unroll
        for (int f = 0; f < 4; ++f) {
            int rw = f * 16 + (l & 15);
            uf[f] = *(const bf16x8*)((const char*)XT + rw * 128 + (((slot ^ rw) & 7) << 4));
        }
#pragma unroll
        for (int f = 0; f < 2; ++f) {
            int rw = f * 16 + (l & 15);
            btf[f] = *(const bf16x8*)((const char*)BT + rw * 128 + (((slot ^ rw) & 7) << 4));
        }
#pragma unroll
        for (int mf = 0; mf < 4; ++mf)
#pragma unroll
            for (int nf = 0; nf < 2; ++nf)
                sacc[mf][nf] = __builtin_amdgcn_mfma_f32_16x16x32_bf16(
                    uf[mf], btf[nf], sacc[mf][nf], 0, 0, 0);
    }
    {
        float* sp = SC + (size_t)(bh * NCH + c) * 64 * 32;
#pragma unroll
        for (int mf = 0; mf < 4; ++mf)
#pragma unroll
            for (int nf = 0; nf < 2; ++nf)
#pragma unroll
                for (int reg = 0; reg < 4; ++reg) {
                    int p = mf * 16 + (l >> 4) * 4 + reg;
                    int n = nf * 16 + (l & 15);
                    sp[p * 32 + n] = sacc[mf][nf][reg];
                }
    }
}

// ---------------- pass B: sequential over 9 chunks; SC slot becomes H_start ----------------
__global__ __launch_bounds__(64) void scanB_kernel(
        float* __restrict__ SC, const float* __restrict__ ECH) {
    int bh = blockIdx.x;
    int p = threadIdx.x;
    float H[32];
#pragma unroll
    for (int n = 0; n < 32; ++n) H[n] = 0.f;
    for (int c = 0; c < NCH; ++c) {
        float e = ECH[bh * NCH + c];
        float* sp = SC + ((size_t)(bh * NCH + c) * 64 + p) * 32;
        float s[32];
#pragma unroll
        for (int n4 = 0; n4 < 8; ++n4) {
            float4 v = *(const float4*)(sp + n4 * 4);
            s[n4*4+0]=v.x; s[n4*4+1]=v.y; s[n4*4+2]=v.z; s[n4*4+3]=v.w;
        }
#pragma unroll
        for (int n4 = 0; n4 < 8; ++n4)
            *(float4*)(sp + n4 * 4) = make_float4(H[n4*4+0], H[n4*4+1], H[n4*4+2], H[n4*4+3]);
#pragma unroll
        for (int n = 0; n < 32; ++n) H[n] = e * H[n] + s[n];
    }
}

// ---------------- pass C: y += exp(L_t) C_t . H_start ----------------
__global__ __launch_bounds__(64) void scanC_kernel(
        unsigned short* __restrict__ XSY, const float* __restrict__ SC,
        const float* __restrict__ CM, const float* __restrict__ ET) {
    int c = blockIdx.x, bh = blockIdx.y;
    int b = bh >> 4, h = bh & 15;
    int l = threadIdx.x;
    int r0 = b * L_TOK + c * 64;
    __shared__ float CEsh[64][36];
#pragma unroll
    for (int i = 0; i < 32; ++i) {
        int idx = i * 64 + l;
        int t = idx >> 5, n = idx & 31;
        CEsh[t][n] = CM[(size_t)(r0 + t) * NSTT + n] * ET[(size_t)bh * L_TOK + c * 64 + t];
    }
    const float* hp = SC + ((size_t)(bh * NCH + c) * 64 + l) * 32;
    float H[32];
#pragma unroll
    for (int n4 = 0; n4 < 8; ++n4) {
        float4 v = *(const float4*)(hp + n4 * 4);
        H[n4*4+0]=v.x; H[n4*4+1]=v.y; H[n4*4+2]=v.z; H[n4*4+3]=v.w;
    }
    __builtin_amdgcn_wave_barrier();
    unsigned short* yp = XSY + (size_t)r0 * DINN + h * HDD + l;
    for (int t = 0; t < 64; ++t) {
        float acc = 0.f;
#pragma unroll
        for (int n4 = 0; n4 < 8; ++n4) {
            float4 ce = *(const float4*)&CEsh[t][n4 * 4];
            acc += ce.x * H[n4*4+0] + ce.y * H[n4*4+1]
                 + ce.z * H[n4*4+2] + ce.w * H[n4*4+3];
        }
        float y = b2f(yp[(size_t)t * DINN]) + acc;
        yp[(size_t)t * DINN] = f2b(y);
    }
}

// ---------------- gate with silu(z) + RMSNorm(1024) * gn_w ----------------
__global__ __launch_bounds__(256) void rmsgate_kernel(
        unsigned short* __restrict__ Y, const unsigned short* __restrict__ Z,
        const float* __restrict__ gw) {
    int row = blockIdx.x * 4 + (threadIdx.x >> 6);
    int lane = threadIdx.x & 63;
    unsigned short* yr = Y + (size_t)row * DINN + lane * 16;
    const unsigned short* zr = Z + (size_t)row * DINN + lane * 16;
    float g[16];
    float q = 0.f;
#pragma unroll
    for (int i = 0; i < 16; ++i) {
        float yv = b2f(yr[i]);
        float zv = b2f(zr[i]);
        float gz = zv / (1.f + expf(-zv));
        g[i] = yv * gz;
        q += g[i] * g[i];
    }
#pragma unroll
    for (int o = 32; o > 0; o >>= 1) q += __shfl_xor(q, o);
    float sc = rsqrtf(q * (1.f / DINN) + 1e-6f);
#pragma unroll
    for (int i = 0; i < 16; ++i) {
        float wv = gw[lane * 16 + i];
        yr[i] = f2b(g[i] * sc * wv);
    }
}

// ---------------- final fused LN + mean over L ----------------
__global__ void lnmean_kernel(const float* __restrict__ X, const float* __restrict__ RS,
                              const float* __restrict__ nw, const float* __restrict__ nb,
                              float* __restrict__ MEAN) {
    int b = blockIdx.x >> 1;
    int d = (blockIdx.x & 1) * 256 + threadIdx.x;
    float w = nw[d], bb = nb[d];
    const float* p = X + (size_t)b * L_TOK * DIMM + d;
    const float* rs = RS + (size_t)b * L_TOK * 2;
    float s = 0.f;
    for (int l = 0; l < L_TOK; ++l) {
        float m = rs[l * 2 + 0], r = rs[l * 2 + 1];
        s += (p[(size_t)l * DIMM] - m) * r * w + bb;
    }
    MEAN[b * DIMM + d] = s * (1.f / L_TOK);
}

// ---------------- head ----------------
__global__ void head_kernel(const float* __restrict__ MEAN, const float* __restrict__ hw,
                            const float* __restrict__ hb, float* __restrict__ out) {
    int t = threadIdx.x;
    if (t >= 64) return;
    int b = t >> 1, c = t & 1;
    float s = 0.f;
    for (int k = 0; k < DIMM; ++k) s += MEAN[b * DIMM + k] * hw[k * 2 + c];
    out[b * 2 + c] = s + hb[c];
}

extern "C" void kernel_launch(void* const* d_in, const int* in_sizes, int n_in,
                              void* d_out, int out_size, void* d_ws, size_t ws_size,
                              hipStream_t stream) {
    const float* x_img   = (const float*)d_in[0];
    const float* patch_w = (const float*)d_in[1];
    const float* patch_b = (const float*)d_in[2];
    const float* pos     = (const float*)d_in[3];
    const float* ln_w    = (const float*)d_in[4];
    const float* ln_b    = (const float*)d_in[5];
    const float* Wp      = (const float*)d_in[6];
    const float* cw      = (const float*)d_in[7];
    const float* cb      = (const float*)d_in[8];
    const float* dtb     = (const float*)d_in[9];
    const float* Alog    = (const float*)d_in[10];
    const float* Dsk     = (const float*)d_in[11];
    const float* Bb      = (const float*)d_in[12];
    const float* Cb      = (const float*)d_in[13];
    const float* gnw     = (const float*)d_in[14];
    const float* Wo      = (const float*)d_in[15];
    const float* nw      = (const float*)d_in[16];
    const float* nb      = (const float*)d_in[17];
    const float* hw      = (const float*)d_in[18];
    const float* hb      = (const float*)d_in[19];
    float* out = (float*)d_out;

    char* base = (char*)d_ws;
    size_t off = 0;
    auto alloc = [&](size_t bytes) -> char* {
        char* p = base + off;
        off += (bytes + 255) & ~(size_t)255;
        return p;
    };
    float*          X     = (float*)alloc((size_t)ROWS * DIMM * 4);
    unsigned short* XBC   = (unsigned short*)alloc((size_t)ROWS * CONVD * 2);
    unsigned short* Z     = (unsigned short*)alloc((size_t)ROWS * DINN * 2);
    unsigned short* XSY   = (unsigned short*)alloc((size_t)ROWS * DINN * 2);
    unsigned short* Hb    = (unsigned short*)alloc((size_t)ROWS * DIMM * 2);
    unsigned short* WpT   = (unsigned short*)alloc((size_t)8 * NPAD * DIMM * 2);
    unsigned short* WoT   = (unsigned short*)alloc((size_t)8 * DIMM * DINN * 2);
    float*          DTRAW = (float*)alloc((size_t)ROWS * NHH * 4);
    float*          BMp   = (float*)alloc((size_t)ROWS * NSTT * 4);
    float*          CMp   = (float*)alloc((size_t)ROWS * NSTT * 4);
    float*          RS    = (float*)alloc((size_t)ROWS * 2 * 4);
    float*          COS   = (float*)alloc((size_t)L_TOK * 8 * 4);
    float*          SIN   = (float*)alloc((size_t)L_TOK * 8 * 4);
    float*          MEAN  = (float*)alloc((size_t)BATCHH * DIMM * 4);
    float*          ET    = (float*)alloc((size_t)BATCHH * NHH * L_TOK * 4);
    float*          ECH   = (float*)alloc((size_t)BATCHH * NHH * NCH * 4);
    unsigned short* AIM   = XBC;          // im2col A aliases XBC
    unsigned short* PWB   = Z;            // patch weight bf16 aliases Z
    float*          SCp   = (float*)XBC;  // chunk states alias XBC
    if (off > ws_size) return;

    rope_init<<<18, 256, 0, stream>>>(COS, SIN);
    transpose_pad<<<dim3(NPAD / 32, DIMM / 32, 8), 256, 0, stream>>>(Wp, WpT, DIMM, DPROJJ, NPAD);
    transpose_pad<<<dim3(DIMM / 32, DINN / 32, 8), 256, 0, stream>>>(Wo, WoT, DINN, DIMM, DIMM);

    f32tobf16_kernel<<<(512 * 768 + 255) / 256, 256, 0, stream>>>(patch_w, PWB, 512 * 768);
    im2col_kernel<<<ROWS, 192, 0, stream>>>(x_img, AIM);
    gemm_patch_mfma<<<dim3(4, 144), 256, 0, stream>>>(AIM, PWB, patch_b, pos, X);

    for (int i = 0; i < 8; ++i) {
        lnbf16_kernel<<<ROWS / 4, 256, 0, stream>>>(X, ln_w + i * DIMM, ln_b + i * DIMM, Hb);
        gemm_in_mfma<<<dim3(NPAD / 128, ROWS / 128), 256, 0, stream>>>(
            Hb, WpT + (size_t)i * NPAD * DIMM, Z, XBC, DTRAW);
        conv_kernel<<<dim3(BATCHH * 18, 9), 256, 0, stream>>>(
            XBC, cw + (size_t)i * CONVD * 4, cb + (size_t)i * CONVD,
            Bb + i * NSTT, Cb + i * NSTT, COS, SIN, XSY, BMp, CMp);
        scanA_kernel<<<dim3(NCH, BATCHH * NHH), 64, 0, stream>>>(
            XSY, DTRAW, dtb + i * NHH, Alog + i * NHH, BMp, CMp, Dsk + i * NHH, SCp, ET, ECH);
        scanB_kernel<<<BATCHH * NHH, 64, 0, stream>>>(SCp, ECH);
        scanC_kernel<<<dim3(NCH, BATCHH * NHH), 64, 0, stream>>>(XSY, SCp, CMp, ET);
        rmsgate_kernel<<<ROWS / 4, 256, 0, stream>>>(XSY, Z, gnw + (size_t)i * DINN);
        gemm_out_mfma<<<dim3(DIMM / 128, ROWS / 128), 256, 0, stream>>>(
            XSY, WoT + (size_t)i * DIMM * DINN, X);
    }

    rowstat_kernel<<<ROWS / 4, 256, 0, stream>>>(X, RS);
    lnmean_kernel<<<64, 256, 0, stream>>>(X, RS, nw, nb, MEAN);
    head_kernel<<<1, 64, 0, stream>>>(MEAN, hw, hb, out);
}

// Round 7
// 2664.786 us; speedup vs baseline: 4.3586x; 1.0443x over previous
//
#include <hip/hip_runtime.h>
#include <cmath>

#define L_TOK 576
#define DIMM  512
#define DINN  1024
#define NHH   16
#define HDD   64
#define NSTT  32
#define CONVD 1088
#define DPROJJ 2128
#define BATCHH 32
#define ROWS  (BATCHH * L_TOK)   // 18432
#define NPAD  2176               // 2128 padded to 17*128
#define NCH   9                  // 576 / 64 chunks

typedef unsigned int uint;
typedef __attribute__((ext_vector_type(8))) short bf16x8;
typedef __attribute__((ext_vector_type(4))) float f32x4;

__device__ __forceinline__ float b2f(unsigned short u) {
    union { uint i; float f; } v; v.i = ((uint)u) << 16; return v.f;
}
__device__ __forceinline__ unsigned short f2b(float x) {
    union { float f; uint i; } v; v.f = x;
    uint r = (v.i + 0x7FFFu + ((v.i >> 16) & 1u)) >> 16;
    return (unsigned short)r;
}

__device__ __forceinline__ void gload16(const unsigned short* g, unsigned short* lds) {
    __builtin_amdgcn_global_load_lds(
        (const __attribute__((address_space(1))) unsigned int*)g,
        (__attribute__((address_space(3))) unsigned int*)lds, 16, 0, 0);
}

// byte offset for [row][col] in a 64-col bf16 row (128B), 16B-slot XOR swizzle
__device__ __forceinline__ int swz64(int row, int col) {
    return row * 128 + ((((col >> 3) ^ row) & 7) << 4) + (col & 7) * 2;
}

// ---------------- RoPE tables ----------------
__global__ void rope_init(float* __restrict__ COS, float* __restrict__ SIN) {
    int i = blockIdx.x * 256 + threadIdx.x;   // L_TOK*8 = 4608
    if (i >= L_TOK * 8) return;
    int l = i >> 3, j = i & 7;
    double inv = pow(10000.0, -(double)(2 * j) / 16.0);
    double a = (double)l * inv;
    COS[i] = (float)cos(a);
    SIN[i] = (float)sin(a);
}

// ---------------- transpose + pad + bf16 convert ----------------
__global__ __launch_bounds__(256) void transpose_pad(
        const float* __restrict__ src, unsigned short* __restrict__ dst,
        int R, int C, int Cp) {
    __shared__ float tile[32][33];
    int lz = blockIdx.z;
    const float* S = src + (size_t)lz * R * C;
    unsigned short* D = dst + (size_t)lz * Cp * R;
    int c0 = blockIdx.x * 32, r0 = blockIdx.y * 32;
    int tx = threadIdx.x & 31, ty = threadIdx.x >> 5;   // 32 x 8
#pragma unroll
    for (int i = 0; i < 32; i += 8) {
        int c = c0 + tx;
        tile[ty + i][tx] = (c < C) ? S[(size_t)(r0 + ty + i) * C + c] : 0.f;
    }
    __syncthreads();
#pragma unroll
    for (int i = 0; i < 32; i += 8) {
        int cc = c0 + ty + i;
        int rr = r0 + tx;
        if (cc < Cp) D[(size_t)cc * R + rr] = f2b(tile[tx][ty + i]);
    }
}

// ---------------- f32 -> bf16 copy ----------------
__global__ void f32tobf16_kernel(const float* __restrict__ src, unsigned short* __restrict__ dst,
                                 int n) {
    int i = blockIdx.x * 256 + threadIdx.x;
    if (i < n) dst[i] = f2b(src[i]);
}

// ---------------- im2col: img[b][c][384][384] -> A[b*576+l][768] bf16 ----------------
__global__ __launch_bounds__(192) void im2col_kernel(
        const float* __restrict__ img, unsigned short* __restrict__ A) {
    int m = blockIdx.x;
    int tid = threadIdx.x;
    int b = m / L_TOK, l = m % L_TOK;
    int oy = l / 24, ox = l % 24;
    int k = tid * 4;
    int c = k >> 8, rem = k & 255, iy = rem >> 4, ix = rem & 15;
    const float* p = img + ((size_t)(b * 3 + c) * 384 + oy * 16 + iy) * 384 + ox * 16 + ix;
    float4 v = *(const float4*)p;
    ushort4 u;
    u.x = f2b(v.x); u.y = f2b(v.y); u.z = f2b(v.z); u.w = f2b(v.w);
    *(ushort4*)(A + (size_t)m * 768 + k) = u;
}

// ---------------- MFMA GEMM: patch (linear grid, XCD swizzle: 576 blocks) ----------------
__global__ __launch_bounds__(256) void gemm_patch_mfma(
        const unsigned short* __restrict__ A, const unsigned short* __restrict__ Bt,
        const float* __restrict__ pb, const float* __restrict__ pos,
        float* __restrict__ X) {
    __shared__ unsigned short As[128 * 64];
    __shared__ unsigned short Bs[128 * 64];
    const int tid = threadIdx.x;
    const int l = tid & 63, w = tid >> 6;
    const int wr = w >> 1, wc = w & 1;
    int swz = (blockIdx.x & 7) * 72 + (blockIdx.x >> 3);   // 576 = 8*72
    const int m0 = (swz >> 2) * 128, n0 = (swz & 3) * 128;
    f32x4 acc[4][4];
#pragma unroll
    for (int i = 0; i < 4; ++i)
#pragma unroll
        for (int j = 0; j < 4; ++j) acc[i][j] = (f32x4)(0.f);

    int rA[4], rB[4];
#pragma unroll
    for (int f = 0; f < 4; ++f) {
        rA[f] = wr * 64 + f * 16 + (l & 15);
        rB[f] = wc * 64 + f * 16 + (l & 15);
    }
    const char* AsB = (const char*)As;
    const char* BsB = (const char*)Bs;

    for (int k0 = 0; k0 < 768; k0 += 64) {
        __syncthreads();
#pragma unroll
        for (int i = 0; i < 4; ++i) {
            int lin = i * 256 + tid;
            int r = lin >> 3, slot = lin & 7;
            int sc = (slot ^ (r & 7)) * 8;
            gload16(A  + (size_t)(m0 + r) * 768 + k0 + sc, As + lin * 8);
            gload16(Bt + (size_t)(n0 + r) * 768 + k0 + sc, Bs + lin * 8);
        }
        __syncthreads();
#pragma unroll
        for (int kk = 0; kk < 2; ++kk) {
            bf16x8 af[4], bfr[4];
            int c16 = kk * 4 + (l >> 4);
#pragma unroll
            for (int f = 0; f < 4; ++f) {
                int row = rA[f];
                af[f] = *(const bf16x8*)(AsB + row * 128 + ((c16 ^ (row & 7)) << 4));
            }
#pragma unroll
            for (int f = 0; f < 4; ++f) {
                int row = rB[f];
                bfr[f] = *(const bf16x8*)(BsB + row * 128 + ((c16 ^ (row & 7)) << 4));
            }
#pragma unroll
            for (int mf = 0; mf < 4; ++mf)
#pragma unroll
                for (int nf = 0; nf < 4; ++nf)
                    acc[mf][nf] = __builtin_amdgcn_mfma_f32_16x16x32_bf16(
                        af[mf], bfr[nf], acc[mf][nf], 0, 0, 0);
        }
    }
#pragma unroll
    for (int mf = 0; mf < 4; ++mf)
#pragma unroll
        for (int nf = 0; nf < 4; ++nf) {
            int col = n0 + wc * 64 + nf * 16 + (l & 15);
            float pbv = pb[col];
#pragma unroll
            for (int reg = 0; reg < 4; ++reg) {
                int row = m0 + wr * 64 + mf * 16 + (l >> 4) * 4 + reg;
                int tokl = row % L_TOK;
                X[(size_t)row * DIMM + col] =
                    acc[mf][nf][reg] + pbv + pos[(size_t)tokl * DIMM + col];
            }
        }
}

// ---------------- fused LN -> bf16 ----------------
__global__ __launch_bounds__(256) void lnbf16_kernel(
        const float* __restrict__ X, const float* __restrict__ w,
        const float* __restrict__ bi, unsigned short* __restrict__ Hb) {
    int row = blockIdx.x * 4 + (threadIdx.x >> 6);
    int lane = threadIdx.x & 63;
    const float* xr = X + (size_t)row * DIMM;
    float4 u0 = *(const float4*)(xr + lane * 8);
    float4 u1 = *(const float4*)(xr + lane * 8 + 4);
    float v[8] = {u0.x, u0.y, u0.z, u0.w, u1.x, u1.y, u1.z, u1.w};
    float s = 0.f;
#pragma unroll
    for (int j = 0; j < 8; ++j) s += v[j];
#pragma unroll
    for (int o = 32; o > 0; o >>= 1) s += __shfl_xor(s, o);
    float m = s * (1.f / DIMM);
    float q = 0.f;
#pragma unroll
    for (int j = 0; j < 8; ++j) { float d = v[j] - m; q += d * d; }
#pragma unroll
    for (int o = 32; o > 0; o >>= 1) q += __shfl_xor(q, o);
    float rstd = rsqrtf(q * (1.f / DIMM) + 1e-6f);
    float4 w0 = *(const float4*)(w + lane * 8);
    float4 w1 = *(const float4*)(w + lane * 8 + 4);
    float4 b0 = *(const float4*)(bi + lane * 8);
    float4 b1 = *(const float4*)(bi + lane * 8 + 4);
    float wv[8] = {w0.x, w0.y, w0.z, w0.w, w1.x, w1.y, w1.z, w1.w};
    float bv[8] = {b0.x, b0.y, b0.z, b0.w, b1.x, b1.y, b1.z, b1.w};
    ushort4 s0, s1;
    s0.x = f2b((v[0] - m) * rstd * wv[0] + bv[0]);
    s0.y = f2b((v[1] - m) * rstd * wv[1] + bv[1]);
    s0.z = f2b((v[2] - m) * rstd * wv[2] + bv[2]);
    s0.w = f2b((v[3] - m) * rstd * wv[3] + bv[3]);
    s1.x = f2b((v[4] - m) * rstd * wv[4] + bv[4]);
    s1.y = f2b((v[5] - m) * rstd * wv[5] + bv[5]);
    s1.z = f2b((v[6] - m) * rstd * wv[6] + bv[6]);
    s1.w = f2b((v[7] - m) * rstd * wv[7] + bv[7]);
    unsigned short* orow = Hb + (size_t)row * DIMM + lane * 8;
    *(ushort4*)(orow) = s0;
    *(ushort4*)(orow + 4) = s1;
}

// ---------------- per-row mean/rstd (final LN) ----------------
__global__ __launch_bounds__(256) void rowstat_kernel(
        const float* __restrict__ X, float* __restrict__ RS) {
    int row = blockIdx.x * 4 + (threadIdx.x >> 6);
    int lane = threadIdx.x & 63;
    const float* xr = X + (size_t)row * DIMM;
    float4 u0 = *(const float4*)(xr + lane * 8);
    float4 u1 = *(const float4*)(xr + lane * 8 + 4);
    float v[8] = {u0.x, u0.y, u0.z, u0.w, u1.x, u1.y, u1.z, u1.w};
    float s = 0.f;
#pragma unroll
    for (int j = 0; j < 8; ++j) s += v[j];
#pragma unroll
    for (int o = 32; o > 0; o >>= 1) s += __shfl_xor(s, o);
    float m = s * (1.f / DIMM);
    float q = 0.f;
#pragma unroll
    for (int j = 0; j < 8; ++j) { float d = v[j] - m; q += d * d; }
#pragma unroll
    for (int o = 32; o > 0; o >>= 1) q += __shfl_xor(q, o);
    float rstd = rsqrtf(q * (1.f / DIMM) + 1e-6f);
    if (lane == 0) {
        RS[row * 2 + 0] = m;
        RS[row * 2 + 1] = rstd;
    }
}

// ---------------- MFMA GEMM: in_proj (linear grid 2448, XCD swizzle, LDS epilogue) ----------------
__global__ __launch_bounds__(256) void gemm_in_mfma(
        const unsigned short* __restrict__ A,
        const unsigned short* __restrict__ Bt,
        unsigned short* __restrict__ Z, unsigned short* __restrict__ XBC,
        float* __restrict__ DTRAW) {
    __shared__ unsigned short SH[2][128 * 64];
    unsigned short* As = SH[0];
    unsigned short* Bs = SH[1];
    const int tid = threadIdx.x;
    const int l = tid & 63, w = tid >> 6;
    const int wr = w >> 1, wc = w & 1;
    int swz = (blockIdx.x & 7) * 306 + (blockIdx.x >> 3);   // 2448 = 8*306
    const int nx = swz % 17, my = swz / 17;
    const int m0 = my * 128, n0 = nx * 128;
    f32x4 acc[4][4];
#pragma unroll
    for (int i = 0; i < 4; ++i)
#pragma unroll
        for (int j = 0; j < 4; ++j) acc[i][j] = (f32x4)(0.f);

    int rA[4], rB[4];
#pragma unroll
    for (int f = 0; f < 4; ++f) {
        rA[f] = wr * 64 + f * 16 + (l & 15);
        rB[f] = wc * 64 + f * 16 + (l & 15);
    }
    const char* AsB = (const char*)As;
    const char* BsB = (const char*)Bs;

    for (int k0 = 0; k0 < 512; k0 += 64) {
        __syncthreads();
#pragma unroll
        for (int i = 0; i < 4; ++i) {
            int lin = i * 256 + tid;
            int r = lin >> 3, slot = lin & 7;
            int sc = (slot ^ (r & 7)) * 8;
            gload16(A  + (size_t)(m0 + r) * 512 + k0 + sc, As + lin * 8);
            gload16(Bt + (size_t)(n0 + r) * 512 + k0 + sc, Bs + lin * 8);
        }
        __syncthreads();
#pragma unroll
        for (int kk = 0; kk < 2; ++kk) {
            bf16x8 af[4], bfr[4];
            int c16 = kk * 4 + (l >> 4);
#pragma unroll
            for (int f = 0; f < 4; ++f) {
                int row = rA[f];
                af[f] = *(const bf16x8*)(AsB + row * 128 + ((c16 ^ (row & 7)) << 4));
            }
#pragma unroll
            for (int f = 0; f < 4; ++f) {
                int row = rB[f];
                bfr[f] = *(const bf16x8*)(BsB + row * 128 + ((c16 ^ (row & 7)) << 4));
            }
#pragma unroll
            for (int mf = 0; mf < 4; ++mf)
#pragma unroll
                for (int nf = 0; nf < 4; ++nf)
                    acc[mf][nf] = __builtin_amdgcn_mfma_f32_16x16x32_bf16(
                        af[mf], bfr[nf], acc[mf][nf], 0, 0, 0);
        }
    }

    if (nx < 16) {
        // fast path: whole 128-col tile goes to ONE dst (Z for nx<8, XBC for 8<=nx<16)
        __syncthreads();   // all waves done reading staging LDS
        unsigned short* T = &SH[0][0];  // 128x128 bf16 tile = 32KB
#pragma unroll
        for (int mf = 0; mf < 4; ++mf)
#pragma unroll
            for (int nf = 0; nf < 4; ++nf) {
                int tcol = wc * 64 + nf * 16 + (l & 15);
#pragma unroll
                for (int reg = 0; reg < 4; ++reg) {
                    int trow = wr * 64 + mf * 16 + (l >> 4) * 4 + reg;
                    T[trow * 128 + tcol] = f2b(acc[mf][nf][reg]);
                }
            }
        __syncthreads();
        const bool isZ = n0 < DINN;
        unsigned short* dbase = isZ ? (Z + n0) : (XBC + (n0 - DINN));
        const int stride = isZ ? DINN : CONVD;
#pragma unroll
        for (int p = 0; p < 8; ++p) {
            int row = p * 16 + (tid >> 4);
            uint4 v = *(const uint4*)((const char*)T + row * 256 + (tid & 15) * 16);
            unsigned short* drow = dbase + (size_t)(m0 + row) * stride;
            *(uint4*)((char*)drow + (tid & 15) * 16) = v;
        }
    } else {
        // boundary tile (cols 2048..2175): XBC tail + DTRAW fp32 + pad — scatter path
#pragma unroll
        for (int mf = 0; mf < 4; ++mf)
#pragma unroll
            for (int nf = 0; nf < 4; ++nf) {
                int col = n0 + wc * 64 + nf * 16 + (l & 15);
#pragma unroll
                for (int reg = 0; reg < 4; ++reg) {
                    int row = m0 + wr * 64 + mf * 16 + (l >> 4) * 4 + reg;
                    float v = acc[mf][nf][reg];
                    if (col < DINN + CONVD)  XBC[(size_t)row * CONVD + (col - DINN)] = f2b(v);
                    else if (col < DPROJJ)   DTRAW[(size_t)row * NHH + (col - DINN - CONVD)] = v;
                }
            }
    }
}

// ---------------- MFMA GEMM: out_proj (linear grid 576, XCD swizzle), X += ----------------
__global__ __launch_bounds__(256) void gemm_out_mfma(
        const unsigned short* __restrict__ A,
        const unsigned short* __restrict__ Bt,
        float* __restrict__ X) {
    __shared__ unsigned short As[128 * 64];
    __shared__ unsigned short Bs[128 * 64];
    const int tid = threadIdx.x;
    const int l = tid & 63, w = tid >> 6;
    const int wr = w >> 1, wc = w & 1;
    int swz = (blockIdx.x & 7) * 72 + (blockIdx.x >> 3);   // 576 = 8*72
    const int m0 = (swz >> 2) * 128, n0 = (swz & 3) * 128;
    f32x4 acc[4][4];
#pragma unroll
    for (int i = 0; i < 4; ++i)
#pragma unroll
        for (int j = 0; j < 4; ++j) acc[i][j] = (f32x4)(0.f);

    int rA[4], rB[4];
#pragma unroll
    for (int f = 0; f < 4; ++f) {
        rA[f] = wr * 64 + f * 16 + (l & 15);
        rB[f] = wc * 64 + f * 16 + (l & 15);
    }
    const char* AsB = (const char*)As;
    const char* BsB = (const char*)Bs;

    for (int k0 = 0; k0 < 1024; k0 += 64) {
        __syncthreads();
#pragma unroll
        for (int i = 0; i < 4; ++i) {
            int lin = i * 256 + tid;
            int r = lin >> 3, slot = lin & 7;
            int sc = (slot ^ (r & 7)) * 8;
            gload16(A  + (size_t)(m0 + r) * 1024 + k0 + sc, As + lin * 8);
            gload16(Bt + (size_t)(n0 + r) * 1024 + k0 + sc, Bs + lin * 8);
        }
        __syncthreads();
#pragma unroll
        for (int kk = 0; kk < 2; ++kk) {
            bf16x8 af[4], bfr[4];
            int c16 = kk * 4 + (l >> 4);
#pragma unroll
            for (int f = 0; f < 4; ++f) {
                int row = rA[f];
                af[f] = *(const bf16x8*)(AsB + row * 128 + ((c16 ^ (row & 7)) << 4));
            }
#pragma unroll
            for (int f = 0; f < 4; ++f) {
                int row = rB[f];
                bfr[f] = *(const bf16x8*)(BsB + row * 128 + ((c16 ^ (row & 7)) << 4));
            }
#pragma unroll
            for (int mf = 0; mf < 4; ++mf)
#pragma unroll
                for (int nf = 0; nf < 4; ++nf)
                    acc[mf][nf] = __builtin_amdgcn_mfma_f32_16x16x32_bf16(
                        af[mf], bfr[nf], acc[mf][nf], 0, 0, 0);
        }
    }
#pragma unroll
    for (int mf = 0; mf < 4; ++mf)
#pragma unroll
        for (int nf = 0; nf < 4; ++nf) {
            int col = n0 + wc * 64 + nf * 16 + (l & 15);
#pragma unroll
            for (int reg = 0; reg < 4; ++reg) {
                int row = m0 + wr * 64 + mf * 16 + (l >> 4) * 4 + reg;
                float* p = X + (size_t)row * DIMM + col;
                *p += acc[mf][nf][reg];
            }
        }
}

// ---------------- Causal depthwise conv + silu + rope split, LDS-tiled ----------------
__global__ __launch_bounds__(256) void conv_kernel(
        const unsigned short* __restrict__ XBC, const float* __restrict__ cw,
        const float* __restrict__ cb,
        const float* __restrict__ Bb, const float* __restrict__ Cb,
        const float* __restrict__ COS, const float* __restrict__ SIN,
        unsigned short* __restrict__ XS, float* __restrict__ BM, float* __restrict__ CM) {
    __shared__ unsigned short sh[35][128];
    int tileIdx = blockIdx.x;
    int c0 = blockIdx.y * 128;
    int b = tileIdx / 18, lt = tileIdx % 18;
    int l0 = lt * 32;
    int r0 = b * L_TOK + l0;

    for (int idx = threadIdx.x; idx < 35 * 128; idx += 256) {
        int row = idx >> 7, col = idx & 127;
        int t = l0 - 3 + row;
        int c = c0 + col;
        unsigned short v = 0;
        if (t >= 0 && c < CONVD)
            v = XBC[(size_t)(b * L_TOK + t) * CONVD + c];
        sh[row][col] = v;
    }
    __syncthreads();

    int tx = threadIdx.x & 127, ty = threadIdx.x >> 7;
    int c = c0 + tx;
    if (c >= CONVD) return;
    float w0 = cw[c * 4 + 0], w1 = cw[c * 4 + 1], w2 = cw[c * 4 + 2], w3 = cw[c * 4 + 3];
    float bias = cb[c];

    if (c < DINN) {
#pragma unroll
        for (int i = 0; i < 16; ++i) {
            int t = ty * 16 + i;
            float acc = w0 * b2f(sh[t][tx]) + w1 * b2f(sh[t + 1][tx])
                      + w2 * b2f(sh[t + 2][tx]) + w3 * b2f(sh[t + 3][tx]);
            float v = acc + bias;
            v = v / (1.f + expf(-v));
            XS[(size_t)(r0 + t) * DINN + c] = f2b(v);
        }
    } else {
        int j = c - DINN;
        int jj = j & 31;
        bool isB = j < 32;
        float bias2 = isB ? Bb[jj] : Cb[jj];
        int i0 = jj & 7;
#pragma unroll
        for (int i = 0; i < 16; ++i) {
            int t = ty * 16 + i;
            int lglob = l0 + t;
            float acc = w0 * b2f(sh[t][tx]) + w1 * b2f(sh[t + 1][tx])
                      + w2 * b2f(sh[t + 2][tx]) + w3 * b2f(sh[t + 3][tx]);
            float v = acc + bias;
            v = v / (1.f + expf(-v));
            float v2 = v + bias2;
            float partner = __shfl_xor(v2, 8);
            float outv;
            if (jj < 16) {
                float cs = COS[lglob * 8 + i0], sn = SIN[lglob * 8 + i0];
                outv = (jj < 8) ? (v2 * cs - partner * sn) : (partner * sn + v2 * cs);
            } else {
                outv = v2;
            }
            if (isB) BM[(size_t)(r0 + t) * NSTT + jj] = outv;
            else     CM[(size_t)(r0 + t) * NSTT + jj] = outv;
        }
    }
}

// ---------------- chunked scan pass A: MFMA SSD intra-chunk ----------------
__global__ __launch_bounds__(64) void scanA_kernel(
        unsigned short* __restrict__ XSY,
        const float* __restrict__ DTRAW, const float* __restrict__ dtb,
        const float* __restrict__ Alog,
        const float* __restrict__ BM, const float* __restrict__ CM,
        const float* __restrict__ Dsk,
        float* __restrict__ SC, float* __restrict__ ET, float* __restrict__ ECH) {
    int c = blockIdx.x, bh = blockIdx.y;
    int b = bh >> 4, h = bh & 15;
    int l = threadIdx.x;
    int r0 = b * L_TOK + c * 64;

    __shared__ unsigned short Wl[64 * 64];
    __shared__ unsigned short XT[64 * 64];
    __shared__ unsigned short BT[32 * 64];
    __shared__ float Lsh[64];
    __shared__ float dtsh[64];

    float raw = DTRAW[(size_t)(r0 + l) * NHH + h] + dtb[h];
    float dtl = fmaxf(raw, 0.f) + log1pf(expf(-fabsf(raw)));
    float L = -expf(Alog[h]) * dtl;
#pragma unroll
    for (int off = 1; off < 64; off <<= 1) {
        float v = __shfl_up(L, off);
        if (l >= off) L += v;
    }
    float LEND = __shfl(L, 63);
    ET[(size_t)bh * L_TOK + c * 64 + l] = __expf(L);
    if (l == 0) ECH[bh * NCH + c] = __expf(LEND);
    Lsh[l] = L;
    dtsh[l] = dtl;
    float ul = __expf(LEND - L) * dtl;
    float dsk = Dsk[h];

    bf16x8 cf[4], bq[4];
#pragma unroll
    for (int f = 0; f < 4; ++f) {
        const float* cp = CM + (size_t)(r0 + f * 16 + (l & 15)) * NSTT + (l >> 4) * 8;
        const float* bp = BM + (size_t)(r0 + f * 16 + (l & 15)) * NSTT + (l >> 4) * 8;
        float4 c0 = *(const float4*)cp, c1 = *(const float4*)(cp + 4);
        float4 b0 = *(const float4*)bp, b1 = *(const float4*)(bp + 4);
        bf16x8 cv, bv;
        cv[0]=(short)f2b(c0.x); cv[1]=(short)f2b(c0.y); cv[2]=(short)f2b(c0.z); cv[3]=(short)f2b(c0.w);
        cv[4]=(short)f2b(c1.x); cv[5]=(short)f2b(c1.y); cv[6]=(short)f2b(c1.z); cv[7]=(short)f2b(c1.w);
        bv[0]=(short)f2b(b0.x); bv[1]=(short)f2b(b0.y); bv[2]=(short)f2b(b0.z); bv[3]=(short)f2b(b0.w);
        bv[4]=(short)f2b(b1.x); bv[5]=(short)f2b(b1.y); bv[6]=(short)f2b(b1.z); bv[7]=(short)f2b(b1.w);
        cf[f] = cv; bq[f] = bv;
    }
    f32x4 acc[4][4];
#pragma unroll
    for (int i = 0; i < 4; ++i)
#pragma unroll
        for (int j = 0; j < 4; ++j) acc[i][j] = (f32x4)(0.f);
#pragma unroll
    for (int mf = 0; mf < 4; ++mf)
#pragma unroll
        for (int nf = 0; nf < 4; ++nf)
            acc[mf][nf] = __builtin_amdgcn_mfma_f32_16x16x32_bf16(cf[mf], bq[nf], acc[mf][nf], 0, 0, 0);

    __builtin_amdgcn_wave_barrier();
#pragma unroll
    for (int nf = 0; nf < 4; ++nf) {
        int s = nf * 16 + (l & 15);
        float Ls = Lsh[s], dts = dtsh[s];
#pragma unroll
        for (int mf = 0; mf < 4; ++mf) {
#pragma unroll
            for (int reg = 0; reg < 4; ++reg) {
                int t = mf * 16 + (l >> 4) * 4 + reg;
                float Lt = Lsh[t];
                float v = acc[mf][nf][reg];
                float wv = (s <= t) ? __expf(Lt - Ls) * dts * v : 0.f;
                if (s == t) wv += dsk;
                *(unsigned short*)((char*)Wl + swz64(t, s)) = f2b(wv);
            }
        }
    }

    uint xw[32];
    {
        const uint* xp = (const uint*)(XSY + (size_t)(r0 + l) * DINN + h * HDD);
#pragma unroll
        for (int i = 0; i < 8; ++i) {
            uint4 v = *(const uint4*)(xp + i * 4);
            xw[i*4+0]=v.x; xw[i*4+1]=v.y; xw[i*4+2]=v.z; xw[i*4+3]=v.w;
        }
    }
#pragma unroll
    for (int p = 0; p < 64; ++p) {
        unsigned short xv = (p & 1) ? (unsigned short)(xw[p >> 1] >> 16)
                                    : (unsigned short)(xw[p >> 1] & 0xffffu);
        *(unsigned short*)((char*)XT + swz64(p, l)) = xv;
    }
    __builtin_amdgcn_wave_barrier();

    f32x4 yacc[4][4];
#pragma unroll
    for (int i = 0; i < 4; ++i)
#pragma unroll
        for (int j = 0; j < 4; ++j) yacc[i][j] = (f32x4)(0.f);
#pragma unroll
    for (int kk = 0; kk < 2; ++kk) {
        int slot = kk * 4 + (l >> 4);
        bf16x8 wf[4], xf[4];
#pragma unroll
        for (int f = 0; f < 4; ++f) {
            int rw = f * 16 + (l & 15);
            wf[f] = *(const bf16x8*)((const char*)Wl + rw * 128 + (((slot ^ rw) & 7) << 4));
            xf[f] = *(const bf16x8*)((const char*)XT + rw * 128 + (((slot ^ rw) & 7) << 4));
        }
#pragma unroll
        for (int mf = 0; mf < 4; ++mf)
#pragma unroll
            for (int nf = 0; nf < 4; ++nf)
                yacc[mf][nf] = __builtin_amdgcn_mfma_f32_16x16x32_bf16(
                    wf[mf], xf[nf], yacc[mf][nf], 0, 0, 0);
    }

    __builtin_amdgcn_wave_barrier();
#pragma unroll
    for (int mf = 0; mf < 4; ++mf)
#pragma unroll
        for (int nf = 0; nf < 4; ++nf)
#pragma unroll
            for (int reg = 0; reg < 4; ++reg) {
                int t = mf * 16 + (l >> 4) * 4 + reg;
                int p = nf * 16 + (l & 15);
                *(unsigned short*)((char*)Wl + swz64(t, p)) = f2b(yacc[mf][nf][reg]);
            }
    __builtin_amdgcn_wave_barrier();
    {
        unsigned short* yp = XSY + (size_t)(r0 + l) * DINN + h * HDD;
#pragma unroll
        for (int j = 0; j < 8; ++j) {
            uint4 v = *(const uint4*)((const char*)Wl + l * 128 + (((j ^ l) & 7) << 4));
            *(uint4*)(yp + j * 8) = v;
        }
    }

    __builtin_amdgcn_wave_barrier();
#pragma unroll
    for (int p = 0; p < 64; ++p) {
        unsigned short xv = (p & 1) ? (unsigned short)(xw[p >> 1] >> 16)
                                    : (unsigned short)(xw[p >> 1] & 0xffffu);
        *(unsigned short*)((char*)XT + swz64(p, l)) = f2b(b2f(xv) * ul);
    }
    {
        const float* bp = BM + (size_t)(r0 + l) * NSTT;
#pragma unroll
        for (int n = 0; n < 32; n += 4) {
            float4 v = *(const float4*)(bp + n);
            *(unsigned short*)((char*)BT + swz64(n + 0, l)) = f2b(v.x);
            *(unsigned short*)((char*)BT + swz64(n + 1, l)) = f2b(v.y);
            *(unsigned short*)((char*)BT + swz64(n + 2, l)) = f2b(v.z);
            *(unsigned short*)((char*)BT + swz64(n + 3, l)) = f2b(v.w);
        }
    }
    __builtin_amdgcn_wave_barrier();
    f32x4 sacc[4][2];
#pragma unroll
    for (int i = 0; i < 4; ++i)
#pragma unroll
        for (int j = 0; j < 2; ++j) sacc[i][j] = (f32x4)(0.f);
#pragma unroll
    for (int kk = 0; kk < 2; ++kk) {
        int slot = kk * 4 + (l >> 4);
        bf16x8 uf[4], btf[2];
#pragma unroll
        for (int f = 0; f < 4; ++f) {
            int rw = f * 16 + (l & 15);
            uf[f] = *(const bf16x8*)((const char*)XT + rw * 128 + (((slot ^ rw) & 7) << 4));
        }
#pragma unroll
        for (int f = 0; f < 2; ++f) {
            int rw = f * 16 + (l & 15);
            btf[f] = *(const bf16x8*)((const char*)BT + rw * 128 + (((slot ^ rw) & 7) << 4));
        }
#pragma unroll
        for (int mf = 0; mf < 4; ++mf)
#pragma unroll
            for (int nf = 0; nf < 2; ++nf)
                sacc[mf][nf] = __builtin_amdgcn_mfma_f32_16x16x32_bf16(
                    uf[mf], btf[nf], sacc[mf][nf], 0, 0, 0);
    }
    {
        float* sp = SC + (size_t)(bh * NCH + c) * 64 * 32;
#pragma unroll
        for (int mf = 0; mf < 4; ++mf)
#pragma unroll
            for (int nf = 0; nf < 2; ++nf)
#pragma unroll
                for (int reg = 0; reg < 4; ++reg) {
                    int p = mf * 16 + (l >> 4) * 4 + reg;
                    int n = nf * 16 + (l & 15);
                    sp[p * 32 + n] = sacc[mf][nf][reg];
                }
    }
}

// ---------------- pass B ----------------
__global__ __launch_bounds__(64) void scanB_kernel(
        float* __restrict__ SC, const float* __restrict__ ECH) {
    int bh = blockIdx.x;
    int p = threadIdx.x;
    float H[32];
#pragma unroll
    for (int n = 0; n < 32; ++n) H[n] = 0.f;
    for (int c = 0; c < NCH; ++c) {
        float e = ECH[bh * NCH + c];
        float* sp = SC + ((size_t)(bh * NCH + c) * 64 + p) * 32;
        float s[32];
#pragma unroll
        for (int n4 = 0; n4 < 8; ++n4) {
            float4 v = *(const float4*)(sp + n4 * 4);
            s[n4*4+0]=v.x; s[n4*4+1]=v.y; s[n4*4+2]=v.z; s[n4*4+3]=v.w;
        }
#pragma unroll
        for (int n4 = 0; n4 < 8; ++n4)
            *(float4*)(sp + n4 * 4) = make_float4(H[n4*4+0], H[n4*4+1], H[n4*4+2], H[n4*4+3]);
#pragma unroll
        for (int n = 0; n < 32; ++n) H[n] = e * H[n] + s[n];
    }
}

// ---------------- pass C ----------------
__global__ __launch_bounds__(64) void scanC_kernel(
        unsigned short* __restrict__ XSY, const float* __restrict__ SC,
        const float* __restrict__ CM, const float* __restrict__ ET) {
    int c = blockIdx.x, bh = blockIdx.y;
    int b = bh >> 4, h = bh & 15;
    int l = threadIdx.x;
    int r0 = b * L_TOK + c * 64;
    __shared__ float CEsh[64][36];
#pragma unroll
    for (int i = 0; i < 32; ++i) {
        int idx = i * 64 + l;
        int t = idx >> 5, n = idx & 31;
        CEsh[t][n] = CM[(size_t)(r0 + t) * NSTT + n] * ET[(size_t)bh * L_TOK + c * 64 + t];
    }
    const float* hp = SC + ((size_t)(bh * NCH + c) * 64 + l) * 32;
    float H[32];
#pragma unroll
    for (int n4 = 0; n4 < 8; ++n4) {
        float4 v = *(const float4*)(hp + n4 * 4);
        H[n4*4+0]=v.x; H[n4*4+1]=v.y; H[n4*4+2]=v.z; H[n4*4+3]=v.w;
    }
    __builtin_amdgcn_wave_barrier();
    unsigned short* yp = XSY + (size_t)r0 * DINN + h * HDD + l;
    for (int t = 0; t < 64; ++t) {
        float acc = 0.f;
#pragma unroll
        for (int n4 = 0; n4 < 8; ++n4) {
            float4 ce = *(const float4*)&CEsh[t][n4 * 4];
            acc += ce.x * H[n4*4+0] + ce.y * H[n4*4+1]
                 + ce.z * H[n4*4+2] + ce.w * H[n4*4+3];
        }
        float y = b2f(yp[(size_t)t * DINN]) + acc;
        yp[(size_t)t * DINN] = f2b(y);
    }
}

// ---------------- gate with silu(z) + RMSNorm(1024) * gn_w (vectorized) ----------------
__global__ __launch_bounds__(256) void rmsgate_kernel(
        unsigned short* __restrict__ Y, const unsigned short* __restrict__ Z,
        const float* __restrict__ gw) {
    int row = blockIdx.x * 4 + (threadIdx.x >> 6);
    int lane = threadIdx.x & 63;
    unsigned short* yr = Y + (size_t)row * DINN + lane * 16;
    const unsigned short* zr = Z + (size_t)row * DINN + lane * 16;
    uint4 y0 = *(const uint4*)yr;
    uint4 y1 = *(const uint4*)(yr + 8);
    uint4 z0 = *(const uint4*)zr;
    uint4 z1 = *(const uint4*)(zr + 8);
    uint yw[8] = {y0.x, y0.y, y0.z, y0.w, y1.x, y1.y, y1.z, y1.w};
    uint zw[8] = {z0.x, z0.y, z0.z, z0.w, z1.x, z1.y, z1.z, z1.w};
    float g[16];
    float q = 0.f;
#pragma unroll
    for (int i = 0; i < 8; ++i) {
        float ylo = b2f((unsigned short)(yw[i] & 0xffffu));
        float yhi = b2f((unsigned short)(yw[i] >> 16));
        float zlo = b2f((unsigned short)(zw[i] & 0xffffu));
        float zhi = b2f((unsigned short)(zw[i] >> 16));
        float glo = ylo * (zlo / (1.f + expf(-zlo)));
        float ghi = yhi * (zhi / (1.f + expf(-zhi)));
        g[2*i] = glo; g[2*i+1] = ghi;
        q += glo * glo + ghi * ghi;
    }
#pragma unroll
    for (int o = 32; o > 0; o >>= 1) q += __shfl_xor(q, o);
    float sc = rsqrtf(q * (1.f / DINN) + 1e-6f);
    const float* gwp = gw + lane * 16;
    uint ow[8];
#pragma unroll
    for (int i = 0; i < 8; ++i) {
        float wlo = gwp[2*i], whi = gwp[2*i+1];
        uint lo = f2b(g[2*i] * sc * wlo);
        uint hi = f2b(g[2*i+1] * sc * whi);
        ow[i] = lo | (hi << 16);
    }
    *(uint4*)yr = make_uint4(ow[0], ow[1], ow[2], ow[3]);
    *(uint4*)(yr + 8) = make_uint4(ow[4], ow[5], ow[6], ow[7]);
}

// ---------------- final fused LN + mean over L ----------------
__global__ void lnmean_kernel(const float* __restrict__ X, const float* __restrict__ RS,
                              const float* __restrict__ nw, const float* __restrict__ nb,
                              float* __restrict__ MEAN) {
    int b = blockIdx.x >> 1;
    int d = (blockIdx.x & 1) * 256 + threadIdx.x;
    float w = nw[d], bb = nb[d];
    const float* p = X + (size_t)b * L_TOK * DIMM + d;
    const float* rs = RS + (size_t)b * L_TOK * 2;
    float s = 0.f;
    for (int l = 0; l < L_TOK; ++l) {
        float m = rs[l * 2 + 0], r = rs[l * 2 + 1];
        s += (p[(size_t)l * DIMM] - m) * r * w + bb;
    }
    MEAN[b * DIMM + d] = s * (1.f / L_TOK);
}

// ---------------- head ----------------
__global__ void head_kernel(const float* __restrict__ MEAN, const float* __restrict__ hw,
                            const float* __restrict__ hb, float* __restrict__ out) {
    int t = threadIdx.x;
    if (t >= 64) return;
    int b = t >> 1, c = t & 1;
    float s = 0.f;
    for (int k = 0; k < DIMM; ++k) s += MEAN[b * DIMM + k] * hw[k * 2 + c];
    out[b * 2 + c] = s + hb[c];
}

extern "C" void kernel_launch(void* const* d_in, const int* in_sizes, int n_in,
                              void* d_out, int out_size, void* d_ws, size_t ws_size,
                              hipStream_t stream) {
    const float* x_img   = (const float*)d_in[0];
    const float* patch_w = (const float*)d_in[1];
    const float* patch_b = (const float*)d_in[2];
    const float* pos     = (const float*)d_in[3];
    const float* ln_w    = (const float*)d_in[4];
    const float* ln_b    = (const float*)d_in[5];
    const float* Wp      = (const float*)d_in[6];
    const float* cw      = (const float*)d_in[7];
    const float* cb      = (const float*)d_in[8];
    const float* dtb     = (const float*)d_in[9];
    const float* Alog    = (const float*)d_in[10];
    const float* Dsk     = (const float*)d_in[11];
    const float* Bb      = (const float*)d_in[12];
    const float* Cb      = (const float*)d_in[13];
    const float* gnw     = (const float*)d_in[14];
    const float* Wo      = (const float*)d_in[15];
    const float* nw      = (const float*)d_in[16];
    const float* nb      = (const float*)d_in[17];
    const float* hw      = (const float*)d_in[18];
    const float* hb      = (const float*)d_in[19];
    float* out = (float*)d_out;

    char* base = (char*)d_ws;
    size_t off = 0;
    auto alloc = [&](size_t bytes) -> char* {
        char* p = base + off;
        off += (bytes + 255) & ~(size_t)255;
        return p;
    };
    float*          X     = (float*)alloc((size_t)ROWS * DIMM * 4);
    unsigned short* XBC   = (unsigned short*)alloc((size_t)ROWS * CONVD * 2);
    unsigned short* Z     = (unsigned short*)alloc((size_t)ROWS * DINN * 2);
    unsigned short* XSY   = (unsigned short*)alloc((size_t)ROWS * DINN * 2);
    unsigned short* Hb    = (unsigned short*)alloc((size_t)ROWS * DIMM * 2);
    unsigned short* WpT   = (unsigned short*)alloc((size_t)8 * NPAD * DIMM * 2);
    unsigned short* WoT   = (unsigned short*)alloc((size_t)8 * DIMM * DINN * 2);
    float*          DTRAW = (float*)alloc((size_t)ROWS * NHH * 4);
    float*          BMp   = (float*)alloc((size_t)ROWS * NSTT * 4);
    float*          CMp   = (float*)alloc((size_t)ROWS * NSTT * 4);
    float*          RS    = (float*)alloc((size_t)ROWS * 2 * 4);
    float*          COS   = (float*)alloc((size_t)L_TOK * 8 * 4);
    float*          SIN   = (float*)alloc((size_t)L_TOK * 8 * 4);
    float*          MEAN  = (float*)alloc((size_t)BATCHH * DIMM * 4);
    float*          ET    = (float*)alloc((size_t)BATCHH * NHH * L_TOK * 4);
    float*          ECH   = (float*)alloc((size_t)BATCHH * NHH * NCH * 4);
    unsigned short* AIM   = XBC;          // im2col A aliases XBC
    unsigned short* PWB   = Z;            // patch weight bf16 aliases Z
    float*          SCp   = (float*)XBC;  // chunk states alias XBC
    if (off > ws_size) return;

    rope_init<<<18, 256, 0, stream>>>(COS, SIN);
    transpose_pad<<<dim3(NPAD / 32, DIMM / 32, 8), 256, 0, stream>>>(Wp, WpT, DIMM, DPROJJ, NPAD);
    transpose_pad<<<dim3(DIMM / 32, DINN / 32, 8), 256, 0, stream>>>(Wo, WoT, DINN, DIMM, DIMM);

    f32tobf16_kernel<<<(512 * 768 + 255) / 256, 256, 0, stream>>>(patch_w, PWB, 512 * 768);
    im2col_kernel<<<ROWS, 192, 0, stream>>>(x_img, AIM);
    gemm_patch_mfma<<<576, 256, 0, stream>>>(AIM, PWB, patch_b, pos, X);

    for (int i = 0; i < 8; ++i) {
        lnbf16_kernel<<<ROWS / 4, 256, 0, stream>>>(X, ln_w + i * DIMM, ln_b + i * DIMM, Hb);
        gemm_in_mfma<<<2448, 256, 0, stream>>>(
            Hb, WpT + (size_t)i * NPAD * DIMM, Z, XBC, DTRAW);
        conv_kernel<<<dim3(BATCHH * 18, 9), 256, 0, stream>>>(
            XBC, cw + (size_t)i * CONVD * 4, cb + (size_t)i * CONVD,
            Bb + i * NSTT, Cb + i * NSTT, COS, SIN, XSY, BMp, CMp);
        scanA_kernel<<<dim3(NCH, BATCHH * NHH), 64, 0, stream>>>(
            XSY, DTRAW, dtb + i * NHH, Alog + i * NHH, BMp, CMp, Dsk + i * NHH, SCp, ET, ECH);
        scanB_kernel<<<BATCHH * NHH, 64, 0, stream>>>(SCp, ECH);
        scanC_kernel<<<dim3(NCH, BATCHH * NHH), 64, 0, stream>>>(XSY, SCp, CMp, ET);
        rmsgate_kernel<<<ROWS / 4, 256, 0, stream>>>(XSY, Z, gnw + (size_t)i * DINN);
        gemm_out_mfma<<<576, 256, 0, stream>>>(
            XSY, WoT + (size_t)i * DIMM * DINN, X);
    }

    rowstat_kernel<<<ROWS / 4, 256, 0, stream>>>(X, RS);
    lnmean_kernel<<<64, 256, 0, stream>>>(X, RS, nw, nb, MEAN);
    head_kernel<<<1, 64, 0, stream>>>(MEAN, hw, hb, out);
}